// Round 5
// baseline (805.462 us; speedup 1.0000x reference)
//
#include <hip/hip_runtime.h>
#include <hip/hip_fp16.h>
#include <cstdint>

#define NTHREADS 256
#define TBL_SIZE (1u << 19)
#define HIDDEN 64
#define NLVL 16

struct Levels { float scale[16]; int res[16]; int dense[16]; };
constexpr Levels make_levels() {
    Levels L{};
    double s = 16.0;
    for (int l = 0; l < 16; ++l) {
        double sc = s - 1.0;
        L.scale[l] = (float)sc;
        int fi = (int)sc;
        int res = fi + (((double)fi < sc) ? 1 : 0) + 1;   // ceil(sc)+1
        L.res[l] = res;
        L.dense[l] = ((long long)res * res * res <= (long long)TBL_SIZE) ? 1 : 0;
        s *= 1.3819;
    }
    return L;
}
constexpr Levels LV = make_levels();

#define H16(M) M(0) M(1) M(2) M(3) M(4) M(5) M(6) M(7) \
               M(8) M(9) M(10) M(11) M(12) M(13) M(14) M(15)

// ---------- f32 table -> fp16 repack ----------
__global__ __launch_bounds__(256) void cvt_table(const float2* __restrict__ in,
                                                 __half2* __restrict__ out, int n) {
    for (int i = blockIdx.x * 256 + threadIdx.x; i < n; i += gridDim.x * 256) {
        const float2 v = in[i];
        out[i] = __floats2half2_rn(v.x, v.y);
    }
}

// ---------- Kernel A: encode only (low-reg, high occupancy, gather-bound) ----------
__global__ __launch_bounds__(NTHREADS, 8) void encode_kernel(
    const float* __restrict__ x,
    const __half2* __restrict__ tbl,
    __half2* __restrict__ enc, int n)
{
    const int i = blockIdx.x * NTHREADS + threadIdx.x;
    if (i >= n) return;

    const float u = (x[3 * i + 0] + 1.0f) * 0.5f;
    const float v = (x[3 * i + 1] + 1.0f) * 0.5f;
    const float w = (x[3 * i + 2] + 1.0f) * 0.5f;

    #pragma unroll
    for (int l = 0; l < NLVL; ++l) {
        const float sc = LV.scale[l];
        const int res = LV.res[l];
        const float pu = u * sc + 0.5f;
        const float pv = v * sc + 0.5f;
        const float pw = w * sc + 0.5f;
        const float fu = floorf(pu), fv = floorf(pv), fw = floorf(pw);
        const float wu = pu - fu, wv = pv - fv, ww = pw - fw;
        const int iu = (int)fu, iv = (int)fv, iw = (int)fw;

        int idx[8];
        #pragma unroll
        for (int b = 0; b < 8; ++b) {
            const int o0 = (b >> 2) & 1, o1 = (b >> 1) & 1, o2 = b & 1;
            if (LV.dense[l]) {
                idx[b] = (iu + o0) + (iv + o1) * res + (iw + o2) * (res * res);
            } else {
                const uint32_t c0 = (uint32_t)(iu + o0);
                const uint32_t c1 = (uint32_t)(iv + o1);
                const uint32_t c2 = (uint32_t)(iw + o2);
                const uint32_t h = c0 ^ (c1 * 2654435761u) ^ (c2 * 805459861u);
                idx[b] = (int)(h & (TBL_SIZE - 1u));
            }
        }
        const __half2* tl = tbl + (size_t)l * TBL_SIZE;
        __half2 cfh[8];
        #pragma unroll
        for (int b = 0; b < 8; ++b) cfh[b] = tl[idx[b]];   // 8 gathers in flight

        float f0 = 0.0f, f1 = 0.0f;
        #pragma unroll
        for (int b = 0; b < 8; ++b) {
            const int o0 = (b >> 2) & 1, o1 = (b >> 1) & 1, o2 = b & 1;
            const float wt = (o0 ? wu : 1.0f - wu) *
                             (o1 ? wv : 1.0f - wv) *
                             (o2 ? ww : 1.0f - ww);
            const float2 cf = __half22float2(cfh[b]);
            f0 = fmaf(cf.x, wt, f0);
            f1 = fmaf(cf.y, wt, f1);
        }
        enc[(size_t)l * n + i] = __floats2half2_rn(f0, f1);   // coalesced 4B store
    }
}

// ---------- Kernel B: MLP only (VALU-bound, coalesced feature reads) ----------
__global__ __launch_bounds__(NTHREADS, 4) void mlp_kernel(
    const __half2* __restrict__ enc,
    const float* __restrict__ W1, const float* __restrict__ b1,
    const float* __restrict__ W2, const float* __restrict__ b2,
    const float* __restrict__ W3, const float* __restrict__ b3,
    float* __restrict__ out, int n)
{
    const int i = blockIdx.x * NTHREADS + threadIdx.x;
    if (i >= n) return;

#define DECLH(m) float4 h##m = *(const float4*)&b1[4 * (m)];
    H16(DECLH)
#undef DECLH

    #pragma unroll
    for (int l = 0; l < NLVL; ++l) {
        const float2 f = __half22float2(enc[(size_t)l * n + i]);
        const float f0 = f.x, f1 = f.y;
        const float* wra = &W1[(2 * l) * HIDDEN];
        const float* wrb = &W1[(2 * l + 1) * HIDDEN];
#define UPDH(m) { \
        const float4 wa = *(const float4*)&wra[4 * (m)]; \
        const float4 wb = *(const float4*)&wrb[4 * (m)]; \
        h##m.x = fmaf(f0, wa.x, fmaf(f1, wb.x, h##m.x)); \
        h##m.y = fmaf(f0, wa.y, fmaf(f1, wb.y, h##m.y)); \
        h##m.z = fmaf(f0, wa.z, fmaf(f1, wb.z, h##m.z)); \
        h##m.w = fmaf(f0, wa.w, fmaf(f1, wb.w, h##m.w)); }
        H16(UPDH)
#undef UPDH
    }

#define RELUH(m) { h##m.x = fmaxf(h##m.x, 0.0f); h##m.y = fmaxf(h##m.y, 0.0f); \
                   h##m.z = fmaxf(h##m.z, 0.0f); h##m.w = fmaxf(h##m.w, 0.0f); }
    H16(RELUH)
#undef RELUH

    float acc = b3[0];
    #pragma unroll 2
    for (int jb = 0; jb < HIDDEN; jb += 4) {
        float4 t = *(const float4*)&b2[jb];
#define L2K(m) { \
        const float4 r0 = *(const float4*)&W2[(4 * (m) + 0) * HIDDEN + jb]; \
        const float4 r1 = *(const float4*)&W2[(4 * (m) + 1) * HIDDEN + jb]; \
        const float4 r2 = *(const float4*)&W2[(4 * (m) + 2) * HIDDEN + jb]; \
        const float4 r3 = *(const float4*)&W2[(4 * (m) + 3) * HIDDEN + jb]; \
        t.x = fmaf(h##m.x, r0.x, t.x); t.y = fmaf(h##m.x, r0.y, t.y); \
        t.z = fmaf(h##m.x, r0.z, t.z); t.w = fmaf(h##m.x, r0.w, t.w); \
        t.x = fmaf(h##m.y, r1.x, t.x); t.y = fmaf(h##m.y, r1.y, t.y); \
        t.z = fmaf(h##m.y, r1.z, t.z); t.w = fmaf(h##m.y, r1.w, t.w); \
        t.x = fmaf(h##m.z, r2.x, t.x); t.y = fmaf(h##m.z, r2.y, t.y); \
        t.z = fmaf(h##m.z, r2.z, t.z); t.w = fmaf(h##m.z, r2.w, t.w); \
        t.x = fmaf(h##m.w, r3.x, t.x); t.y = fmaf(h##m.w, r3.y, t.y); \
        t.z = fmaf(h##m.w, r3.z, t.z); t.w = fmaf(h##m.w, r3.w, t.w); }
        H16(L2K)
#undef L2K
        const float4 w3v = *(const float4*)&W3[jb];
        acc = fmaf(fmaxf(t.x, 0.0f), w3v.x, acc);
        acc = fmaf(fmaxf(t.y, 0.0f), w3v.y, acc);
        acc = fmaf(fmaxf(t.z, 0.0f), w3v.z, acc);
        acc = fmaf(fmaxf(t.w, 0.0f), w3v.w, acc);
    }

    out[i] = acc;
}

// ---------- Fallback: round-4 fused kernel (if ws too small for split) ----------
template <bool USE_H2>
__global__ __launch_bounds__(NTHREADS, 4) void sdf_tcnn_fused(
    const float* __restrict__ x,
    const void* __restrict__ tbl,
    const float* __restrict__ W1, const float* __restrict__ b1,
    const float* __restrict__ W2, const float* __restrict__ b2,
    const float* __restrict__ W3, const float* __restrict__ b3,
    float* __restrict__ out, int n)
{
    const int i = blockIdx.x * NTHREADS + threadIdx.x;
    if (i >= n) return;

    const float u = (x[3 * i + 0] + 1.0f) * 0.5f;
    const float v = (x[3 * i + 1] + 1.0f) * 0.5f;
    const float w = (x[3 * i + 2] + 1.0f) * 0.5f;

#define DECLH(m) float4 h##m = *(const float4*)&b1[4 * (m)];
    H16(DECLH)
#undef DECLH

    #pragma unroll
    for (int l = 0; l < NLVL; ++l) {
        const float sc = LV.scale[l];
        const int res = LV.res[l];
        const float pu = u * sc + 0.5f;
        const float pv = v * sc + 0.5f;
        const float pw = w * sc + 0.5f;
        const float fu = floorf(pu), fv = floorf(pv), fw = floorf(pw);
        const float wu = pu - fu, wv = pv - fv, ww = pw - fw;
        const int iu = (int)fu, iv = (int)fv, iw = (int)fw;

        int idx[8];
        #pragma unroll
        for (int b = 0; b < 8; ++b) {
            const int o0 = (b >> 2) & 1, o1 = (b >> 1) & 1, o2 = b & 1;
            if (LV.dense[l]) {
                idx[b] = (iu + o0) + (iv + o1) * res + (iw + o2) * (res * res);
            } else {
                const uint32_t c0 = (uint32_t)(iu + o0);
                const uint32_t c1 = (uint32_t)(iv + o1);
                const uint32_t c2 = (uint32_t)(iw + o2);
                const uint32_t h = c0 ^ (c1 * 2654435761u) ^ (c2 * 805459861u);
                idx[b] = (int)(h & (TBL_SIZE - 1u));
            }
        }

        float f0 = 0.0f, f1 = 0.0f;
        if constexpr (USE_H2) {
            const __half2* tl = (const __half2*)tbl + (size_t)l * TBL_SIZE;
            __half2 cfh[8];
            #pragma unroll
            for (int b = 0; b < 8; ++b) cfh[b] = tl[idx[b]];
            #pragma unroll
            for (int b = 0; b < 8; ++b) {
                const int o0 = (b >> 2) & 1, o1 = (b >> 1) & 1, o2 = b & 1;
                const float wt = (o0 ? wu : 1.0f - wu) *
                                 (o1 ? wv : 1.0f - wv) *
                                 (o2 ? ww : 1.0f - ww);
                const float2 cf = __half22float2(cfh[b]);
                f0 = fmaf(cf.x, wt, f0);
                f1 = fmaf(cf.y, wt, f1);
            }
        } else {
            const float2* tl = (const float2*)tbl + (size_t)l * TBL_SIZE;
            float2 cf[8];
            #pragma unroll
            for (int b = 0; b < 8; ++b) cf[b] = tl[idx[b]];
            #pragma unroll
            for (int b = 0; b < 8; ++b) {
                const int o0 = (b >> 2) & 1, o1 = (b >> 1) & 1, o2 = b & 1;
                const float wt = (o0 ? wu : 1.0f - wu) *
                                 (o1 ? wv : 1.0f - wv) *
                                 (o2 ? ww : 1.0f - ww);
                f0 = fmaf(cf[b].x, wt, f0);
                f1 = fmaf(cf[b].y, wt, f1);
            }
        }

        const float* wra = &W1[(2 * l) * HIDDEN];
        const float* wrb = &W1[(2 * l + 1) * HIDDEN];
#define UPDH(m) { \
        const float4 wa = *(const float4*)&wra[4 * (m)]; \
        const float4 wb = *(const float4*)&wrb[4 * (m)]; \
        h##m.x = fmaf(f0, wa.x, fmaf(f1, wb.x, h##m.x)); \
        h##m.y = fmaf(f0, wa.y, fmaf(f1, wb.y, h##m.y)); \
        h##m.z = fmaf(f0, wa.z, fmaf(f1, wb.z, h##m.z)); \
        h##m.w = fmaf(f0, wa.w, fmaf(f1, wb.w, h##m.w)); }
        H16(UPDH)
#undef UPDH
    }

#define RELUH(m) { h##m.x = fmaxf(h##m.x, 0.0f); h##m.y = fmaxf(h##m.y, 0.0f); \
                   h##m.z = fmaxf(h##m.z, 0.0f); h##m.w = fmaxf(h##m.w, 0.0f); }
    H16(RELUH)
#undef RELUH

    float acc = b3[0];
    #pragma unroll 2
    for (int jb = 0; jb < HIDDEN; jb += 4) {
        float4 t = *(const float4*)&b2[jb];
#define L2K(m) { \
        const float4 r0 = *(const float4*)&W2[(4 * (m) + 0) * HIDDEN + jb]; \
        const float4 r1 = *(const float4*)&W2[(4 * (m) + 1) * HIDDEN + jb]; \
        const float4 r2 = *(const float4*)&W2[(4 * (m) + 2) * HIDDEN + jb]; \
        const float4 r3 = *(const float4*)&W2[(4 * (m) + 3) * HIDDEN + jb]; \
        t.x = fmaf(h##m.x, r0.x, t.x); t.y = fmaf(h##m.x, r0.y, t.y); \
        t.z = fmaf(h##m.x, r0.z, t.z); t.w = fmaf(h##m.x, r0.w, t.w); \
        t.x = fmaf(h##m.y, r1.x, t.x); t.y = fmaf(h##m.y, r1.y, t.y); \
        t.z = fmaf(h##m.y, r1.z, t.z); t.w = fmaf(h##m.y, r1.w, t.w); \
        t.x = fmaf(h##m.z, r2.x, t.x); t.y = fmaf(h##m.z, r2.y, t.y); \
        t.z = fmaf(h##m.z, r2.z, t.z); t.w = fmaf(h##m.z, r2.w, t.w); \
        t.x = fmaf(h##m.w, r3.x, t.x); t.y = fmaf(h##m.w, r3.y, t.y); \
        t.z = fmaf(h##m.w, r3.z, t.z); t.w = fmaf(h##m.w, r3.w, t.w); }
        H16(L2K)
#undef L2K
        const float4 w3v = *(const float4*)&W3[jb];
        acc = fmaf(fmaxf(t.x, 0.0f), w3v.x, acc);
        acc = fmaf(fmaxf(t.y, 0.0f), w3v.y, acc);
        acc = fmaf(fmaxf(t.z, 0.0f), w3v.z, acc);
        acc = fmaf(fmaxf(t.w, 0.0f), w3v.w, acc);
    }

    out[i] = acc;
}

extern "C" void kernel_launch(void* const* d_in, const int* in_sizes, int n_in,
                              void* d_out, int out_size, void* d_ws, size_t ws_size,
                              hipStream_t stream) {
    const float* x     = (const float*)d_in[0];
    const float* table = (const float*)d_in[1];
    const float* W1    = (const float*)d_in[2];
    const float* b1    = (const float*)d_in[3];
    const float* W2    = (const float*)d_in[4];
    const float* b2    = (const float*)d_in[5];
    const float* W3    = (const float*)d_in[6];
    const float* b3    = (const float*)d_in[7];
    float* out = (float*)d_out;

    const int n = in_sizes[0] / 3;
    const int n_entries = NLVL * (int)TBL_SIZE;
    const size_t tbl_bytes = (size_t)n_entries * sizeof(__half2);      // 33.6 MB
    const size_t enc_bytes = (size_t)NLVL * (size_t)n * sizeof(__half2); // 64 MB
    dim3 grid((n + NTHREADS - 1) / NTHREADS);

    if (ws_size >= tbl_bytes + enc_bytes) {
        __half2* tbl_h2 = (__half2*)d_ws;
        __half2* enc    = (__half2*)((char*)d_ws + tbl_bytes);
        hipLaunchKernelGGL(cvt_table, dim3(2048), dim3(256), 0, stream,
                           (const float2*)table, tbl_h2, n_entries);
        hipLaunchKernelGGL(encode_kernel, grid, dim3(NTHREADS), 0, stream,
                           x, tbl_h2, enc, n);
        hipLaunchKernelGGL(mlp_kernel, grid, dim3(NTHREADS), 0, stream,
                           enc, W1, b1, W2, b2, W3, b3, out, n);
    } else if (ws_size >= tbl_bytes) {
        __half2* tbl_h2 = (__half2*)d_ws;
        hipLaunchKernelGGL(cvt_table, dim3(2048), dim3(256), 0, stream,
                           (const float2*)table, tbl_h2, n_entries);
        hipLaunchKernelGGL((sdf_tcnn_fused<true>), grid, dim3(NTHREADS), 0, stream,
                           x, (const void*)tbl_h2, W1, b1, W2, b2, W3, b3, out, n);
    } else {
        hipLaunchKernelGGL((sdf_tcnn_fused<false>), grid, dim3(NTHREADS), 0, stream,
                           x, (const void*)table, W1, b1, W2, b2, W3, b3, out, n);
    }
}

// Round 6
// 679.184 us; speedup vs baseline: 1.1859x; 1.1859x over previous
//
#include <hip/hip_runtime.h>
#include <hip/hip_fp16.h>
#include <cstdint>

#define NTHREADS 256
#define TBL_SIZE (1u << 19)
#define HIDDEN 64
#define NLVL 16

struct Levels { float scale[16]; int res[16]; int dense[16]; };
constexpr Levels make_levels() {
    Levels L{};
    double s = 16.0;
    for (int l = 0; l < 16; ++l) {
        double sc = s - 1.0;
        L.scale[l] = (float)sc;
        int fi = (int)sc;
        int res = fi + (((double)fi < sc) ? 1 : 0) + 1;   // ceil(sc)+1
        L.res[l] = res;
        L.dense[l] = ((long long)res * res * res <= (long long)TBL_SIZE) ? 1 : 0;
        s *= 1.3819;
    }
    return L;
}
constexpr Levels LV = make_levels();

#define H16(M) M(0) M(1) M(2) M(3) M(4) M(5) M(6) M(7) \
               M(8) M(9) M(10) M(11) M(12) M(13) M(14) M(15)

// ---------- f32 table -> fp16 repack ----------
__global__ __launch_bounds__(256) void cvt_table(const float2* __restrict__ in,
                                                 __half2* __restrict__ out, int n) {
    for (int i = blockIdx.x * 256 + threadIdx.x; i < n; i += gridDim.x * 256) {
        const float2 v = in[i];
        out[i] = __floats2half2_rn(v.x, v.y);
    }
}

// ---------- Kernel A: LEVEL-PHASED encode ----------
// grid = NLVL * nb blocks, level-major: blocks [l*nb, (l+1)*nb) all process
// level l. Dispatch order round-robins consecutive blocks across XCDs, so at
// any moment each XCD works on ~one level whose 2MB fp16 table fits its 4MB
// L2 -> gathers become L2 hits instead of L3-recycled misses.
__global__ __launch_bounds__(NTHREADS, 8) void encode_phased(
    const float* __restrict__ x,
    const __half2* __restrict__ tbl,
    __half2* __restrict__ enc, int n, int nb)
{
    const int bid = blockIdx.x;
    const int lvl = bid / nb;                 // uniform per block
    const int pb  = bid - lvl * nb;
    const int i = pb * NTHREADS + threadIdx.x;
    if (i >= n) return;

    const float u = (x[3 * i + 0] + 1.0f) * 0.5f;
    const float v = (x[3 * i + 1] + 1.0f) * 0.5f;
    const float w = (x[3 * i + 2] + 1.0f) * 0.5f;

    const float sc = LV.scale[lvl];           // uniform scalar loads from .rodata
    const int res = LV.res[lvl];
    const int dense = LV.dense[lvl];

    const float pu = u * sc + 0.5f;
    const float pv = v * sc + 0.5f;
    const float pw = w * sc + 0.5f;
    const float fu = floorf(pu), fv = floorf(pv), fw = floorf(pw);
    const float wu = pu - fu, wv = pv - fv, ww = pw - fw;
    const int iu = (int)fu, iv = (int)fv, iw = (int)fw;

    int idx[8];
    if (dense) {                              // block-uniform branch
        #pragma unroll
        for (int b = 0; b < 8; ++b) {
            const int o0 = (b >> 2) & 1, o1 = (b >> 1) & 1, o2 = b & 1;
            idx[b] = (iu + o0) + (iv + o1) * res + (iw + o2) * (res * res);
        }
    } else {
        #pragma unroll
        for (int b = 0; b < 8; ++b) {
            const int o0 = (b >> 2) & 1, o1 = (b >> 1) & 1, o2 = b & 1;
            const uint32_t c0 = (uint32_t)(iu + o0);
            const uint32_t c1 = (uint32_t)(iv + o1);
            const uint32_t c2 = (uint32_t)(iw + o2);
            const uint32_t h = c0 ^ (c1 * 2654435761u) ^ (c2 * 805459861u);
            idx[b] = (int)(h & (TBL_SIZE - 1u));
        }
    }

    const __half2* tl = tbl + (size_t)lvl * TBL_SIZE;
    __half2 cfh[8];
    #pragma unroll
    for (int b = 0; b < 8; ++b) cfh[b] = tl[idx[b]];   // 8 gathers in flight

    float f0 = 0.0f, f1 = 0.0f;
    #pragma unroll
    for (int b = 0; b < 8; ++b) {
        const int o0 = (b >> 2) & 1, o1 = (b >> 1) & 1, o2 = b & 1;
        const float wt = (o0 ? wu : 1.0f - wu) *
                         (o1 ? wv : 1.0f - wv) *
                         (o2 ? ww : 1.0f - ww);
        const float2 cf = __half22float2(cfh[b]);
        f0 = fmaf(cf.x, wt, f0);
        f1 = fmaf(cf.y, wt, f1);
    }
    enc[(size_t)lvl * n + i] = __floats2half2_rn(f0, f1);  // coalesced 4B store
}

// ---------- Kernel B: MLP only (VALU-bound, coalesced feature reads) ----------
__global__ __launch_bounds__(NTHREADS, 4) void mlp_kernel(
    const __half2* __restrict__ enc,
    const float* __restrict__ W1, const float* __restrict__ b1,
    const float* __restrict__ W2, const float* __restrict__ b2,
    const float* __restrict__ W3, const float* __restrict__ b3,
    float* __restrict__ out, int n)
{
    const int i = blockIdx.x * NTHREADS + threadIdx.x;
    if (i >= n) return;

#define DECLH(m) float4 h##m = *(const float4*)&b1[4 * (m)];
    H16(DECLH)
#undef DECLH

    #pragma unroll
    for (int l = 0; l < NLVL; ++l) {
        const float2 f = __half22float2(enc[(size_t)l * n + i]);
        const float f0 = f.x, f1 = f.y;
        const float* wra = &W1[(2 * l) * HIDDEN];
        const float* wrb = &W1[(2 * l + 1) * HIDDEN];
#define UPDH(m) { \
        const float4 wa = *(const float4*)&wra[4 * (m)]; \
        const float4 wb = *(const float4*)&wrb[4 * (m)]; \
        h##m.x = fmaf(f0, wa.x, fmaf(f1, wb.x, h##m.x)); \
        h##m.y = fmaf(f0, wa.y, fmaf(f1, wb.y, h##m.y)); \
        h##m.z = fmaf(f0, wa.z, fmaf(f1, wb.z, h##m.z)); \
        h##m.w = fmaf(f0, wa.w, fmaf(f1, wb.w, h##m.w)); }
        H16(UPDH)
#undef UPDH
    }

#define RELUH(m) { h##m.x = fmaxf(h##m.x, 0.0f); h##m.y = fmaxf(h##m.y, 0.0f); \
                   h##m.z = fmaxf(h##m.z, 0.0f); h##m.w = fmaxf(h##m.w, 0.0f); }
    H16(RELUH)
#undef RELUH

    float acc = b3[0];
    #pragma unroll 2
    for (int jb = 0; jb < HIDDEN; jb += 4) {
        float4 t = *(const float4*)&b2[jb];
#define L2K(m) { \
        const float4 r0 = *(const float4*)&W2[(4 * (m) + 0) * HIDDEN + jb]; \
        const float4 r1 = *(const float4*)&W2[(4 * (m) + 1) * HIDDEN + jb]; \
        const float4 r2 = *(const float4*)&W2[(4 * (m) + 2) * HIDDEN + jb]; \
        const float4 r3 = *(const float4*)&W2[(4 * (m) + 3) * HIDDEN + jb]; \
        t.x = fmaf(h##m.x, r0.x, t.x); t.y = fmaf(h##m.x, r0.y, t.y); \
        t.z = fmaf(h##m.x, r0.z, t.z); t.w = fmaf(h##m.x, r0.w, t.w); \
        t.x = fmaf(h##m.y, r1.x, t.x); t.y = fmaf(h##m.y, r1.y, t.y); \
        t.z = fmaf(h##m.y, r1.z, t.z); t.w = fmaf(h##m.y, r1.w, t.w); \
        t.x = fmaf(h##m.z, r2.x, t.x); t.y = fmaf(h##m.z, r2.y, t.y); \
        t.z = fmaf(h##m.z, r2.z, t.z); t.w = fmaf(h##m.z, r2.w, t.w); \
        t.x = fmaf(h##m.w, r3.x, t.x); t.y = fmaf(h##m.w, r3.y, t.y); \
        t.z = fmaf(h##m.w, r3.z, t.z); t.w = fmaf(h##m.w, r3.w, t.w); }
        H16(L2K)
#undef L2K
        const float4 w3v = *(const float4*)&W3[jb];
        acc = fmaf(fmaxf(t.x, 0.0f), w3v.x, acc);
        acc = fmaf(fmaxf(t.y, 0.0f), w3v.y, acc);
        acc = fmaf(fmaxf(t.z, 0.0f), w3v.z, acc);
        acc = fmaf(fmaxf(t.w, 0.0f), w3v.w, acc);
    }

    out[i] = acc;
}

// ---------- Fallback: fused kernel (if ws too small for split) ----------
template <bool USE_H2>
__global__ __launch_bounds__(NTHREADS, 4) void sdf_tcnn_fused(
    const float* __restrict__ x,
    const void* __restrict__ tbl,
    const float* __restrict__ W1, const float* __restrict__ b1,
    const float* __restrict__ W2, const float* __restrict__ b2,
    const float* __restrict__ W3, const float* __restrict__ b3,
    float* __restrict__ out, int n)
{
    const int i = blockIdx.x * NTHREADS + threadIdx.x;
    if (i >= n) return;

    const float u = (x[3 * i + 0] + 1.0f) * 0.5f;
    const float v = (x[3 * i + 1] + 1.0f) * 0.5f;
    const float w = (x[3 * i + 2] + 1.0f) * 0.5f;

#define DECLH(m) float4 h##m = *(const float4*)&b1[4 * (m)];
    H16(DECLH)
#undef DECLH

    #pragma unroll
    for (int l = 0; l < NLVL; ++l) {
        const float sc = LV.scale[l];
        const int res = LV.res[l];
        const float pu = u * sc + 0.5f;
        const float pv = v * sc + 0.5f;
        const float pw = w * sc + 0.5f;
        const float fu = floorf(pu), fv = floorf(pv), fw = floorf(pw);
        const float wu = pu - fu, wv = pv - fv, ww = pw - fw;
        const int iu = (int)fu, iv = (int)fv, iw = (int)fw;

        int idx[8];
        #pragma unroll
        for (int b = 0; b < 8; ++b) {
            const int o0 = (b >> 2) & 1, o1 = (b >> 1) & 1, o2 = b & 1;
            if (LV.dense[l]) {
                idx[b] = (iu + o0) + (iv + o1) * res + (iw + o2) * (res * res);
            } else {
                const uint32_t c0 = (uint32_t)(iu + o0);
                const uint32_t c1 = (uint32_t)(iv + o1);
                const uint32_t c2 = (uint32_t)(iw + o2);
                const uint32_t h = c0 ^ (c1 * 2654435761u) ^ (c2 * 805459861u);
                idx[b] = (int)(h & (TBL_SIZE - 1u));
            }
        }

        float f0 = 0.0f, f1 = 0.0f;
        if constexpr (USE_H2) {
            const __half2* tl = (const __half2*)tbl + (size_t)l * TBL_SIZE;
            __half2 cfh[8];
            #pragma unroll
            for (int b = 0; b < 8; ++b) cfh[b] = tl[idx[b]];
            #pragma unroll
            for (int b = 0; b < 8; ++b) {
                const int o0 = (b >> 2) & 1, o1 = (b >> 1) & 1, o2 = b & 1;
                const float wt = (o0 ? wu : 1.0f - wu) *
                                 (o1 ? wv : 1.0f - wv) *
                                 (o2 ? ww : 1.0f - ww);
                const float2 cf = __half22float2(cfh[b]);
                f0 = fmaf(cf.x, wt, f0);
                f1 = fmaf(cf.y, wt, f1);
            }
        } else {
            const float2* tl = (const float2*)tbl + (size_t)l * TBL_SIZE;
            float2 cf[8];
            #pragma unroll
            for (int b = 0; b < 8; ++b) cf[b] = tl[idx[b]];
            #pragma unroll
            for (int b = 0; b < 8; ++b) {
                const int o0 = (b >> 2) & 1, o1 = (b >> 1) & 1, o2 = b & 1;
                const float wt = (o0 ? wu : 1.0f - wu) *
                                 (o1 ? wv : 1.0f - wv) *
                                 (o2 ? ww : 1.0f - ww);
                f0 = fmaf(cf[b].x, wt, f0);
                f1 = fmaf(cf[b].y, wt, f1);
            }
        }

        const float* wra = &W1[(2 * l) * HIDDEN];
        const float* wrb = &W1[(2 * l + 1) * HIDDEN];
#define UPDH(m) { \
        const float4 wa = *(const float4*)&wra[4 * (m)]; \
        const float4 wb = *(const float4*)&wrb[4 * (m)]; \
        h##m.x = fmaf(f0, wa.x, fmaf(f1, wb.x, h##m.x)); \
        h##m.y = fmaf(f0, wa.y, fmaf(f1, wb.y, h##m.y)); \
        h##m.z = fmaf(f0, wa.z, fmaf(f1, wb.z, h##m.z)); \
        h##m.w = fmaf(f0, wa.w, fmaf(f1, wb.w, h##m.w)); }
        H16(UPDH)
#undef UPDH
    }

#define RELUH(m) { h##m.x = fmaxf(h##m.x, 0.0f); h##m.y = fmaxf(h##m.y, 0.0f); \
                   h##m.z = fmaxf(h##m.z, 0.0f); h##m.w = fmaxf(h##m.w, 0.0f); }
    H16(RELUH)
#undef RELUH

    float acc = b3[0];
    #pragma unroll 2
    for (int jb = 0; jb < HIDDEN; jb += 4) {
        float4 t = *(const float4*)&b2[jb];
#define L2K(m) { \
        const float4 r0 = *(const float4*)&W2[(4 * (m) + 0) * HIDDEN + jb]; \
        const float4 r1 = *(const float4*)&W2[(4 * (m) + 1) * HIDDEN + jb]; \
        const float4 r2 = *(const float4*)&W2[(4 * (m) + 2) * HIDDEN + jb]; \
        const float4 r3 = *(const float4*)&W2[(4 * (m) + 3) * HIDDEN + jb]; \
        t.x = fmaf(h##m.x, r0.x, t.x); t.y = fmaf(h##m.x, r0.y, t.y); \
        t.z = fmaf(h##m.x, r0.z, t.z); t.w = fmaf(h##m.x, r0.w, t.w); \
        t.x = fmaf(h##m.y, r1.x, t.x); t.y = fmaf(h##m.y, r1.y, t.y); \
        t.z = fmaf(h##m.y, r1.z, t.z); t.w = fmaf(h##m.y, r1.w, t.w); \
        t.x = fmaf(h##m.z, r2.x, t.x); t.y = fmaf(h##m.z, r2.y, t.y); \
        t.z = fmaf(h##m.z, r2.z, t.z); t.w = fmaf(h##m.z, r2.w, t.w); \
        t.x = fmaf(h##m.w, r3.x, t.x); t.y = fmaf(h##m.w, r3.y, t.y); \
        t.z = fmaf(h##m.w, r3.z, t.z); t.w = fmaf(h##m.w, r3.w, t.w); }
        H16(L2K)
#undef L2K
        const float4 w3v = *(const float4*)&W3[jb];
        acc = fmaf(fmaxf(t.x, 0.0f), w3v.x, acc);
        acc = fmaf(fmaxf(t.y, 0.0f), w3v.y, acc);
        acc = fmaf(fmaxf(t.z, 0.0f), w3v.z, acc);
        acc = fmaf(fmaxf(t.w, 0.0f), w3v.w, acc);
    }

    out[i] = acc;
}

extern "C" void kernel_launch(void* const* d_in, const int* in_sizes, int n_in,
                              void* d_out, int out_size, void* d_ws, size_t ws_size,
                              hipStream_t stream) {
    const float* x     = (const float*)d_in[0];
    const float* table = (const float*)d_in[1];
    const float* W1    = (const float*)d_in[2];
    const float* b1    = (const float*)d_in[3];
    const float* W2    = (const float*)d_in[4];
    const float* b2    = (const float*)d_in[5];
    const float* W3    = (const float*)d_in[6];
    const float* b3    = (const float*)d_in[7];
    float* out = (float*)d_out;

    const int n = in_sizes[0] / 3;
    const int n_entries = NLVL * (int)TBL_SIZE;
    const size_t tbl_bytes = (size_t)n_entries * sizeof(__half2);        // 33.6 MB
    const size_t enc_bytes = (size_t)NLVL * (size_t)n * sizeof(__half2); // 64 MB
    const int nb = (n + NTHREADS - 1) / NTHREADS;
    dim3 grid(nb);

    if (ws_size >= tbl_bytes + enc_bytes) {
        __half2* tbl_h2 = (__half2*)d_ws;
        __half2* enc    = (__half2*)((char*)d_ws + tbl_bytes);
        hipLaunchKernelGGL(cvt_table, dim3(2048), dim3(256), 0, stream,
                           (const float2*)table, tbl_h2, n_entries);
        hipLaunchKernelGGL(encode_phased, dim3(nb * NLVL), dim3(NTHREADS), 0, stream,
                           x, tbl_h2, enc, n, nb);
        hipLaunchKernelGGL(mlp_kernel, grid, dim3(NTHREADS), 0, stream,
                           enc, W1, b1, W2, b2, W3, b3, out, n);
    } else if (ws_size >= tbl_bytes) {
        __half2* tbl_h2 = (__half2*)d_ws;
        hipLaunchKernelGGL(cvt_table, dim3(2048), dim3(256), 0, stream,
                           (const float2*)table, tbl_h2, n_entries);
        hipLaunchKernelGGL((sdf_tcnn_fused<true>), grid, dim3(NTHREADS), 0, stream,
                           x, (const void*)tbl_h2, W1, b1, W2, b2, W3, b3, out, n);
    } else {
        hipLaunchKernelGGL((sdf_tcnn_fused<false>), grid, dim3(NTHREADS), 0, stream,
                           x, (const void*)table, W1, b1, W2, b2, W3, b3, out, n);
    }
}

// Round 7
// 672.711 us; speedup vs baseline: 1.1973x; 1.0096x over previous
//
#include <hip/hip_runtime.h>
#include <hip/hip_fp16.h>
#include <cstdint>

#define NTHREADS 256
#define TBL_SIZE (1u << 19)
#define HIDDEN 64
#define NLVL 16
#define PPT 2   // points per thread in encode (MLP-latency hiding)

struct Levels { float scale[16]; int res[16]; int dense[16]; };
constexpr Levels make_levels() {
    Levels L{};
    double s = 16.0;
    for (int l = 0; l < 16; ++l) {
        double sc = s - 1.0;
        L.scale[l] = (float)sc;
        int fi = (int)sc;
        int res = fi + (((double)fi < sc) ? 1 : 0) + 1;   // ceil(sc)+1
        L.res[l] = res;
        L.dense[l] = ((long long)res * res * res <= (long long)TBL_SIZE) ? 1 : 0;
        s *= 1.3819;
    }
    return L;
}
constexpr Levels LV = make_levels();

#define H16(M) M(0) M(1) M(2) M(3) M(4) M(5) M(6) M(7) \
               M(8) M(9) M(10) M(11) M(12) M(13) M(14) M(15)

// ---------- f32 table -> fp16 repack ----------
__global__ __launch_bounds__(256) void cvt_table(const float2* __restrict__ in,
                                                 __half2* __restrict__ out, int n) {
    for (int i = blockIdx.x * 256 + threadIdx.x; i < n; i += gridDim.x * 256) {
        const float2 v = in[i];
        out[i] = __floats2half2_rn(v.x, v.y);
    }
}

// ---------- Kernel A: LEVEL-PHASED encode, 2 points/thread ----------
// Level-major block order keeps each XCD's L2 on ~one 2MB level table.
// 2 points/thread -> 16 gathers in flight per wave (~2x outstanding misses).
__global__ __launch_bounds__(NTHREADS, 8) void encode_phased(
    const float* __restrict__ x,
    const __half2* __restrict__ tbl,
    __half2* __restrict__ enc, int n, int nb)
{
    const int bid = blockIdx.x;
    const int lvl = bid / nb;                 // uniform per block
    const int pb  = bid - lvl * nb;
    const int i0 = pb * (NTHREADS * PPT) + threadIdx.x;
    const int i1 = i0 + NTHREADS;
    if (i0 >= n) return;

    const float sc = LV.scale[lvl];           // uniform scalar loads
    const int res = LV.res[lvl];
    const int dense = LV.dense[lvl];
    const __half2* tl = tbl + (size_t)lvl * TBL_SIZE;

    // ---- point 0 ----
    const float u0 = (x[3 * i0 + 0] + 1.0f) * 0.5f;
    const float v0 = (x[3 * i0 + 1] + 1.0f) * 0.5f;
    const float w0 = (x[3 * i0 + 2] + 1.0f) * 0.5f;
    const float pu0 = u0 * sc + 0.5f, pv0 = v0 * sc + 0.5f, pw0 = w0 * sc + 0.5f;
    const float fu0 = floorf(pu0), fv0 = floorf(pv0), fw0 = floorf(pw0);
    const float wu0 = pu0 - fu0, wv0 = pv0 - fv0, ww0 = pw0 - fw0;
    const int iu0 = (int)fu0, iv0 = (int)fv0, iw0 = (int)fw0;

    // ---- point 1 (may be out of range only in tail blocks) ----
    const bool has1 = (i1 < n);
    const int j1 = has1 ? i1 : i0;
    const float u1 = (x[3 * j1 + 0] + 1.0f) * 0.5f;
    const float v1 = (x[3 * j1 + 1] + 1.0f) * 0.5f;
    const float w1 = (x[3 * j1 + 2] + 1.0f) * 0.5f;
    const float pu1 = u1 * sc + 0.5f, pv1 = v1 * sc + 0.5f, pw1 = w1 * sc + 0.5f;
    const float fu1 = floorf(pu1), fv1 = floorf(pv1), fw1 = floorf(pw1);
    const float wu1 = pu1 - fu1, wv1 = pv1 - fv1, ww1 = pw1 - fw1;
    const int iu1 = (int)fu1, iv1 = (int)fv1, iw1 = (int)fw1;

    int idxA[8], idxB[8];
    if (dense) {                              // block-uniform branch
        #pragma unroll
        for (int b = 0; b < 8; ++b) {
            const int o0 = (b >> 2) & 1, o1 = (b >> 1) & 1, o2 = b & 1;
            idxA[b] = (iu0 + o0) + (iv0 + o1) * res + (iw0 + o2) * (res * res);
            idxB[b] = (iu1 + o0) + (iv1 + o1) * res + (iw1 + o2) * (res * res);
        }
    } else {
        #pragma unroll
        for (int b = 0; b < 8; ++b) {
            const int o0 = (b >> 2) & 1, o1 = (b >> 1) & 1, o2 = b & 1;
            const uint32_t hA = (uint32_t)(iu0 + o0)
                              ^ ((uint32_t)(iv0 + o1) * 2654435761u)
                              ^ ((uint32_t)(iw0 + o2) * 805459861u);
            const uint32_t hB = (uint32_t)(iu1 + o0)
                              ^ ((uint32_t)(iv1 + o1) * 2654435761u)
                              ^ ((uint32_t)(iw1 + o2) * 805459861u);
            idxA[b] = (int)(hA & (TBL_SIZE - 1u));
            idxB[b] = (int)(hB & (TBL_SIZE - 1u));
        }
    }

    // issue all 16 gathers back-to-back (16 outstanding per thread-pair)
    __half2 cfA[8], cfB[8];
    #pragma unroll
    for (int b = 0; b < 8; ++b) cfA[b] = tl[idxA[b]];
    #pragma unroll
    for (int b = 0; b < 8; ++b) cfB[b] = tl[idxB[b]];

    float a0 = 0.0f, a1 = 0.0f, b0 = 0.0f, b1f = 0.0f;
    #pragma unroll
    for (int b = 0; b < 8; ++b) {
        const int o0 = (b >> 2) & 1, o1 = (b >> 1) & 1, o2 = b & 1;
        const float wtA = (o0 ? wu0 : 1.0f - wu0) *
                          (o1 ? wv0 : 1.0f - wv0) *
                          (o2 ? ww0 : 1.0f - ww0);
        const float wtB = (o0 ? wu1 : 1.0f - wu1) *
                          (o1 ? wv1 : 1.0f - wv1) *
                          (o2 ? ww1 : 1.0f - ww1);
        const float2 cA = __half22float2(cfA[b]);
        const float2 cB = __half22float2(cfB[b]);
        a0 = fmaf(cA.x, wtA, a0);
        a1 = fmaf(cA.y, wtA, a1);
        b0 = fmaf(cB.x, wtB, b0);
        b1f = fmaf(cB.y, wtB, b1f);
    }
    enc[(size_t)lvl * n + i0] = __floats2half2_rn(a0, a1);
    if (has1) enc[(size_t)lvl * n + i1] = __floats2half2_rn(b0, b1f);
}

// ---------- Kernel B: MLP only (VALU-bound, coalesced feature reads) ----------
__global__ __launch_bounds__(NTHREADS, 4) void mlp_kernel(
    const __half2* __restrict__ enc,
    const float* __restrict__ W1, const float* __restrict__ b1,
    const float* __restrict__ W2, const float* __restrict__ b2,
    const float* __restrict__ W3, const float* __restrict__ b3,
    float* __restrict__ out, int n)
{
    const int i = blockIdx.x * NTHREADS + threadIdx.x;
    if (i >= n) return;

#define DECLH(m) float4 h##m = *(const float4*)&b1[4 * (m)];
    H16(DECLH)
#undef DECLH

    #pragma unroll
    for (int l = 0; l < NLVL; ++l) {
        const float2 f = __half22float2(enc[(size_t)l * n + i]);
        const float f0 = f.x, f1 = f.y;
        const float* wra = &W1[(2 * l) * HIDDEN];
        const float* wrb = &W1[(2 * l + 1) * HIDDEN];
#define UPDH(m) { \
        const float4 wa = *(const float4*)&wra[4 * (m)]; \
        const float4 wb = *(const float4*)&wrb[4 * (m)]; \
        h##m.x = fmaf(f0, wa.x, fmaf(f1, wb.x, h##m.x)); \
        h##m.y = fmaf(f0, wa.y, fmaf(f1, wb.y, h##m.y)); \
        h##m.z = fmaf(f0, wa.z, fmaf(f1, wb.z, h##m.z)); \
        h##m.w = fmaf(f0, wa.w, fmaf(f1, wb.w, h##m.w)); }
        H16(UPDH)
#undef UPDH
    }

#define RELUH(m) { h##m.x = fmaxf(h##m.x, 0.0f); h##m.y = fmaxf(h##m.y, 0.0f); \
                   h##m.z = fmaxf(h##m.z, 0.0f); h##m.w = fmaxf(h##m.w, 0.0f); }
    H16(RELUH)
#undef RELUH

    float acc = b3[0];
    #pragma unroll 2
    for (int jb = 0; jb < HIDDEN; jb += 4) {
        float4 t = *(const float4*)&b2[jb];
#define L2K(m) { \
        const float4 r0 = *(const float4*)&W2[(4 * (m) + 0) * HIDDEN + jb]; \
        const float4 r1 = *(const float4*)&W2[(4 * (m) + 1) * HIDDEN + jb]; \
        const float4 r2 = *(const float4*)&W2[(4 * (m) + 2) * HIDDEN + jb]; \
        const float4 r3 = *(const float4*)&W2[(4 * (m) + 3) * HIDDEN + jb]; \
        t.x = fmaf(h##m.x, r0.x, t.x); t.y = fmaf(h##m.x, r0.y, t.y); \
        t.z = fmaf(h##m.x, r0.z, t.z); t.w = fmaf(h##m.x, r0.w, t.w); \
        t.x = fmaf(h##m.y, r1.x, t.x); t.y = fmaf(h##m.y, r1.y, t.y); \
        t.z = fmaf(h##m.y, r1.z, t.z); t.w = fmaf(h##m.y, r1.w, t.w); \
        t.x = fmaf(h##m.z, r2.x, t.x); t.y = fmaf(h##m.z, r2.y, t.y); \
        t.z = fmaf(h##m.z, r2.z, t.z); t.w = fmaf(h##m.z, r2.w, t.w); \
        t.x = fmaf(h##m.w, r3.x, t.x); t.y = fmaf(h##m.w, r3.y, t.y); \
        t.z = fmaf(h##m.w, r3.z, t.z); t.w = fmaf(h##m.w, r3.w, t.w); }
        H16(L2K)
#undef L2K
        const float4 w3v = *(const float4*)&W3[jb];
        acc = fmaf(fmaxf(t.x, 0.0f), w3v.x, acc);
        acc = fmaf(fmaxf(t.y, 0.0f), w3v.y, acc);
        acc = fmaf(fmaxf(t.z, 0.0f), w3v.z, acc);
        acc = fmaf(fmaxf(t.w, 0.0f), w3v.w, acc);
    }

    out[i] = acc;
}

// ---------- Fallback: fused kernel (if ws too small for split) ----------
template <bool USE_H2>
__global__ __launch_bounds__(NTHREADS, 4) void sdf_tcnn_fused(
    const float* __restrict__ x,
    const void* __restrict__ tbl,
    const float* __restrict__ W1, const float* __restrict__ b1,
    const float* __restrict__ W2, const float* __restrict__ b2,
    const float* __restrict__ W3, const float* __restrict__ b3,
    float* __restrict__ out, int n)
{
    const int i = blockIdx.x * NTHREADS + threadIdx.x;
    if (i >= n) return;

    const float u = (x[3 * i + 0] + 1.0f) * 0.5f;
    const float v = (x[3 * i + 1] + 1.0f) * 0.5f;
    const float w = (x[3 * i + 2] + 1.0f) * 0.5f;

#define DECLH(m) float4 h##m = *(const float4*)&b1[4 * (m)];
    H16(DECLH)
#undef DECLH

    #pragma unroll
    for (int l = 0; l < NLVL; ++l) {
        const float sc = LV.scale[l];
        const int res = LV.res[l];
        const float pu = u * sc + 0.5f;
        const float pv = v * sc + 0.5f;
        const float pw = w * sc + 0.5f;
        const float fu = floorf(pu), fv = floorf(pv), fw = floorf(pw);
        const float wu = pu - fu, wv = pv - fv, ww = pw - fw;
        const int iu = (int)fu, iv = (int)fv, iw = (int)fw;

        int idx[8];
        #pragma unroll
        for (int b = 0; b < 8; ++b) {
            const int o0 = (b >> 2) & 1, o1 = (b >> 1) & 1, o2 = b & 1;
            if (LV.dense[l]) {
                idx[b] = (iu + o0) + (iv + o1) * res + (iw + o2) * (res * res);
            } else {
                const uint32_t c0 = (uint32_t)(iu + o0);
                const uint32_t c1 = (uint32_t)(iv + o1);
                const uint32_t c2 = (uint32_t)(iw + o2);
                const uint32_t h = c0 ^ (c1 * 2654435761u) ^ (c2 * 805459861u);
                idx[b] = (int)(h & (TBL_SIZE - 1u));
            }
        }

        float f0 = 0.0f, f1 = 0.0f;
        if constexpr (USE_H2) {
            const __half2* tl = (const __half2*)tbl + (size_t)l * TBL_SIZE;
            __half2 cfh[8];
            #pragma unroll
            for (int b = 0; b < 8; ++b) cfh[b] = tl[idx[b]];
            #pragma unroll
            for (int b = 0; b < 8; ++b) {
                const int o0 = (b >> 2) & 1, o1 = (b >> 1) & 1, o2 = b & 1;
                const float wt = (o0 ? wu : 1.0f - wu) *
                                 (o1 ? wv : 1.0f - wv) *
                                 (o2 ? ww : 1.0f - ww);
                const float2 cf = __half22float2(cfh[b]);
                f0 = fmaf(cf.x, wt, f0);
                f1 = fmaf(cf.y, wt, f1);
            }
        } else {
            const float2* tl = (const float2*)tbl + (size_t)l * TBL_SIZE;
            float2 cf[8];
            #pragma unroll
            for (int b = 0; b < 8; ++b) cf[b] = tl[idx[b]];
            #pragma unroll
            for (int b = 0; b < 8; ++b) {
                const int o0 = (b >> 2) & 1, o1 = (b >> 1) & 1, o2 = b & 1;
                const float wt = (o0 ? wu : 1.0f - wu) *
                                 (o1 ? wv : 1.0f - wv) *
                                 (o2 ? ww : 1.0f - ww);
                f0 = fmaf(cf[b].x, wt, f0);
                f1 = fmaf(cf[b].y, wt, f1);
            }
        }

        const float* wra = &W1[(2 * l) * HIDDEN];
        const float* wrb = &W1[(2 * l + 1) * HIDDEN];
#define UPDH(m) { \
        const float4 wa = *(const float4*)&wra[4 * (m)]; \
        const float4 wb = *(const float4*)&wrb[4 * (m)]; \
        h##m.x = fmaf(f0, wa.x, fmaf(f1, wb.x, h##m.x)); \
        h##m.y = fmaf(f0, wa.y, fmaf(f1, wb.y, h##m.y)); \
        h##m.z = fmaf(f0, wa.z, fmaf(f1, wb.z, h##m.z)); \
        h##m.w = fmaf(f0, wa.w, fmaf(f1, wb.w, h##m.w)); }
        H16(UPDH)
#undef UPDH
    }

#define RELUH(m) { h##m.x = fmaxf(h##m.x, 0.0f); h##m.y = fmaxf(h##m.y, 0.0f); \
                   h##m.z = fmaxf(h##m.z, 0.0f); h##m.w = fmaxf(h##m.w, 0.0f); }
    H16(RELUH)
#undef RELUH

    float acc = b3[0];
    #pragma unroll 2
    for (int jb = 0; jb < HIDDEN; jb += 4) {
        float4 t = *(const float4*)&b2[jb];
#define L2K(m) { \
        const float4 r0 = *(const float4*)&W2[(4 * (m) + 0) * HIDDEN + jb]; \
        const float4 r1 = *(const float4*)&W2[(4 * (m) + 1) * HIDDEN + jb]; \
        const float4 r2 = *(const float4*)&W2[(4 * (m) + 2) * HIDDEN + jb]; \
        const float4 r3 = *(const float4*)&W2[(4 * (m) + 3) * HIDDEN + jb]; \
        t.x = fmaf(h##m.x, r0.x, t.x); t.y = fmaf(h##m.x, r0.y, t.y); \
        t.z = fmaf(h##m.x, r0.z, t.z); t.w = fmaf(h##m.x, r0.w, t.w); \
        t.x = fmaf(h##m.y, r1.x, t.x); t.y = fmaf(h##m.y, r1.y, t.y); \
        t.z = fmaf(h##m.y, r1.z, t.z); t.w = fmaf(h##m.y, r1.w, t.w); \
        t.x = fmaf(h##m.z, r2.x, t.x); t.y = fmaf(h##m.z, r2.y, t.y); \
        t.z = fmaf(h##m.z, r2.z, t.z); t.w = fmaf(h##m.z, r2.w, t.w); \
        t.x = fmaf(h##m.w, r3.x, t.x); t.y = fmaf(h##m.w, r3.y, t.y); \
        t.z = fmaf(h##m.w, r3.z, t.z); t.w = fmaf(h##m.w, r3.w, t.w); }
        H16(L2K)
#undef L2K
        const float4 w3v = *(const float4*)&W3[jb];
        acc = fmaf(fmaxf(t.x, 0.0f), w3v.x, acc);
        acc = fmaf(fmaxf(t.y, 0.0f), w3v.y, acc);
        acc = fmaf(fmaxf(t.z, 0.0f), w3v.z, acc);
        acc = fmaf(fmaxf(t.w, 0.0f), w3v.w, acc);
    }

    out[i] = acc;
}

extern "C" void kernel_launch(void* const* d_in, const int* in_sizes, int n_in,
                              void* d_out, int out_size, void* d_ws, size_t ws_size,
                              hipStream_t stream) {
    const float* x     = (const float*)d_in[0];
    const float* table = (const float*)d_in[1];
    const float* W1    = (const float*)d_in[2];
    const float* b1    = (const float*)d_in[3];
    const float* W2    = (const float*)d_in[4];
    const float* b2    = (const float*)d_in[5];
    const float* W3    = (const float*)d_in[6];
    const float* b3    = (const float*)d_in[7];
    float* out = (float*)d_out;

    const int n = in_sizes[0] / 3;
    const int n_entries = NLVL * (int)TBL_SIZE;
    const size_t tbl_bytes = (size_t)n_entries * sizeof(__half2);        // 33.6 MB
    const size_t enc_bytes = (size_t)NLVL * (size_t)n * sizeof(__half2); // 64 MB
    const int nb_mlp = (n + NTHREADS - 1) / NTHREADS;
    const int nb_enc = (n + NTHREADS * PPT - 1) / (NTHREADS * PPT);

    if (ws_size >= tbl_bytes + enc_bytes) {
        __half2* tbl_h2 = (__half2*)d_ws;
        __half2* enc    = (__half2*)((char*)d_ws + tbl_bytes);
        hipLaunchKernelGGL(cvt_table, dim3(2048), dim3(256), 0, stream,
                           (const float2*)table, tbl_h2, n_entries);
        hipLaunchKernelGGL(encode_phased, dim3(nb_enc * NLVL), dim3(NTHREADS), 0, stream,
                           x, tbl_h2, enc, n, nb_enc);
        hipLaunchKernelGGL(mlp_kernel, dim3(nb_mlp), dim3(NTHREADS), 0, stream,
                           enc, W1, b1, W2, b2, W3, b3, out, n);
    } else if (ws_size >= tbl_bytes) {
        __half2* tbl_h2 = (__half2*)d_ws;
        hipLaunchKernelGGL(cvt_table, dim3(2048), dim3(256), 0, stream,
                           (const float2*)table, tbl_h2, n_entries);
        hipLaunchKernelGGL((sdf_tcnn_fused<true>), dim3(nb_mlp), dim3(NTHREADS), 0, stream,
                           x, (const void*)tbl_h2, W1, b1, W2, b2, W3, b3, out, n);
    } else {
        hipLaunchKernelGGL((sdf_tcnn_fused<false>), dim3(nb_mlp), dim3(NTHREADS), 0, stream,
                           x, (const void*)table, W1, b1, W2, b2, W3, b3, out, n);
    }
}

// Round 8
// 671.848 us; speedup vs baseline: 1.1989x; 1.0013x over previous
//
#include <hip/hip_runtime.h>
#include <hip/hip_fp16.h>
#include <cstdint>

#define NTHREADS 256
#define TBL_SIZE (1u << 19)
#define HIDDEN 64
#define NLVL 16
#define PPT 2   // points per thread in encode

struct Levels { float scale[16]; int res[16]; int dense[16]; };
constexpr Levels make_levels() {
    Levels L{};
    double s = 16.0;
    for (int l = 0; l < 16; ++l) {
        double sc = s - 1.0;
        L.scale[l] = (float)sc;
        int fi = (int)sc;
        int res = fi + (((double)fi < sc) ? 1 : 0) + 1;   // ceil(sc)+1
        L.res[l] = res;
        L.dense[l] = ((long long)res * res * res <= (long long)TBL_SIZE) ? 1 : 0;
        s *= 1.3819;
    }
    return L;
}
constexpr Levels LV = make_levels();

#define H16(M) M(0) M(1) M(2) M(3) M(4) M(5) M(6) M(7) \
               M(8) M(9) M(10) M(11) M(12) M(13) M(14) M(15)

// ---------- f32 table -> fp16 repack ----------
__global__ __launch_bounds__(256) void cvt_table(const float2* __restrict__ in,
                                                 __half2* __restrict__ out, int n) {
    for (int i = blockIdx.x * 256 + threadIdx.x; i < n; i += gridDim.x * 256) {
        const float2 v = in[i];
        out[i] = __floats2half2_rn(v.x, v.y);
    }
}

static __device__ __forceinline__ __half2 ld_nt(const __half2* p) {
    const uint32_t* pu = reinterpret_cast<const uint32_t*>(p);
    uint32_t a = __builtin_nontemporal_load(pu);
    union { uint32_t u; __half2 h; } c; c.u = a;
    return c.h;
}

// ---------- Kernel A: LEVEL-PHASED encode, 2 points/thread ----------
// Level-major block order keeps each XCD's L2 on ~one 2MB level table.
// Levels >= 4 have ~no L1 reuse per CU -> nontemporal loads bypass L1 and
// avoid the 64B-line-fill-per-4B-gather amplification.
__global__ __launch_bounds__(NTHREADS, 8) void encode_phased(
    const float* __restrict__ x,
    const __half2* __restrict__ tbl,
    __half2* __restrict__ enc, int n, int nb)
{
    const int bid = blockIdx.x;
    const int lvl = bid / nb;                 // uniform per block
    const int pb  = bid - lvl * nb;
    const int i0 = pb * (NTHREADS * PPT) + threadIdx.x;
    const int i1 = i0 + NTHREADS;
    if (i0 >= n) return;

    const float sc = LV.scale[lvl];           // uniform scalar loads
    const int res = LV.res[lvl];
    const int dense = LV.dense[lvl];
    const __half2* tl = tbl + (size_t)lvl * TBL_SIZE;

    // ---- point 0 ----
    const float u0 = (x[3 * i0 + 0] + 1.0f) * 0.5f;
    const float v0 = (x[3 * i0 + 1] + 1.0f) * 0.5f;
    const float w0 = (x[3 * i0 + 2] + 1.0f) * 0.5f;
    const float pu0 = u0 * sc + 0.5f, pv0 = v0 * sc + 0.5f, pw0 = w0 * sc + 0.5f;
    const float fu0 = floorf(pu0), fv0 = floorf(pv0), fw0 = floorf(pw0);
    const float wu0 = pu0 - fu0, wv0 = pv0 - fv0, ww0 = pw0 - fw0;
    const int iu0 = (int)fu0, iv0 = (int)fv0, iw0 = (int)fw0;

    // ---- point 1 (tail-guarded) ----
    const bool has1 = (i1 < n);
    const int j1 = has1 ? i1 : i0;
    const float u1 = (x[3 * j1 + 0] + 1.0f) * 0.5f;
    const float v1 = (x[3 * j1 + 1] + 1.0f) * 0.5f;
    const float w1 = (x[3 * j1 + 2] + 1.0f) * 0.5f;
    const float pu1 = u1 * sc + 0.5f, pv1 = v1 * sc + 0.5f, pw1 = w1 * sc + 0.5f;
    const float fu1 = floorf(pu1), fv1 = floorf(pv1), fw1 = floorf(pw1);
    const float wu1 = pu1 - fu1, wv1 = pv1 - fv1, ww1 = pw1 - fw1;
    const int iu1 = (int)fu1, iv1 = (int)fv1, iw1 = (int)fw1;

    int idxA[8], idxB[8];
    if (dense) {                              // block-uniform branch
        #pragma unroll
        for (int b = 0; b < 8; ++b) {
            const int o0 = (b >> 2) & 1, o1 = (b >> 1) & 1, o2 = b & 1;
            idxA[b] = (iu0 + o0) + (iv0 + o1) * res + (iw0 + o2) * (res * res);
            idxB[b] = (iu1 + o0) + (iv1 + o1) * res + (iw1 + o2) * (res * res);
        }
    } else {
        #pragma unroll
        for (int b = 0; b < 8; ++b) {
            const int o0 = (b >> 2) & 1, o1 = (b >> 1) & 1, o2 = b & 1;
            const uint32_t hA = (uint32_t)(iu0 + o0)
                              ^ ((uint32_t)(iv0 + o1) * 2654435761u)
                              ^ ((uint32_t)(iw0 + o2) * 805459861u);
            const uint32_t hB = (uint32_t)(iu1 + o0)
                              ^ ((uint32_t)(iv1 + o1) * 2654435761u)
                              ^ ((uint32_t)(iw1 + o2) * 805459861u);
            idxA[b] = (int)(hA & (TBL_SIZE - 1u));
            idxB[b] = (int)(hB & (TBL_SIZE - 1u));
        }
    }

    __half2 cfA[8], cfB[8];
    if (lvl >= 4) {
        // no-L1-reuse levels: bypass L1 (nt), serve straight from L2
        #pragma unroll
        for (int b = 0; b < 8; ++b) cfA[b] = ld_nt(&tl[idxA[b]]);
        #pragma unroll
        for (int b = 0; b < 8; ++b) cfB[b] = ld_nt(&tl[idxB[b]]);
    } else {
        // small dense tables: keep L1-cached loads
        #pragma unroll
        for (int b = 0; b < 8; ++b) cfA[b] = tl[idxA[b]];
        #pragma unroll
        for (int b = 0; b < 8; ++b) cfB[b] = tl[idxB[b]];
    }

    float a0 = 0.0f, a1 = 0.0f, b0 = 0.0f, b1f = 0.0f;
    #pragma unroll
    for (int b = 0; b < 8; ++b) {
        const int o0 = (b >> 2) & 1, o1 = (b >> 1) & 1, o2 = b & 1;
        const float wtA = (o0 ? wu0 : 1.0f - wu0) *
                          (o1 ? wv0 : 1.0f - wv0) *
                          (o2 ? ww0 : 1.0f - ww0);
        const float wtB = (o0 ? wu1 : 1.0f - wu1) *
                          (o1 ? wv1 : 1.0f - wv1) *
                          (o2 ? ww1 : 1.0f - ww1);
        const float2 cA = __half22float2(cfA[b]);
        const float2 cB = __half22float2(cfB[b]);
        a0 = fmaf(cA.x, wtA, a0);
        a1 = fmaf(cA.y, wtA, a1);
        b0 = fmaf(cB.x, wtB, b0);
        b1f = fmaf(cB.y, wtB, b1f);
    }
    enc[(size_t)lvl * n + i0] = __floats2half2_rn(a0, a1);
    if (has1) enc[(size_t)lvl * n + i1] = __floats2half2_rn(b0, b1f);
}

// ---------- Kernel B: MLP only (VALU-bound, coalesced feature reads) ----------
__global__ __launch_bounds__(NTHREADS, 4) void mlp_kernel(
    const __half2* __restrict__ enc,
    const float* __restrict__ W1, const float* __restrict__ b1,
    const float* __restrict__ W2, const float* __restrict__ b2,
    const float* __restrict__ W3, const float* __restrict__ b3,
    float* __restrict__ out, int n)
{
    const int i = blockIdx.x * NTHREADS + threadIdx.x;
    if (i >= n) return;

#define DECLH(m) float4 h##m = *(const float4*)&b1[4 * (m)];
    H16(DECLH)
#undef DECLH

    #pragma unroll
    for (int l = 0; l < NLVL; ++l) {
        const float2 f = __half22float2(enc[(size_t)l * n + i]);
        const float f0 = f.x, f1 = f.y;
        const float* wra = &W1[(2 * l) * HIDDEN];
        const float* wrb = &W1[(2 * l + 1) * HIDDEN];
#define UPDH(m) { \
        const float4 wa = *(const float4*)&wra[4 * (m)]; \
        const float4 wb = *(const float4*)&wrb[4 * (m)]; \
        h##m.x = fmaf(f0, wa.x, fmaf(f1, wb.x, h##m.x)); \
        h##m.y = fmaf(f0, wa.y, fmaf(f1, wb.y, h##m.y)); \
        h##m.z = fmaf(f0, wa.z, fmaf(f1, wb.z, h##m.z)); \
        h##m.w = fmaf(f0, wa.w, fmaf(f1, wb.w, h##m.w)); }
        H16(UPDH)
#undef UPDH
    }

#define RELUH(m) { h##m.x = fmaxf(h##m.x, 0.0f); h##m.y = fmaxf(h##m.y, 0.0f); \
                   h##m.z = fmaxf(h##m.z, 0.0f); h##m.w = fmaxf(h##m.w, 0.0f); }
    H16(RELUH)
#undef RELUH

    float acc = b3[0];
    #pragma unroll 2
    for (int jb = 0; jb < HIDDEN; jb += 4) {
        float4 t = *(const float4*)&b2[jb];
#define L2K(m) { \
        const float4 r0 = *(const float4*)&W2[(4 * (m) + 0) * HIDDEN + jb]; \
        const float4 r1 = *(const float4*)&W2[(4 * (m) + 1) * HIDDEN + jb]; \
        const float4 r2 = *(const float4*)&W2[(4 * (m) + 2) * HIDDEN + jb]; \
        const float4 r3 = *(const float4*)&W2[(4 * (m) + 3) * HIDDEN + jb]; \
        t.x = fmaf(h##m.x, r0.x, t.x); t.y = fmaf(h##m.x, r0.y, t.y); \
        t.z = fmaf(h##m.x, r0.z, t.z); t.w = fmaf(h##m.x, r0.w, t.w); \
        t.x = fmaf(h##m.y, r1.x, t.x); t.y = fmaf(h##m.y, r1.y, t.y); \
        t.z = fmaf(h##m.y, r1.z, t.z); t.w = fmaf(h##m.y, r1.w, t.w); \
        t.x = fmaf(h##m.z, r2.x, t.x); t.y = fmaf(h##m.z, r2.y, t.y); \
        t.z = fmaf(h##m.z, r2.z, t.z); t.w = fmaf(h##m.z, r2.w, t.w); \
        t.x = fmaf(h##m.w, r3.x, t.x); t.y = fmaf(h##m.w, r3.y, t.y); \
        t.z = fmaf(h##m.w, r3.z, t.z); t.w = fmaf(h##m.w, r3.w, t.w); }
        H16(L2K)
#undef L2K
        const float4 w3v = *(const float4*)&W3[jb];
        acc = fmaf(fmaxf(t.x, 0.0f), w3v.x, acc);
        acc = fmaf(fmaxf(t.y, 0.0f), w3v.y, acc);
        acc = fmaf(fmaxf(t.z, 0.0f), w3v.z, acc);
        acc = fmaf(fmaxf(t.w, 0.0f), w3v.w, acc);
    }

    out[i] = acc;
}

// ---------- Fallback: fused kernel (if ws too small for split) ----------
template <bool USE_H2>
__global__ __launch_bounds__(NTHREADS, 4) void sdf_tcnn_fused(
    const float* __restrict__ x,
    const void* __restrict__ tbl,
    const float* __restrict__ W1, const float* __restrict__ b1,
    const float* __restrict__ W2, const float* __restrict__ b2,
    const float* __restrict__ W3, const float* __restrict__ b3,
    float* __restrict__ out, int n)
{
    const int i = blockIdx.x * NTHREADS + threadIdx.x;
    if (i >= n) return;

    const float u = (x[3 * i + 0] + 1.0f) * 0.5f;
    const float v = (x[3 * i + 1] + 1.0f) * 0.5f;
    const float w = (x[3 * i + 2] + 1.0f) * 0.5f;

#define DECLH(m) float4 h##m = *(const float4*)&b1[4 * (m)];
    H16(DECLH)
#undef DECLH

    #pragma unroll
    for (int l = 0; l < NLVL; ++l) {
        const float sc = LV.scale[l];
        const int res = LV.res[l];
        const float pu = u * sc + 0.5f;
        const float pv = v * sc + 0.5f;
        const float pw = w * sc + 0.5f;
        const float fu = floorf(pu), fv = floorf(pv), fw = floorf(pw);
        const float wu = pu - fu, wv = pv - fv, ww = pw - fw;
        const int iu = (int)fu, iv = (int)fv, iw = (int)fw;

        int idx[8];
        #pragma unroll
        for (int b = 0; b < 8; ++b) {
            const int o0 = (b >> 2) & 1, o1 = (b >> 1) & 1, o2 = b & 1;
            if (LV.dense[l]) {
                idx[b] = (iu + o0) + (iv + o1) * res + (iw + o2) * (res * res);
            } else {
                const uint32_t c0 = (uint32_t)(iu + o0);
                const uint32_t c1 = (uint32_t)(iv + o1);
                const uint32_t c2 = (uint32_t)(iw + o2);
                const uint32_t h = c0 ^ (c1 * 2654435761u) ^ (c2 * 805459861u);
                idx[b] = (int)(h & (TBL_SIZE - 1u));
            }
        }

        float f0 = 0.0f, f1 = 0.0f;
        if constexpr (USE_H2) {
            const __half2* tl = (const __half2*)tbl + (size_t)l * TBL_SIZE;
            __half2 cfh[8];
            #pragma unroll
            for (int b = 0; b < 8; ++b) cfh[b] = tl[idx[b]];
            #pragma unroll
            for (int b = 0; b < 8; ++b) {
                const int o0 = (b >> 2) & 1, o1 = (b >> 1) & 1, o2 = b & 1;
                const float wt = (o0 ? wu : 1.0f - wu) *
                                 (o1 ? wv : 1.0f - wv) *
                                 (o2 ? ww : 1.0f - ww);
                const float2 cf = __half22float2(cfh[b]);
                f0 = fmaf(cf.x, wt, f0);
                f1 = fmaf(cf.y, wt, f1);
            }
        } else {
            const float2* tl = (const float2*)tbl + (size_t)l * TBL_SIZE;
            float2 cf[8];
            #pragma unroll
            for (int b = 0; b < 8; ++b) cf[b] = tl[idx[b]];
            #pragma unroll
            for (int b = 0; b < 8; ++b) {
                const int o0 = (b >> 2) & 1, o1 = (b >> 1) & 1, o2 = b & 1;
                const float wt = (o0 ? wu : 1.0f - wu) *
                                 (o1 ? wv : 1.0f - wv) *
                                 (o2 ? ww : 1.0f - ww);
                f0 = fmaf(cf[b].x, wt, f0);
                f1 = fmaf(cf[b].y, wt, f1);
            }
        }

        const float* wra = &W1[(2 * l) * HIDDEN];
        const float* wrb = &W1[(2 * l + 1) * HIDDEN];
#define UPDH(m) { \
        const float4 wa = *(const float4*)&wra[4 * (m)]; \
        const float4 wb = *(const float4*)&wrb[4 * (m)]; \
        h##m.x = fmaf(f0, wa.x, fmaf(f1, wb.x, h##m.x)); \
        h##m.y = fmaf(f0, wa.y, fmaf(f1, wb.y, h##m.y)); \
        h##m.z = fmaf(f0, wa.z, fmaf(f1, wb.z, h##m.z)); \
        h##m.w = fmaf(f0, wa.w, fmaf(f1, wb.w, h##m.w)); }
        H16(UPDH)
#undef UPDH
    }

#define RELUH(m) { h##m.x = fmaxf(h##m.x, 0.0f); h##m.y = fmaxf(h##m.y, 0.0f); \
                   h##m.z = fmaxf(h##m.z, 0.0f); h##m.w = fmaxf(h##m.w, 0.0f); }
    H16(RELUH)
#undef RELUH

    float acc = b3[0];
    #pragma unroll 2
    for (int jb = 0; jb < HIDDEN; jb += 4) {
        float4 t = *(const float4*)&b2[jb];
#define L2K(m) { \
        const float4 r0 = *(const float4*)&W2[(4 * (m) + 0) * HIDDEN + jb]; \
        const float4 r1 = *(const float4*)&W2[(4 * (m) + 1) * HIDDEN + jb]; \
        const float4 r2 = *(const float4*)&W2[(4 * (m) + 2) * HIDDEN + jb]; \
        const float4 r3 = *(const float4*)&W2[(4 * (m) + 3) * HIDDEN + jb]; \
        t.x = fmaf(h##m.x, r0.x, t.x); t.y = fmaf(h##m.x, r0.y, t.y); \
        t.z = fmaf(h##m.x, r0.z, t.z); t.w = fmaf(h##m.x, r0.w, t.w); \
        t.x = fmaf(h##m.y, r1.x, t.x); t.y = fmaf(h##m.y, r1.y, t.y); \
        t.z = fmaf(h##m.y, r1.z, t.z); t.w = fmaf(h##m.y, r1.w, t.w); \
        t.x = fmaf(h##m.z, r2.x, t.x); t.y = fmaf(h##m.z, r2.y, t.y); \
        t.z = fmaf(h##m.z, r2.z, t.z); t.w = fmaf(h##m.z, r2.w, t.w); \
        t.x = fmaf(h##m.w, r3.x, t.x); t.y = fmaf(h##m.w, r3.y, t.y); \
        t.z = fmaf(h##m.w, r3.z, t.z); t.w = fmaf(h##m.w, r3.w, t.w); }
        H16(L2K)
#undef L2K
        const float4 w3v = *(const float4*)&W3[jb];
        acc = fmaf(fmaxf(t.x, 0.0f), w3v.x, acc);
        acc = fmaf(fmaxf(t.y, 0.0f), w3v.y, acc);
        acc = fmaf(fmaxf(t.z, 0.0f), w3v.z, acc);
        acc = fmaf(fmaxf(t.w, 0.0f), w3v.w, acc);
    }

    out[i] = acc;
}

extern "C" void kernel_launch(void* const* d_in, const int* in_sizes, int n_in,
                              void* d_out, int out_size, void* d_ws, size_t ws_size,
                              hipStream_t stream) {
    const float* x     = (const float*)d_in[0];
    const float* table = (const float*)d_in[1];
    const float* W1    = (const float*)d_in[2];
    const float* b1    = (const float*)d_in[3];
    const float* W2    = (const float*)d_in[4];
    const float* b2    = (const float*)d_in[5];
    const float* W3    = (const float*)d_in[6];
    const float* b3    = (const float*)d_in[7];
    float* out = (float*)d_out;

    const int n = in_sizes[0] / 3;
    const int n_entries = NLVL * (int)TBL_SIZE;
    const size_t tbl_bytes = (size_t)n_entries * sizeof(__half2);        // 33.6 MB
    const size_t enc_bytes = (size_t)NLVL * (size_t)n * sizeof(__half2); // 64 MB
    const int nb_mlp = (n + NTHREADS - 1) / NTHREADS;
    const int nb_enc = (n + NTHREADS * PPT - 1) / (NTHREADS * PPT);

    if (ws_size >= tbl_bytes + enc_bytes) {
        __half2* tbl_h2 = (__half2*)d_ws;
        __half2* enc    = (__half2*)((char*)d_ws + tbl_bytes);
        hipLaunchKernelGGL(cvt_table, dim3(2048), dim3(256), 0, stream,
                           (const float2*)table, tbl_h2, n_entries);
        hipLaunchKernelGGL(encode_phased, dim3(nb_enc * NLVL), dim3(NTHREADS), 0, stream,
                           x, tbl_h2, enc, n, nb_enc);
        hipLaunchKernelGGL(mlp_kernel, dim3(nb_mlp), dim3(NTHREADS), 0, stream,
                           enc, W1, b1, W2, b2, W3, b3, out, n);
    } else if (ws_size >= tbl_bytes) {
        __half2* tbl_h2 = (__half2*)d_ws;
        hipLaunchKernelGGL(cvt_table, dim3(2048), dim3(256), 0, stream,
                           (const float2*)table, tbl_h2, n_entries);
        hipLaunchKernelGGL((sdf_tcnn_fused<true>), dim3(nb_mlp), dim3(NTHREADS), 0, stream,
                           x, (const void*)tbl_h2, W1, b1, W2, b2, W3, b3, out, n);
    } else {
        hipLaunchKernelGGL((sdf_tcnn_fused<false>), dim3(nb_mlp), dim3(NTHREADS), 0, stream,
                           x, (const void*)table, W1, b1, W2, b2, W3, b3, out, n);
    }
}

// Round 10
// 486.662 us; speedup vs baseline: 1.6551x; 1.3805x over previous
//
#include <hip/hip_runtime.h>
#include <hip/hip_fp16.h>
#include <cstdint>

#define NTHREADS 256
#define TBL_SIZE (1u << 19)
#define HIDDEN 64
#define NLVL 16
#define PPT 2   // points per thread in encode

struct Levels { float scale[16]; int res[16]; int dense[16]; };
constexpr Levels make_levels() {
    Levels L{};
    double s = 16.0;
    for (int l = 0; l < 16; ++l) {
        double sc = s - 1.0;
        L.scale[l] = (float)sc;
        int fi = (int)sc;
        int res = fi + (((double)fi < sc) ? 1 : 0) + 1;   // ceil(sc)+1
        L.res[l] = res;
        L.dense[l] = ((long long)res * res * res <= (long long)TBL_SIZE) ? 1 : 0;
        s *= 1.3819;
    }
    return L;
}
constexpr Levels LV = make_levels();

// pair-table offsets for dense levels (8B entries).
// Region size per dense level: res*(1+res+res^2)+2 — tcnn's unclamped dense
// indexing reads idx up to res(1+res+res^2) (corner coords can equal res),
// so res^3 is NOT enough (that was round-9's bug).
struct PairOffs { int off[17]; int total; };
constexpr PairOffs make_pairoffs() {
    PairOffs P{}; int o = 0;
    for (int l = 0; l < 16; ++l) {
        P.off[l] = o;
        if (LV.dense[l]) {
            const int r = LV.res[l];
            o += r * (1 + r + r * r) + 2;
        }
    }
    P.off[16] = o; P.total = o;
    return P;
}
constexpr PairOffs PO = make_pairoffs();

#define H16(M) M(0) M(1) M(2) M(3) M(4) M(5) M(6) M(7) \
               M(8) M(9) M(10) M(11) M(12) M(13) M(14) M(15)

static __device__ __forceinline__ __half2 u32_h2(uint32_t u) {
    union { uint32_t u; __half2 h; } c; c.u = u; return c.h;
}

// ---------- f32 table -> fp16 repack ----------
__global__ __launch_bounds__(256) void cvt_table(const float2* __restrict__ in,
                                                 __half2* __restrict__ out, int n) {
    for (int i = blockIdx.x * 256 + threadIdx.x; i < n; i += gridDim.x * 256) {
        const float2 v = in[i];
        out[i] = __floats2half2_rn(v.x, v.y);
    }
}

// ---------- dense-level pair table: dp[off+idx] = (h2[idx], h2[idx+1]) ----------
__global__ __launch_bounds__(256) void cvt_pairs(const __half2* __restrict__ h2,
                                                 unsigned long long* __restrict__ dp) {
    for (int i = blockIdx.x * 256 + threadIdx.x; i < PO.total; i += gridDim.x * 256) {
        int lvl = 0;
        #pragma unroll
        for (int l = 0; l < NLVL; ++l)
            if (LV.dense[l] && i >= PO.off[l] && i < PO.off[l + 1]) lvl = l;
        const int local = i - PO.off[lvl];
        // local+1 <= res(1+res+res^2)+2 << TBL_SIZE: always a valid table read
        const uint32_t a = *reinterpret_cast<const uint32_t*>(h2 + (size_t)lvl * TBL_SIZE + local);
        const uint32_t b = *reinterpret_cast<const uint32_t*>(h2 + (size_t)lvl * TBL_SIZE + local + 1);
        dp[i] = (unsigned long long)a | ((unsigned long long)b << 32);
    }
}

// gather one level for one point; returns (f0,f1).
// dense: 4x 8B pair loads. hash: iu even -> 4x 8B pair loads (h^1 trick,
// PRIMES[0]==1); iu odd -> 8x 4B loads.
static __device__ __forceinline__ float2 gather_level(
    const __half2* __restrict__ tl, const unsigned long long* __restrict__ dp,
    int dense, int res, int doff,
    int iu, int iv, int iw, float wu, float wv, float ww)
{
    float f0 = 0.0f, f1 = 0.0f;
    const float lx = 1.0f - wu;
    if (dense) {
        const int base = iu + iv * res + iw * res * res;
        #pragma unroll
        for (int b4 = 0; b4 < 4; ++b4) {
            const int o1 = (b4 >> 1) & 1, o2 = b4 & 1;
            const int idx = base + (o1 ? res : 0) + (o2 ? res * res : 0);
            const unsigned long long pr = dp[doff + idx];
            const float2 a = __half22float2(u32_h2((uint32_t)pr));
            const float2 b = __half22float2(u32_h2((uint32_t)(pr >> 32)));
            const float wyz = (o1 ? wv : 1.0f - wv) * (o2 ? ww : 1.0f - ww);
            f0 = fmaf(fmaf(lx, a.x, wu * b.x), wyz, f0);
            f1 = fmaf(fmaf(lx, a.y, wu * b.y), wyz, f1);
        }
    } else {
        const uint32_t r1a = (uint32_t)iv * 2654435761u;
        const uint32_t r1b = r1a + 2654435761u;
        const uint32_t r2a = (uint32_t)iw * 805459861u;
        const uint32_t r2b = r2a + 805459861u;
        if ((iu & 1) == 0) {
            // even iu: corners {h, h^1} = one aligned 8B pair per (o1,o2)
            #pragma unroll
            for (int b4 = 0; b4 < 4; ++b4) {
                const int o1 = (b4 >> 1) & 1, o2 = b4 & 1;
                const uint32_t rest = (o1 ? r1b : r1a) ^ (o2 ? r2b : r2a);
                const uint32_t h0 = ((uint32_t)iu ^ rest) & (TBL_SIZE - 1u);
                const unsigned long long pr =
                    *reinterpret_cast<const unsigned long long*>(tl + (h0 & ~1u));
                const uint32_t lo = (uint32_t)pr, hi = (uint32_t)(pr >> 32);
                const uint32_t sel = h0 & 1u;
                const float2 a = __half22float2(u32_h2(sel ? hi : lo)); // c0 (o0=0)
                const float2 b = __half22float2(u32_h2(sel ? lo : hi)); // c1 (o0=1)
                const float wyz = (o1 ? wv : 1.0f - wv) * (o2 ? ww : 1.0f - ww);
                f0 = fmaf(fmaf(lx, a.x, wu * b.x), wyz, f0);
                f1 = fmaf(fmaf(lx, a.y, wu * b.y), wyz, f1);
            }
        } else {
            #pragma unroll
            for (int b4 = 0; b4 < 4; ++b4) {
                const int o1 = (b4 >> 1) & 1, o2 = b4 & 1;
                const uint32_t rest = (o1 ? r1b : r1a) ^ (o2 ? r2b : r2a);
                const uint32_t h0 = ((uint32_t)iu ^ rest) & (TBL_SIZE - 1u);
                const uint32_t h1 = ((uint32_t)(iu + 1) ^ rest) & (TBL_SIZE - 1u);
                const float2 a = __half22float2(tl[h0]);
                const float2 b = __half22float2(tl[h1]);
                const float wyz = (o1 ? wv : 1.0f - wv) * (o2 ? ww : 1.0f - ww);
                f0 = fmaf(fmaf(lx, a.x, wu * b.x), wyz, f0);
                f1 = fmaf(fmaf(lx, a.y, wu * b.y), wyz, f1);
            }
        }
    }
    return make_float2(f0, f1);
}

// ---------- Kernel A: LEVEL-PHASED encode, 2 points/thread, paired gathers ----------
__global__ __launch_bounds__(NTHREADS, 8) void encode_phased(
    const float* __restrict__ x,
    const __half2* __restrict__ tbl,
    const unsigned long long* __restrict__ dpair,
    __half2* __restrict__ enc, int n, int nb)
{
    const int bid = blockIdx.x;
    const int lvl = bid / nb;                 // uniform per block
    const int pb  = bid - lvl * nb;
    const int i0 = pb * (NTHREADS * PPT) + threadIdx.x;
    const int i1 = i0 + NTHREADS;
    if (i0 >= n) return;

    const float sc = LV.scale[lvl];
    const int res = LV.res[lvl];
    const int dense = LV.dense[lvl];
    const int doff = PO.off[lvl];
    const __half2* tl = tbl + (size_t)lvl * TBL_SIZE;

    // ---- point 0 ----
    const float u0 = (x[3 * i0 + 0] + 1.0f) * 0.5f;
    const float v0 = (x[3 * i0 + 1] + 1.0f) * 0.5f;
    const float w0 = (x[3 * i0 + 2] + 1.0f) * 0.5f;
    const float pu0 = u0 * sc + 0.5f, pv0 = v0 * sc + 0.5f, pw0 = w0 * sc + 0.5f;
    const float fu0 = floorf(pu0), fv0 = floorf(pv0), fw0 = floorf(pw0);

    // ---- point 1 (tail-guarded) ----
    const bool has1 = (i1 < n);
    const int j1 = has1 ? i1 : i0;
    const float u1 = (x[3 * j1 + 0] + 1.0f) * 0.5f;
    const float v1 = (x[3 * j1 + 1] + 1.0f) * 0.5f;
    const float w1 = (x[3 * j1 + 2] + 1.0f) * 0.5f;
    const float pu1 = u1 * sc + 0.5f, pv1 = v1 * sc + 0.5f, pw1 = w1 * sc + 0.5f;
    const float fu1 = floorf(pu1), fv1 = floorf(pv1), fw1 = floorf(pw1);

    const float2 fA = gather_level(tl, dpair, dense, res, doff,
                                   (int)fu0, (int)fv0, (int)fw0,
                                   pu0 - fu0, pv0 - fv0, pw0 - fw0);
    const float2 fB = gather_level(tl, dpair, dense, res, doff,
                                   (int)fu1, (int)fv1, (int)fw1,
                                   pu1 - fu1, pv1 - fv1, pw1 - fw1);

    enc[(size_t)lvl * n + i0] = __floats2half2_rn(fA.x, fA.y);
    if (has1) enc[(size_t)lvl * n + i1] = __floats2half2_rn(fB.x, fB.y);
}

// ---------- Kernel B: MLP only (VALU-bound, coalesced feature reads) ----------
__global__ __launch_bounds__(NTHREADS, 4) void mlp_kernel(
    const __half2* __restrict__ enc,
    const float* __restrict__ W1, const float* __restrict__ b1,
    const float* __restrict__ W2, const float* __restrict__ b2,
    const float* __restrict__ W3, const float* __restrict__ b3,
    float* __restrict__ out, int n)
{
    const int i = blockIdx.x * NTHREADS + threadIdx.x;
    if (i >= n) return;

#define DECLH(m) float4 h##m = *(const float4*)&b1[4 * (m)];
    H16(DECLH)
#undef DECLH

    #pragma unroll
    for (int l = 0; l < NLVL; ++l) {
        const float2 f = __half22float2(enc[(size_t)l * n + i]);
        const float f0 = f.x, f1 = f.y;
        const float* wra = &W1[(2 * l) * HIDDEN];
        const float* wrb = &W1[(2 * l + 1) * HIDDEN];
#define UPDH(m) { \
        const float4 wa = *(const float4*)&wra[4 * (m)]; \
        const float4 wb = *(const float4*)&wrb[4 * (m)]; \
        h##m.x = fmaf(f0, wa.x, fmaf(f1, wb.x, h##m.x)); \
        h##m.y = fmaf(f0, wa.y, fmaf(f1, wb.y, h##m.y)); \
        h##m.z = fmaf(f0, wa.z, fmaf(f1, wb.z, h##m.z)); \
        h##m.w = fmaf(f0, wa.w, fmaf(f1, wb.w, h##m.w)); }
        H16(UPDH)
#undef UPDH
    }

#define RELUH(m) { h##m.x = fmaxf(h##m.x, 0.0f); h##m.y = fmaxf(h##m.y, 0.0f); \
                   h##m.z = fmaxf(h##m.z, 0.0f); h##m.w = fmaxf(h##m.w, 0.0f); }
    H16(RELUH)
#undef RELUH

    float acc = b3[0];
    #pragma unroll 2
    for (int jb = 0; jb < HIDDEN; jb += 4) {
        float4 t = *(const float4*)&b2[jb];
#define L2K(m) { \
        const float4 r0 = *(const float4*)&W2[(4 * (m) + 0) * HIDDEN + jb]; \
        const float4 r1 = *(const float4*)&W2[(4 * (m) + 1) * HIDDEN + jb]; \
        const float4 r2 = *(const float4*)&W2[(4 * (m) + 2) * HIDDEN + jb]; \
        const float4 r3 = *(const float4*)&W2[(4 * (m) + 3) * HIDDEN + jb]; \
        t.x = fmaf(h##m.x, r0.x, t.x); t.y = fmaf(h##m.x, r0.y, t.y); \
        t.z = fmaf(h##m.x, r0.z, t.z); t.w = fmaf(h##m.x, r0.w, t.w); \
        t.x = fmaf(h##m.y, r1.x, t.x); t.y = fmaf(h##m.y, r1.y, t.y); \
        t.z = fmaf(h##m.y, r1.z, t.z); t.w = fmaf(h##m.y, r1.w, t.w); \
        t.x = fmaf(h##m.z, r2.x, t.x); t.y = fmaf(h##m.z, r2.y, t.y); \
        t.z = fmaf(h##m.z, r2.z, t.z); t.w = fmaf(h##m.z, r2.w, t.w); \
        t.x = fmaf(h##m.w, r3.x, t.x); t.y = fmaf(h##m.w, r3.y, t.y); \
        t.z = fmaf(h##m.w, r3.z, t.z); t.w = fmaf(h##m.w, r3.w, t.w); }
        H16(L2K)
#undef L2K
        const float4 w3v = *(const float4*)&W3[jb];
        acc = fmaf(fmaxf(t.x, 0.0f), w3v.x, acc);
        acc = fmaf(fmaxf(t.y, 0.0f), w3v.y, acc);
        acc = fmaf(fmaxf(t.z, 0.0f), w3v.z, acc);
        acc = fmaf(fmaxf(t.w, 0.0f), w3v.w, acc);
    }

    out[i] = acc;
}

// ---------- Fallback: fused kernel (if ws too small for split) ----------
template <bool USE_H2>
__global__ __launch_bounds__(NTHREADS, 4) void sdf_tcnn_fused(
    const float* __restrict__ x,
    const void* __restrict__ tbl,
    const float* __restrict__ W1, const float* __restrict__ b1,
    const float* __restrict__ W2, const float* __restrict__ b2,
    const float* __restrict__ W3, const float* __restrict__ b3,
    float* __restrict__ out, int n)
{
    const int i = blockIdx.x * NTHREADS + threadIdx.x;
    if (i >= n) return;

    const float u = (x[3 * i + 0] + 1.0f) * 0.5f;
    const float v = (x[3 * i + 1] + 1.0f) * 0.5f;
    const float w = (x[3 * i + 2] + 1.0f) * 0.5f;

#define DECLH(m) float4 h##m = *(const float4*)&b1[4 * (m)];
    H16(DECLH)
#undef DECLH

    #pragma unroll
    for (int l = 0; l < NLVL; ++l) {
        const float sc = LV.scale[l];
        const int res = LV.res[l];
        const float pu = u * sc + 0.5f;
        const float pv = v * sc + 0.5f;
        const float pw = w * sc + 0.5f;
        const float fu = floorf(pu), fv = floorf(pv), fw = floorf(pw);
        const float wu = pu - fu, wv = pv - fv, ww = pw - fw;
        const int iu = (int)fu, iv = (int)fv, iw = (int)fw;

        int idx[8];
        #pragma unroll
        for (int b = 0; b < 8; ++b) {
            const int o0 = (b >> 2) & 1, o1 = (b >> 1) & 1, o2 = b & 1;
            if (LV.dense[l]) {
                idx[b] = (iu + o0) + (iv + o1) * res + (iw + o2) * (res * res);
            } else {
                const uint32_t c0 = (uint32_t)(iu + o0);
                const uint32_t c1 = (uint32_t)(iv + o1);
                const uint32_t c2 = (uint32_t)(iw + o2);
                const uint32_t h = c0 ^ (c1 * 2654435761u) ^ (c2 * 805459861u);
                idx[b] = (int)(h & (TBL_SIZE - 1u));
            }
        }

        float f0 = 0.0f, f1 = 0.0f;
        if constexpr (USE_H2) {
            const __half2* tl = (const __half2*)tbl + (size_t)l * TBL_SIZE;
            __half2 cfh[8];
            #pragma unroll
            for (int b = 0; b < 8; ++b) cfh[b] = tl[idx[b]];
            #pragma unroll
            for (int b = 0; b < 8; ++b) {
                const int o0 = (b >> 2) & 1, o1 = (b >> 1) & 1, o2 = b & 1;
                const float wt = (o0 ? wu : 1.0f - wu) *
                                 (o1 ? wv : 1.0f - wv) *
                                 (o2 ? ww : 1.0f - ww);
                const float2 cf = __half22float2(cfh[b]);
                f0 = fmaf(cf.x, wt, f0);
                f1 = fmaf(cf.y, wt, f1);
            }
        } else {
            const float2* tl = (const float2*)tbl + (size_t)l * TBL_SIZE;
            float2 cf[8];
            #pragma unroll
            for (int b = 0; b < 8; ++b) cf[b] = tl[idx[b]];
            #pragma unroll
            for (int b = 0; b < 8; ++b) {
                const int o0 = (b >> 2) & 1, o1 = (b >> 1) & 1, o2 = b & 1;
                const float wt = (o0 ? wu : 1.0f - wu) *
                                 (o1 ? wv : 1.0f - wv) *
                                 (o2 ? ww : 1.0f - ww);
                f0 = fmaf(cf[b].x, wt, f0);
                f1 = fmaf(cf[b].y, wt, f1);
            }
        }

        const float* wra = &W1[(2 * l) * HIDDEN];
        const float* wrb = &W1[(2 * l + 1) * HIDDEN];
#define UPDH(m) { \
        const float4 wa = *(const float4*)&wra[4 * (m)]; \
        const float4 wb = *(const float4*)&wrb[4 * (m)]; \
        h##m.x = fmaf(f0, wa.x, fmaf(f1, wb.x, h##m.x)); \
        h##m.y = fmaf(f0, wa.y, fmaf(f1, wb.y, h##m.y)); \
        h##m.z = fmaf(f0, wa.z, fmaf(f1, wb.z, h##m.z)); \
        h##m.w = fmaf(f0, wa.w, fmaf(f1, wb.w, h##m.w)); }
        H16(UPDH)
#undef UPDH
    }

#define RELUH(m) { h##m.x = fmaxf(h##m.x, 0.0f); h##m.y = fmaxf(h##m.y, 0.0f); \
                   h##m.z = fmaxf(h##m.z, 0.0f); h##m.w = fmaxf(h##m.w, 0.0f); }
    H16(RELUH)
#undef RELUH

    float acc = b3[0];
    #pragma unroll 2
    for (int jb = 0; jb < HIDDEN; jb += 4) {
        float4 t = *(const float4*)&b2[jb];
#define L2K(m) { \
        const float4 r0 = *(const float4*)&W2[(4 * (m) + 0) * HIDDEN + jb]; \
        const float4 r1 = *(const float4*)&W2[(4 * (m) + 1) * HIDDEN + jb]; \
        const float4 r2 = *(const float4*)&W2[(4 * (m) + 2) * HIDDEN + jb]; \
        const float4 r3 = *(const float4*)&W2[(4 * (m) + 3) * HIDDEN + jb]; \
        t.x = fmaf(h##m.x, r0.x, t.x); t.y = fmaf(h##m.x, r0.y, t.y); \
        t.z = fmaf(h##m.x, r0.z, t.z); t.w = fmaf(h##m.x, r0.w, t.w); \
        t.x = fmaf(h##m.y, r1.x, t.x); t.y = fmaf(h##m.y, r1.y, t.y); \
        t.z = fmaf(h##m.y, r1.z, t.z); t.w = fmaf(h##m.y, r1.w, t.w); \
        t.x = fmaf(h##m.z, r2.x, t.x); t.y = fmaf(h##m.z, r2.y, t.y); \
        t.z = fmaf(h##m.z, r2.z, t.z); t.w = fmaf(h##m.z, r2.w, t.w); \
        t.x = fmaf(h##m.w, r3.x, t.x); t.y = fmaf(h##m.w, r3.y, t.y); \
        t.z = fmaf(h##m.w, r3.z, t.z); t.w = fmaf(h##m.w, r3.w, t.w); }
        H16(L2K)
#undef L2K
        const float4 w3v = *(const float4*)&W3[jb];
        acc = fmaf(fmaxf(t.x, 0.0f), w3v.x, acc);
        acc = fmaf(fmaxf(t.y, 0.0f), w3v.y, acc);
        acc = fmaf(fmaxf(t.z, 0.0f), w3v.z, acc);
        acc = fmaf(fmaxf(t.w, 0.0f), w3v.w, acc);
    }

    out[i] = acc;
}

extern "C" void kernel_launch(void* const* d_in, const int* in_sizes, int n_in,
                              void* d_out, int out_size, void* d_ws, size_t ws_size,
                              hipStream_t stream) {
    const float* x     = (const float*)d_in[0];
    const float* table = (const float*)d_in[1];
    const float* W1    = (const float*)d_in[2];
    const float* b1    = (const float*)d_in[3];
    const float* W2    = (const float*)d_in[4];
    const float* b2    = (const float*)d_in[5];
    const float* W3    = (const float*)d_in[6];
    const float* b3    = (const float*)d_in[7];
    float* out = (float*)d_out;

    const int n = in_sizes[0] / 3;
    const int n_entries = NLVL * (int)TBL_SIZE;
    const size_t tbl_bytes  = (size_t)n_entries * sizeof(__half2);        // 33.6 MB
    const size_t pair_bytes = (size_t)PO.total * 8;                       // ~2.7 MB
    const size_t enc_bytes  = (size_t)NLVL * (size_t)n * sizeof(__half2); // 64 MB
    const int nb_mlp = (n + NTHREADS - 1) / NTHREADS;
    const int nb_enc = (n + NTHREADS * PPT - 1) / (NTHREADS * PPT);

    if (ws_size >= tbl_bytes + pair_bytes + enc_bytes) {
        __half2* tbl_h2 = (__half2*)d_ws;
        unsigned long long* dpair = (unsigned long long*)((char*)d_ws + tbl_bytes);
        __half2* enc = (__half2*)((char*)d_ws + tbl_bytes + pair_bytes);
        hipLaunchKernelGGL(cvt_table, dim3(2048), dim3(256), 0, stream,
                           (const float2*)table, tbl_h2, n_entries);
        hipLaunchKernelGGL(cvt_pairs, dim3((PO.total + 255) / 256), dim3(256), 0, stream,
                           tbl_h2, dpair);
        hipLaunchKernelGGL(encode_phased, dim3(nb_enc * NLVL), dim3(NTHREADS), 0, stream,
                           x, tbl_h2, dpair, enc, n, nb_enc);
        hipLaunchKernelGGL(mlp_kernel, dim3(nb_mlp), dim3(NTHREADS), 0, stream,
                           enc, W1, b1, W2, b2, W3, b3, out, n);
    } else if (ws_size >= tbl_bytes) {
        __half2* tbl_h2 = (__half2*)d_ws;
        hipLaunchKernelGGL(cvt_table, dim3(2048), dim3(256), 0, stream,
                           (const float2*)table, tbl_h2, n_entries);
        hipLaunchKernelGGL((sdf_tcnn_fused<true>), dim3(nb_mlp), dim3(NTHREADS), 0, stream,
                           x, (const void*)tbl_h2, W1, b1, W2, b2, W3, b3, out, n);
    } else {
        hipLaunchKernelGGL((sdf_tcnn_fused<false>), dim3(nb_mlp), dim3(NTHREADS), 0, stream,
                           x, (const void*)table, W1, b1, W2, b2, W3, b3, out, n);
    }
}

// Round 11
// 338.001 us; speedup vs baseline: 2.3830x; 1.4398x over previous
//
#include <hip/hip_runtime.h>
#include <hip/hip_fp16.h>
#include <cstdint>

#define NTHREADS 256
#define TBL_SIZE (1u << 19)
#define HIDDEN 64
#define NLVL 16
#define PPT 2   // points per thread in encode
#define ENC_SCALE 256.0f     // exact pow2: keeps fp16 enc/h1 in normal range for MFMA
#define ENC_INV (1.0f / 256.0f)

struct Levels { float scale[16]; int res[16]; int dense[16]; };
constexpr Levels make_levels() {
    Levels L{};
    double s = 16.0;
    for (int l = 0; l < 16; ++l) {
        double sc = s - 1.0;
        L.scale[l] = (float)sc;
        int fi = (int)sc;
        int res = fi + (((double)fi < sc) ? 1 : 0) + 1;   // ceil(sc)+1
        L.res[l] = res;
        L.dense[l] = ((long long)res * res * res <= (long long)TBL_SIZE) ? 1 : 0;
        s *= 1.3819;
    }
    return L;
}
constexpr Levels LV = make_levels();

// pair-table offsets for dense levels (8B entries); region covers tcnn's
// unclamped dense indexing up to res(1+res+res^2) (round-9 bugfix).
struct PairOffs { int off[17]; int total; };
constexpr PairOffs make_pairoffs() {
    PairOffs P{}; int o = 0;
    for (int l = 0; l < 16; ++l) {
        P.off[l] = o;
        if (LV.dense[l]) {
            const int r = LV.res[l];
            o += r * (1 + r + r * r) + 2;
        }
    }
    P.off[16] = o; P.total = o;
    return P;
}
constexpr PairOffs PO = make_pairoffs();

#define H16(M) M(0) M(1) M(2) M(3) M(4) M(5) M(6) M(7) \
               M(8) M(9) M(10) M(11) M(12) M(13) M(14) M(15)

typedef _Float16 f16x8 __attribute__((ext_vector_type(8)));
typedef float f32x4 __attribute__((ext_vector_type(4)));

static __device__ __forceinline__ __half2 u32_h2(uint32_t u) {
    union { uint32_t u; __half2 h; } c; c.u = u; return c.h;
}

// ---------- f32 table -> fp16 repack ----------
__global__ __launch_bounds__(256) void cvt_table(const float2* __restrict__ in,
                                                 __half2* __restrict__ out, int n) {
    for (int i = blockIdx.x * 256 + threadIdx.x; i < n; i += gridDim.x * 256) {
        const float2 v = in[i];
        out[i] = __floats2half2_rn(v.x, v.y);
    }
}

// ---------- dense-level pair table: dp[off+idx] = (h2[idx], h2[idx+1]) ----------
__global__ __launch_bounds__(256) void cvt_pairs(const __half2* __restrict__ h2,
                                                 unsigned long long* __restrict__ dp) {
    for (int i = blockIdx.x * 256 + threadIdx.x; i < PO.total; i += gridDim.x * 256) {
        int lvl = 0;
        #pragma unroll
        for (int l = 0; l < NLVL; ++l)
            if (LV.dense[l] && i >= PO.off[l] && i < PO.off[l + 1]) lvl = l;
        const int local = i - PO.off[lvl];
        const uint32_t a = *reinterpret_cast<const uint32_t*>(h2 + (size_t)lvl * TBL_SIZE + local);
        const uint32_t b = *reinterpret_cast<const uint32_t*>(h2 + (size_t)lvl * TBL_SIZE + local + 1);
        dp[i] = (unsigned long long)a | ((unsigned long long)b << 32);
    }
}

// ---------- W1^T / W2^T packed into exact MFMA A-fragment order (f16) ----------
// A-frag (16x16x32): lane holds row m=lane&15, k=(lane>>4)*8+j (j=0..7).
// w1f[((nt*64)+lane)*8+j]        = W1[k][16nt+m]
// w2f[(((nt*2)+kb)*64+lane)*8+j] = W2[32kb+k][16nt+m]
__global__ __launch_bounds__(256) void cvt_wfrags(const float* __restrict__ W1,
                                                  const float* __restrict__ W2,
                                                  __half* __restrict__ w1f,
                                                  __half* __restrict__ w2f) {
    const int t = blockIdx.x * 256 + threadIdx.x;
    for (int i = t; i < 4 * 64 * 8; i += gridDim.x * 256) {
        const int j = i & 7, lane = (i >> 3) & 63, nt = i >> 9;
        const int k = (lane >> 4) * 8 + j;
        const int o = (lane & 15) + 16 * nt;
        w1f[i] = __float2half(W1[k * HIDDEN + o]);
    }
    for (int i = t; i < 4 * 2 * 64 * 8; i += gridDim.x * 256) {
        const int j = i & 7, lane = (i >> 3) & 63, kb = (i >> 9) & 1, nt = i >> 10;
        const int k = 32 * kb + (lane >> 4) * 8 + j;
        const int o = (lane & 15) + 16 * nt;
        w2f[i] = __float2half(W2[k * HIDDEN + o]);
    }
}

// gather one level for one point; returns (f0,f1) UNSCALED.
static __device__ __forceinline__ float2 gather_level(
    const __half2* __restrict__ tl, const unsigned long long* __restrict__ dp,
    int dense, int res, int doff,
    int iu, int iv, int iw, float wu, float wv, float ww)
{
    float f0 = 0.0f, f1 = 0.0f;
    const float lx = 1.0f - wu;
    if (dense) {
        const int base = iu + iv * res + iw * res * res;
        #pragma unroll
        for (int b4 = 0; b4 < 4; ++b4) {
            const int o1 = (b4 >> 1) & 1, o2 = b4 & 1;
            const int idx = base + (o1 ? res : 0) + (o2 ? res * res : 0);
            const unsigned long long pr = dp[doff + idx];
            const float2 a = __half22float2(u32_h2((uint32_t)pr));
            const float2 b = __half22float2(u32_h2((uint32_t)(pr >> 32)));
            const float wyz = (o1 ? wv : 1.0f - wv) * (o2 ? ww : 1.0f - ww);
            f0 = fmaf(fmaf(lx, a.x, wu * b.x), wyz, f0);
            f1 = fmaf(fmaf(lx, a.y, wu * b.y), wyz, f1);
        }
    } else {
        const uint32_t r1a = (uint32_t)iv * 2654435761u;
        const uint32_t r1b = r1a + 2654435761u;
        const uint32_t r2a = (uint32_t)iw * 805459861u;
        const uint32_t r2b = r2a + 805459861u;
        if ((iu & 1) == 0) {
            #pragma unroll
            for (int b4 = 0; b4 < 4; ++b4) {
                const int o1 = (b4 >> 1) & 1, o2 = b4 & 1;
                const uint32_t rest = (o1 ? r1b : r1a) ^ (o2 ? r2b : r2a);
                const uint32_t h0 = ((uint32_t)iu ^ rest) & (TBL_SIZE - 1u);
                const unsigned long long pr =
                    *reinterpret_cast<const unsigned long long*>(tl + (h0 & ~1u));
                const uint32_t lo = (uint32_t)pr, hi = (uint32_t)(pr >> 32);
                const uint32_t sel = h0 & 1u;
                const float2 a = __half22float2(u32_h2(sel ? hi : lo)); // c0
                const float2 b = __half22float2(u32_h2(sel ? lo : hi)); // c1
                const float wyz = (o1 ? wv : 1.0f - wv) * (o2 ? ww : 1.0f - ww);
                f0 = fmaf(fmaf(lx, a.x, wu * b.x), wyz, f0);
                f1 = fmaf(fmaf(lx, a.y, wu * b.y), wyz, f1);
            }
        } else {
            #pragma unroll
            for (int b4 = 0; b4 < 4; ++b4) {
                const int o1 = (b4 >> 1) & 1, o2 = b4 & 1;
                const uint32_t rest = (o1 ? r1b : r1a) ^ (o2 ? r2b : r2a);
                const uint32_t h0 = ((uint32_t)iu ^ rest) & (TBL_SIZE - 1u);
                const uint32_t h1 = ((uint32_t)(iu + 1) ^ rest) & (TBL_SIZE - 1u);
                const float2 a = __half22float2(tl[h0]);
                const float2 b = __half22float2(tl[h1]);
                const float wyz = (o1 ? wv : 1.0f - wv) * (o2 ? ww : 1.0f - ww);
                f0 = fmaf(fmaf(lx, a.x, wu * b.x), wyz, f0);
                f1 = fmaf(fmaf(lx, a.y, wu * b.y), wyz, f1);
            }
        }
    }
    return make_float2(f0, f1);
}

// ---------- Kernel A: LEVEL-PHASED encode (enc stored x256) ----------
__global__ __launch_bounds__(NTHREADS, 8) void encode_phased(
    const float* __restrict__ x,
    const __half2* __restrict__ tbl,
    const unsigned long long* __restrict__ dpair,
    __half2* __restrict__ enc, int n, int nb)
{
    const int bid = blockIdx.x;
    const int lvl = bid / nb;
    const int pb  = bid - lvl * nb;
    const int i0 = pb * (NTHREADS * PPT) + threadIdx.x;
    const int i1 = i0 + NTHREADS;
    if (i0 >= n) return;

    const float sc = LV.scale[lvl];
    const int res = LV.res[lvl];
    const int dense = LV.dense[lvl];
    const int doff = PO.off[lvl];
    const __half2* tl = tbl + (size_t)lvl * TBL_SIZE;

    const float u0 = (x[3 * i0 + 0] + 1.0f) * 0.5f;
    const float v0 = (x[3 * i0 + 1] + 1.0f) * 0.5f;
    const float w0 = (x[3 * i0 + 2] + 1.0f) * 0.5f;
    const float pu0 = u0 * sc + 0.5f, pv0 = v0 * sc + 0.5f, pw0 = w0 * sc + 0.5f;
    const float fu0 = floorf(pu0), fv0 = floorf(pv0), fw0 = floorf(pw0);

    const bool has1 = (i1 < n);
    const int j1 = has1 ? i1 : i0;
    const float u1 = (x[3 * j1 + 0] + 1.0f) * 0.5f;
    const float v1 = (x[3 * j1 + 1] + 1.0f) * 0.5f;
    const float w1 = (x[3 * j1 + 2] + 1.0f) * 0.5f;
    const float pu1 = u1 * sc + 0.5f, pv1 = v1 * sc + 0.5f, pw1 = w1 * sc + 0.5f;
    const float fu1 = floorf(pu1), fv1 = floorf(pv1), fw1 = floorf(pw1);

    const float2 fA = gather_level(tl, dpair, dense, res, doff,
                                   (int)fu0, (int)fv0, (int)fw0,
                                   pu0 - fu0, pv0 - fv0, pw0 - fw0);
    const float2 fB = gather_level(tl, dpair, dense, res, doff,
                                   (int)fu1, (int)fv1, (int)fw1,
                                   pu1 - fu1, pv1 - fv1, pw1 - fw1);

    enc[(size_t)lvl * n + i0] = __floats2half2_rn(fA.x * ENC_SCALE, fA.y * ENC_SCALE);
    if (has1) enc[(size_t)lvl * n + i1] = __floats2half2_rn(fB.x * ENC_SCALE, fB.y * ENC_SCALE);
}

// ---------- Kernel B: MFMA MLP (transposed: h^T = W^T @ enc^T) ----------
// 1 wave = 16 points. Layer1: 4x mfma_f32_16x16x32_f16 (K=32).
// Layer2: LDS turnaround ([64][18] f16, wave-private) + 8x mfma (K=64).
// Layer3: VALU dot + shfl_xor reduce. All biases x256; output /256.
__global__ __launch_bounds__(256) void mlp_mfma(
    const __half2* __restrict__ enc,
    const __half* __restrict__ w1f, const __half* __restrict__ w2f,
    const float* __restrict__ b1, const float* __restrict__ b2,
    const float* __restrict__ W3, const float* __restrict__ b3,
    float* __restrict__ out, int n)
{
    __shared__ __half lds_h1[4][64][18];
    const int wid  = threadIdx.x >> 6;
    const int lane = threadIdx.x & 63;
    const int tile = blockIdx.x * 4 + wid;
    const int pt = lane & 15;        // point column within tile
    const int qw = lane >> 4;        // quarter-wave
    const int i = tile * 16 + pt;

    // enc B-frag: k=(qw*8+j) -> levels qw*4..+3, point i (coalesced 4B loads)
    union { uint32_t u[4]; f16x8 v; } bf;
    #pragma unroll
    for (int jj = 0; jj < 4; ++jj)
        bf.u[jj] = *reinterpret_cast<const uint32_t*>(&enc[(size_t)(qw * 4 + jj) * n + i]);

    // ---- layer 1 ----
    f32x4 c1[4];
    #pragma unroll
    for (int nt = 0; nt < 4; ++nt) {
        const float4 bb = *(const float4*)&b1[16 * nt + qw * 4];
        c1[nt][0] = bb.x * ENC_SCALE; c1[nt][1] = bb.y * ENC_SCALE;
        c1[nt][2] = bb.z * ENC_SCALE; c1[nt][3] = bb.w * ENC_SCALE;
        const f16x8 a = *reinterpret_cast<const f16x8*>(&w1f[(nt * 64 + lane) * 8]);
        c1[nt] = __builtin_amdgcn_mfma_f32_16x16x32_f16(a, bf.v, c1[nt], 0, 0, 0);
    }

    // relu -> f16 -> LDS h1^T[k][pt]  (k = layer-2 reduction index)
    #pragma unroll
    for (int nt = 0; nt < 4; ++nt) {
        #pragma unroll
        for (int r = 0; r < 4; ++r) {
            const int o = 16 * nt + qw * 4 + r;
            lds_h1[wid][o][pt] = __float2half(fmaxf(c1[nt][r], 0.0f));
        }
    }

    // ---- layer 2 ----
    f32x4 c2[4];
    #pragma unroll
    for (int nt = 0; nt < 4; ++nt) {
        const float4 bb = *(const float4*)&b2[16 * nt + qw * 4];
        c2[nt][0] = bb.x * ENC_SCALE; c2[nt][1] = bb.y * ENC_SCALE;
        c2[nt][2] = bb.z * ENC_SCALE; c2[nt][3] = bb.w * ENC_SCALE;
    }
    #pragma unroll
    for (int kb = 0; kb < 2; ++kb) {
        union { uint32_t u[4]; f16x8 v; } hb;
        #pragma unroll
        for (int j2 = 0; j2 < 4; ++j2) {
            const int k0 = kb * 32 + qw * 8 + 2 * j2;
            const uint32_t lo = __half_as_ushort(lds_h1[wid][k0][pt]);
            const uint32_t hi = __half_as_ushort(lds_h1[wid][k0 + 1][pt]);
            hb.u[j2] = lo | (hi << 16);
        }
        #pragma unroll
        for (int nt = 0; nt < 4; ++nt) {
            const f16x8 a = *reinterpret_cast<const f16x8*>(&w2f[((nt * 2 + kb) * 64 + lane) * 8]);
            c2[nt] = __builtin_amdgcn_mfma_f32_16x16x32_f16(a, hb.v, c2[nt], 0, 0, 0);
        }
    }

    // ---- layer 3 ----
    float part = 0.0f;
    #pragma unroll
    for (int nt = 0; nt < 4; ++nt) {
        const float4 w3v = *(const float4*)&W3[16 * nt + qw * 4];
        part = fmaf(fmaxf(c2[nt][0], 0.0f), w3v.x, part);
        part = fmaf(fmaxf(c2[nt][1], 0.0f), w3v.y, part);
        part = fmaf(fmaxf(c2[nt][2], 0.0f), w3v.z, part);
        part = fmaf(fmaxf(c2[nt][3], 0.0f), w3v.w, part);
    }
    part += __shfl_xor(part, 16, 64);
    part += __shfl_xor(part, 32, 64);
    if (lane < 16) out[i] = part * ENC_INV + b3[0];
}

// ---------- Fallback VALU MLP (enc stored x256 -> rescale on read) ----------
__global__ __launch_bounds__(NTHREADS, 4) void mlp_kernel(
    const __half2* __restrict__ enc,
    const float* __restrict__ W1, const float* __restrict__ b1,
    const float* __restrict__ W2, const float* __restrict__ b2,
    const float* __restrict__ W3, const float* __restrict__ b3,
    float* __restrict__ out, int n)
{
    const int i = blockIdx.x * NTHREADS + threadIdx.x;
    if (i >= n) return;

#define DECLH(m) float4 h##m = *(const float4*)&b1[4 * (m)];
    H16(DECLH)
#undef DECLH

    #pragma unroll
    for (int l = 0; l < NLVL; ++l) {
        const float2 f = __half22float2(enc[(size_t)l * n + i]);
        const float f0 = f.x * ENC_INV, f1 = f.y * ENC_INV;
        const float* wra = &W1[(2 * l) * HIDDEN];
        const float* wrb = &W1[(2 * l + 1) * HIDDEN];
#define UPDH(m) { \
        const float4 wa = *(const float4*)&wra[4 * (m)]; \
        const float4 wb = *(const float4*)&wrb[4 * (m)]; \
        h##m.x = fmaf(f0, wa.x, fmaf(f1, wb.x, h##m.x)); \
        h##m.y = fmaf(f0, wa.y, fmaf(f1, wb.y, h##m.y)); \
        h##m.z = fmaf(f0, wa.z, fmaf(f1, wb.z, h##m.z)); \
        h##m.w = fmaf(f0, wa.w, fmaf(f1, wb.w, h##m.w)); }
        H16(UPDH)
#undef UPDH
    }

#define RELUH(m) { h##m.x = fmaxf(h##m.x, 0.0f); h##m.y = fmaxf(h##m.y, 0.0f); \
                   h##m.z = fmaxf(h##m.z, 0.0f); h##m.w = fmaxf(h##m.w, 0.0f); }
    H16(RELUH)
#undef RELUH

    float acc = b3[0];
    #pragma unroll 2
    for (int jb = 0; jb < HIDDEN; jb += 4) {
        float4 t = *(const float4*)&b2[jb];
#define L2K(m) { \
        const float4 r0 = *(const float4*)&W2[(4 * (m) + 0) * HIDDEN + jb]; \
        const float4 r1 = *(const float4*)&W2[(4 * (m) + 1) * HIDDEN + jb]; \
        const float4 r2 = *(const float4*)&W2[(4 * (m) + 2) * HIDDEN + jb]; \
        const float4 r3 = *(const float4*)&W2[(4 * (m) + 3) * HIDDEN + jb]; \
        t.x = fmaf(h##m.x, r0.x, t.x); t.y = fmaf(h##m.x, r0.y, t.y); \
        t.z = fmaf(h##m.x, r0.z, t.z); t.w = fmaf(h##m.x, r0.w, t.w); \
        t.x = fmaf(h##m.y, r1.x, t.x); t.y = fmaf(h##m.y, r1.y, t.y); \
        t.z = fmaf(h##m.y, r1.z, t.z); t.w = fmaf(h##m.y, r1.w, t.w); \
        t.x = fmaf(h##m.z, r2.x, t.x); t.y = fmaf(h##m.z, r2.y, t.y); \
        t.z = fmaf(h##m.z, r2.z, t.z); t.w = fmaf(h##m.z, r2.w, t.w); \
        t.x = fmaf(h##m.w, r3.x, t.x); t.y = fmaf(h##m.w, r3.y, t.y); \
        t.z = fmaf(h##m.w, r3.z, t.z); t.w = fmaf(h##m.w, r3.w, t.w); }
        H16(L2K)
#undef L2K
        const float4 w3v = *(const float4*)&W3[jb];
        acc = fmaf(fmaxf(t.x, 0.0f), w3v.x, acc);
        acc = fmaf(fmaxf(t.y, 0.0f), w3v.y, acc);
        acc = fmaf(fmaxf(t.z, 0.0f), w3v.z, acc);
        acc = fmaf(fmaxf(t.w, 0.0f), w3v.w, acc);
    }

    out[i] = acc;
}

// ---------- Fallback: fused kernel (if ws too small for split) ----------
template <bool USE_H2>
__global__ __launch_bounds__(NTHREADS, 4) void sdf_tcnn_fused(
    const float* __restrict__ x,
    const void* __restrict__ tbl,
    const float* __restrict__ W1, const float* __restrict__ b1,
    const float* __restrict__ W2, const float* __restrict__ b2,
    const float* __restrict__ W3, const float* __restrict__ b3,
    float* __restrict__ out, int n)
{
    const int i = blockIdx.x * NTHREADS + threadIdx.x;
    if (i >= n) return;

    const float u = (x[3 * i + 0] + 1.0f) * 0.5f;
    const float v = (x[3 * i + 1] + 1.0f) * 0.5f;
    const float w = (x[3 * i + 2] + 1.0f) * 0.5f;

#define DECLH(m) float4 h##m = *(const float4*)&b1[4 * (m)];
    H16(DECLH)
#undef DECLH

    #pragma unroll
    for (int l = 0; l < NLVL; ++l) {
        const float sc = LV.scale[l];
        const int res = LV.res[l];
        const float pu = u * sc + 0.5f;
        const float pv = v * sc + 0.5f;
        const float pw = w * sc + 0.5f;
        const float fu = floorf(pu), fv = floorf(pv), fw = floorf(pw);
        const float wu = pu - fu, wv = pv - fv, ww = pw - fw;
        const int iu = (int)fu, iv = (int)fv, iw = (int)fw;

        int idx[8];
        #pragma unroll
        for (int b = 0; b < 8; ++b) {
            const int o0 = (b >> 2) & 1, o1 = (b >> 1) & 1, o2 = b & 1;
            if (LV.dense[l]) {
                idx[b] = (iu + o0) + (iv + o1) * res + (iw + o2) * (res * res);
            } else {
                const uint32_t c0 = (uint32_t)(iu + o0);
                const uint32_t c1 = (uint32_t)(iv + o1);
                const uint32_t c2 = (uint32_t)(iw + o2);
                const uint32_t h = c0 ^ (c1 * 2654435761u) ^ (c2 * 805459861u);
                idx[b] = (int)(h & (TBL_SIZE - 1u));
            }
        }

        float f0 = 0.0f, f1 = 0.0f;
        if constexpr (USE_H2) {
            const __half2* tl = (const __half2*)tbl + (size_t)l * TBL_SIZE;
            __half2 cfh[8];
            #pragma unroll
            for (int b = 0; b < 8; ++b) cfh[b] = tl[idx[b]];
            #pragma unroll
            for (int b = 0; b < 8; ++b) {
                const int o0 = (b >> 2) & 1, o1 = (b >> 1) & 1, o2 = b & 1;
                const float wt = (o0 ? wu : 1.0f - wu) *
                                 (o1 ? wv : 1.0f - wv) *
                                 (o2 ? ww : 1.0f - ww);
                const float2 cf = __half22float2(cfh[b]);
                f0 = fmaf(cf.x, wt, f0);
                f1 = fmaf(cf.y, wt, f1);
            }
        } else {
            const float2* tl = (const float2*)tbl + (size_t)l * TBL_SIZE;
            float2 cf[8];
            #pragma unroll
            for (int b = 0; b < 8; ++b) cf[b] = tl[idx[b]];
            #pragma unroll
            for (int b = 0; b < 8; ++b) {
                const int o0 = (b >> 2) & 1, o1 = (b >> 1) & 1, o2 = b & 1;
                const float wt = (o0 ? wu : 1.0f - wu) *
                                 (o1 ? wv : 1.0f - wv) *
                                 (o2 ? ww : 1.0f - ww);
                f0 = fmaf(cf[b].x, wt, f0);
                f1 = fmaf(cf[b].y, wt, f1);
            }
        }

        const float* wra = &W1[(2 * l) * HIDDEN];
        const float* wrb = &W1[(2 * l + 1) * HIDDEN];
#define UPDH(m) { \
        const float4 wa = *(const float4*)&wra[4 * (m)]; \
        const float4 wb = *(const float4*)&wrb[4 * (m)]; \
        h##m.x = fmaf(f0, wa.x, fmaf(f1, wb.x, h##m.x)); \
        h##m.y = fmaf(f0, wa.y, fmaf(f1, wb.y, h##m.y)); \
        h##m.z = fmaf(f0, wa.z, fmaf(f1, wb.z, h##m.z)); \
        h##m.w = fmaf(f0, wa.w, fmaf(f1, wb.w, h##m.w)); }
        H16(UPDH)
#undef UPDH
    }

#define RELUH(m) { h##m.x = fmaxf(h##m.x, 0.0f); h##m.y = fmaxf(h##m.y, 0.0f); \
                   h##m.z = fmaxf(h##m.z, 0.0f); h##m.w = fmaxf(h##m.w, 0.0f); }
    H16(RELUH)
#undef RELUH

    float acc = b3[0];
    #pragma unroll 2
    for (int jb = 0; jb < HIDDEN; jb += 4) {
        float4 t = *(const float4*)&b2[jb];
#define L2K(m) { \
        const float4 r0 = *(const float4*)&W2[(4 * (m) + 0) * HIDDEN + jb]; \
        const float4 r1 = *(const float4*)&W2[(4 * (m) + 1) * HIDDEN + jb]; \
        const float4 r2 = *(const float4*)&W2[(4 * (m) + 2) * HIDDEN + jb]; \
        const float4 r3 = *(const float4*)&W2[(4 * (m) + 3) * HIDDEN + jb]; \
        t.x = fmaf(h##m.x, r0.x, t.x); t.y = fmaf(h##m.x, r0.y, t.y); \
        t.z = fmaf(h##m.x, r0.z, t.z); t.w = fmaf(h##m.x, r0.w, t.w); \
        t.x = fmaf(h##m.y, r1.x, t.x); t.y = fmaf(h##m.y, r1.y, t.y); \
        t.z = fmaf(h##m.y, r1.z, t.z); t.w = fmaf(h##m.y, r1.w, t.w); \
        t.x = fmaf(h##m.z, r2.x, t.x); t.y = fmaf(h##m.z, r2.y, t.y); \
        t.z = fmaf(h##m.z, r2.z, t.z); t.w = fmaf(h##m.z, r2.w, t.w); \
        t.x = fmaf(h##m.w, r3.x, t.x); t.y = fmaf(h##m.w, r3.y, t.y); \
        t.z = fmaf(h##m.w, r3.z, t.z); t.w = fmaf(h##m.w, r3.w, t.w); }
        H16(L2K)
#undef L2K
        const float4 w3v = *(const float4*)&W3[jb];
        acc = fmaf(fmaxf(t.x, 0.0f), w3v.x, acc);
        acc = fmaf(fmaxf(t.y, 0.0f), w3v.y, acc);
        acc = fmaf(fmaxf(t.z, 0.0f), w3v.z, acc);
        acc = fmaf(fmaxf(t.w, 0.0f), w3v.w, acc);
    }

    out[i] = acc;
}

extern "C" void kernel_launch(void* const* d_in, const int* in_sizes, int n_in,
                              void* d_out, int out_size, void* d_ws, size_t ws_size,
                              hipStream_t stream) {
    const float* x     = (const float*)d_in[0];
    const float* table = (const float*)d_in[1];
    const float* W1    = (const float*)d_in[2];
    const float* b1    = (const float*)d_in[3];
    const float* W2    = (const float*)d_in[4];
    const float* b2    = (const float*)d_in[5];
    const float* W3    = (const float*)d_in[6];
    const float* b3    = (const float*)d_in[7];
    float* out = (float*)d_out;

    const int n = in_sizes[0] / 3;
    const int n_entries = NLVL * (int)TBL_SIZE;
    const size_t tbl_bytes   = (size_t)n_entries * sizeof(__half2);        // 33.6 MB
    const size_t pair_bytes  = (((size_t)PO.total * 8) + 15) & ~(size_t)15; // ~2.7 MB
    const size_t wfrag_bytes = 16384;                                       // w1f 4KB + w2f 8KB
    const size_t enc_bytes   = (size_t)NLVL * (size_t)n * sizeof(__half2); // 64 MB
    const int nb_mlp = (n + NTHREADS - 1) / NTHREADS;
    const int nb_enc = (n + NTHREADS * PPT - 1) / (NTHREADS * PPT);

    if (ws_size >= tbl_bytes + pair_bytes + wfrag_bytes + enc_bytes) {
        __half2* tbl_h2 = (__half2*)d_ws;
        unsigned long long* dpair = (unsigned long long*)((char*)d_ws + tbl_bytes);
        __half* w1f = (__half*)((char*)d_ws + tbl_bytes + pair_bytes);
        __half* w2f = w1f + 4 * 64 * 8;
        __half2* enc = (__half2*)((char*)d_ws + tbl_bytes + pair_bytes + wfrag_bytes);

        hipLaunchKernelGGL(cvt_table, dim3(2048), dim3(256), 0, stream,
                           (const float2*)table, tbl_h2, n_entries);
        hipLaunchKernelGGL(cvt_pairs, dim3((PO.total + 255) / 256), dim3(256), 0, stream,
                           tbl_h2, dpair);
        hipLaunchKernelGGL(cvt_wfrags, dim3(16), dim3(256), 0, stream,
                           W1, W2, w1f, w2f);
        hipLaunchKernelGGL(encode_phased, dim3(nb_enc * NLVL), dim3(NTHREADS), 0, stream,
                           x, tbl_h2, dpair, enc, n, nb_enc);
        if ((n & 63) == 0) {
            hipLaunchKernelGGL(mlp_mfma, dim3(n / 64), dim3(256), 0, stream,
                               enc, w1f, w2f, b1, b2, W3, b3, out, n);
        } else {
            hipLaunchKernelGGL(mlp_kernel, dim3(nb_mlp), dim3(NTHREADS), 0, stream,
                               enc, W1, b1, W2, b2, W3, b3, out, n);
        }
    } else if (ws_size >= tbl_bytes) {
        __half2* tbl_h2 = (__half2*)d_ws;
        hipLaunchKernelGGL(cvt_table, dim3(2048), dim3(256), 0, stream,
                           (const float2*)table, tbl_h2, n_entries);
        hipLaunchKernelGGL((sdf_tcnn_fused<true>), dim3(nb_mlp), dim3(NTHREADS), 0, stream,
                           x, (const void*)tbl_h2, W1, b1, W2, b2, W3, b3, out, n);
    } else {
        hipLaunchKernelGGL((sdf_tcnn_fused<false>), dim3(nb_mlp), dim3(NTHREADS), 0, stream,
                           x, (const void*)table, W1, b1, W2, b2, W3, b3, out, n);
    }
}

// Round 12
// 334.326 us; speedup vs baseline: 2.4092x; 1.0110x over previous
//
#include <hip/hip_runtime.h>
#include <hip/hip_fp16.h>
#include <cstdint>

#define NTHREADS 256
#define TBL_SIZE (1u << 19)
#define HIDDEN 64
#define NLVL 16
#define PPT 2   // points per thread in encode
#define ENC_SCALE 256.0f     // exact pow2: keeps fp16 enc/h1 in normal range for MFMA
#define ENC_INV (1.0f / 256.0f)

struct Levels { float scale[16]; int res[16]; int dense[16]; };
constexpr Levels make_levels() {
    Levels L{};
    double s = 16.0;
    for (int l = 0; l < 16; ++l) {
        double sc = s - 1.0;
        L.scale[l] = (float)sc;
        int fi = (int)sc;
        int res = fi + (((double)fi < sc) ? 1 : 0) + 1;   // ceil(sc)+1
        L.res[l] = res;
        L.dense[l] = ((long long)res * res * res <= (long long)TBL_SIZE) ? 1 : 0;
        s *= 1.3819;
    }
    return L;
}
constexpr Levels LV = make_levels();

// quad-table offsets for dense levels (16B entries).
// Region per dense level: res*(1+res+res^2)+2 — covers tcnn's unclamped dense
// indexing (corner coords can equal res); quad internal reads +res+1 stay
// well inside the level's TBL_SIZE entries.
struct PairOffs { int off[17]; int total; };
constexpr PairOffs make_pairoffs() {
    PairOffs P{}; int o = 0;
    for (int l = 0; l < 16; ++l) {
        P.off[l] = o;
        if (LV.dense[l]) {
            const int r = LV.res[l];
            o += r * (1 + r + r * r) + 2;
        }
    }
    P.off[16] = o; P.total = o;
    return P;
}
constexpr PairOffs PO = make_pairoffs();

#define H16(M) M(0) M(1) M(2) M(3) M(4) M(5) M(6) M(7) \
               M(8) M(9) M(10) M(11) M(12) M(13) M(14) M(15)

typedef _Float16 f16x8 __attribute__((ext_vector_type(8)));
typedef float f32x4 __attribute__((ext_vector_type(4)));

static __device__ __forceinline__ __half2 u32_h2(uint32_t u) {
    union { uint32_t u; __half2 h; } c; c.u = u; return c.h;
}

// ---------- f32 table -> fp16 repack ----------
__global__ __launch_bounds__(256) void cvt_table(const float2* __restrict__ in,
                                                 __half2* __restrict__ out, int n) {
    for (int i = blockIdx.x * 256 + threadIdx.x; i < n; i += gridDim.x * 256) {
        const float2 v = in[i];
        out[i] = __floats2half2_rn(v.x, v.y);
    }
}

// ---------- dense-level quad table ----------
// qd[off+idx] = (h2[idx], h2[idx+1], h2[idx+res], h2[idx+res+1])
//             = corners (x,y) = (0,0),(1,0),(0,1),(1,1) at fixed z-plane
__global__ __launch_bounds__(256) void cvt_quads(const __half2* __restrict__ h2,
                                                 uint4* __restrict__ qd) {
    for (int i = blockIdx.x * 256 + threadIdx.x; i < PO.total; i += gridDim.x * 256) {
        int lvl = 0;
        #pragma unroll
        for (int l = 0; l < NLVL; ++l)
            if (LV.dense[l] && i >= PO.off[l] && i < PO.off[l + 1]) lvl = l;
        const int local = i - PO.off[lvl];
        const int res = LV.res[lvl];
        const uint32_t* base = reinterpret_cast<const uint32_t*>(h2 + (size_t)lvl * TBL_SIZE + local);
        uint4 q;
        q.x = base[0];
        q.y = base[1];
        q.z = base[res];
        q.w = base[res + 1];
        qd[i] = q;
    }
}

// ---------- W1^T / W2^T packed into exact MFMA A-fragment order (f16) ----------
__global__ __launch_bounds__(256) void cvt_wfrags(const float* __restrict__ W1,
                                                  const float* __restrict__ W2,
                                                  __half* __restrict__ w1f,
                                                  __half* __restrict__ w2f) {
    const int t = blockIdx.x * 256 + threadIdx.x;
    for (int i = t; i < 4 * 64 * 8; i += gridDim.x * 256) {
        const int j = i & 7, lane = (i >> 3) & 63, nt = i >> 9;
        const int k = (lane >> 4) * 8 + j;
        const int o = (lane & 15) + 16 * nt;
        w1f[i] = __float2half(W1[k * HIDDEN + o]);
    }
    for (int i = t; i < 4 * 2 * 64 * 8; i += gridDim.x * 256) {
        const int j = i & 7, lane = (i >> 3) & 63, kb = (i >> 9) & 1, nt = i >> 10;
        const int k = 32 * kb + (lane >> 4) * 8 + j;
        const int o = (lane & 15) + 16 * nt;
        w2f[i] = __float2half(W2[k * HIDDEN + o]);
    }
}

// gather one level for one point; returns (f0,f1) UNSCALED.
// dense: 2x 16B quad loads (bilinear xy + lerp z).
// hash: iu even -> 4x 8B pair loads (h^1 trick); iu odd -> 8x 4B loads.
static __device__ __forceinline__ float2 gather_level(
    const __half2* __restrict__ tl, const uint4* __restrict__ qd,
    int dense, int res, int doff,
    int iu, int iv, int iw, float wu, float wv, float ww)
{
    float f0 = 0.0f, f1 = 0.0f;
    const float lx = 1.0f - wu;
    if (dense) {
        const int base = iu + iv * res + iw * res * res;
        #pragma unroll
        for (int o2 = 0; o2 < 2; ++o2) {
            const int idx = base + (o2 ? res * res : 0);
            const uint4 q = qd[doff + idx];
            const float2 a = __half22float2(u32_h2(q.x));   // (0,0)
            const float2 b = __half22float2(u32_h2(q.y));   // (1,0)
            const float2 c = __half22float2(u32_h2(q.z));   // (0,1)
            const float2 d = __half22float2(u32_h2(q.w));   // (1,1)
            const float x0l = fmaf(lx, a.x, wu * b.x);
            const float x1l = fmaf(lx, c.x, wu * d.x);
            const float y0l = fmaf(lx, a.y, wu * b.y);
            const float y1l = fmaf(lx, c.y, wu * d.y);
            const float bil0 = fmaf(1.0f - wv, x0l, wv * x1l);
            const float bil1 = fmaf(1.0f - wv, y0l, wv * y1l);
            const float wz = o2 ? ww : 1.0f - ww;
            f0 = fmaf(bil0, wz, f0);
            f1 = fmaf(bil1, wz, f1);
        }
    } else {
        const uint32_t r1a = (uint32_t)iv * 2654435761u;
        const uint32_t r1b = r1a + 2654435761u;
        const uint32_t r2a = (uint32_t)iw * 805459861u;
        const uint32_t r2b = r2a + 805459861u;
        if ((iu & 1) == 0) {
            #pragma unroll
            for (int b4 = 0; b4 < 4; ++b4) {
                const int o1 = (b4 >> 1) & 1, o2 = b4 & 1;
                const uint32_t rest = (o1 ? r1b : r1a) ^ (o2 ? r2b : r2a);
                const uint32_t h0 = ((uint32_t)iu ^ rest) & (TBL_SIZE - 1u);
                const unsigned long long pr =
                    *reinterpret_cast<const unsigned long long*>(tl + (h0 & ~1u));
                const uint32_t lo = (uint32_t)pr, hi = (uint32_t)(pr >> 32);
                const uint32_t sel = h0 & 1u;
                const float2 a = __half22float2(u32_h2(sel ? hi : lo)); // c0
                const float2 b = __half22float2(u32_h2(sel ? lo : hi)); // c1
                const float wyz = (o1 ? wv : 1.0f - wv) * (o2 ? ww : 1.0f - ww);
                f0 = fmaf(fmaf(lx, a.x, wu * b.x), wyz, f0);
                f1 = fmaf(fmaf(lx, a.y, wu * b.y), wyz, f1);
            }
        } else {
            #pragma unroll
            for (int b4 = 0; b4 < 4; ++b4) {
                const int o1 = (b4 >> 1) & 1, o2 = b4 & 1;
                const uint32_t rest = (o1 ? r1b : r1a) ^ (o2 ? r2b : r2a);
                const uint32_t h0 = ((uint32_t)iu ^ rest) & (TBL_SIZE - 1u);
                const uint32_t h1 = ((uint32_t)(iu + 1) ^ rest) & (TBL_SIZE - 1u);
                const float2 a = __half22float2(tl[h0]);
                const float2 b = __half22float2(tl[h1]);
                const float wyz = (o1 ? wv : 1.0f - wv) * (o2 ? ww : 1.0f - ww);
                f0 = fmaf(fmaf(lx, a.x, wu * b.x), wyz, f0);
                f1 = fmaf(fmaf(lx, a.y, wu * b.y), wyz, f1);
            }
        }
    }
    return make_float2(f0, f1);
}

// ---------- Kernel A: LEVEL-PHASED encode (enc stored x256) ----------
__global__ __launch_bounds__(NTHREADS, 8) void encode_phased(
    const float* __restrict__ x,
    const __half2* __restrict__ tbl,
    const uint4* __restrict__ qd,
    __half2* __restrict__ enc, int n, int nb)
{
    const int bid = blockIdx.x;
    const int lvl = bid / nb;
    const int pb  = bid - lvl * nb;
    const int i0 = pb * (NTHREADS * PPT) + threadIdx.x;
    const int i1 = i0 + NTHREADS;
    if (i0 >= n) return;

    const float sc = LV.scale[lvl];
    const int res = LV.res[lvl];
    const int dense = LV.dense[lvl];
    const int doff = PO.off[lvl];
    const __half2* tl = tbl + (size_t)lvl * TBL_SIZE;

    const float u0 = (x[3 * i0 + 0] + 1.0f) * 0.5f;
    const float v0 = (x[3 * i0 + 1] + 1.0f) * 0.5f;
    const float w0 = (x[3 * i0 + 2] + 1.0f) * 0.5f;
    const float pu0 = u0 * sc + 0.5f, pv0 = v0 * sc + 0.5f, pw0 = w0 * sc + 0.5f;
    const float fu0 = floorf(pu0), fv0 = floorf(pv0), fw0 = floorf(pw0);

    const bool has1 = (i1 < n);
    const int j1 = has1 ? i1 : i0;
    const float u1 = (x[3 * j1 + 0] + 1.0f) * 0.5f;
    const float v1 = (x[3 * j1 + 1] + 1.0f) * 0.5f;
    const float w1 = (x[3 * j1 + 2] + 1.0f) * 0.5f;
    const float pu1 = u1 * sc + 0.5f, pv1 = v1 * sc + 0.5f, pw1 = w1 * sc + 0.5f;
    const float fu1 = floorf(pu1), fv1 = floorf(pv1), fw1 = floorf(pw1);

    const float2 fA = gather_level(tl, qd, dense, res, doff,
                                   (int)fu0, (int)fv0, (int)fw0,
                                   pu0 - fu0, pv0 - fv0, pw0 - fw0);
    const float2 fB = gather_level(tl, qd, dense, res, doff,
                                   (int)fu1, (int)fv1, (int)fw1,
                                   pu1 - fu1, pv1 - fv1, pw1 - fw1);

    enc[(size_t)lvl * n + i0] = __floats2half2_rn(fA.x * ENC_SCALE, fA.y * ENC_SCALE);
    if (has1) enc[(size_t)lvl * n + i1] = __floats2half2_rn(fB.x * ENC_SCALE, fB.y * ENC_SCALE);
}

// ---------- Kernel B: MFMA MLP (transposed: h^T = W^T @ enc^T) ----------
__global__ __launch_bounds__(256) void mlp_mfma(
    const __half2* __restrict__ enc,
    const __half* __restrict__ w1f, const __half* __restrict__ w2f,
    const float* __restrict__ b1, const float* __restrict__ b2,
    const float* __restrict__ W3, const float* __restrict__ b3,
    float* __restrict__ out, int n)
{
    __shared__ __half lds_h1[4][64][18];
    const int wid  = threadIdx.x >> 6;
    const int lane = threadIdx.x & 63;
    const int tile = blockIdx.x * 4 + wid;
    const int pt = lane & 15;
    const int qw = lane >> 4;
    const int i = tile * 16 + pt;

    union { uint32_t u[4]; f16x8 v; } bf;
    #pragma unroll
    for (int jj = 0; jj < 4; ++jj)
        bf.u[jj] = *reinterpret_cast<const uint32_t*>(&enc[(size_t)(qw * 4 + jj) * n + i]);

    f32x4 c1[4];
    #pragma unroll
    for (int nt = 0; nt < 4; ++nt) {
        const float4 bb = *(const float4*)&b1[16 * nt + qw * 4];
        c1[nt][0] = bb.x * ENC_SCALE; c1[nt][1] = bb.y * ENC_SCALE;
        c1[nt][2] = bb.z * ENC_SCALE; c1[nt][3] = bb.w * ENC_SCALE;
        const f16x8 a = *reinterpret_cast<const f16x8*>(&w1f[(nt * 64 + lane) * 8]);
        c1[nt] = __builtin_amdgcn_mfma_f32_16x16x32_f16(a, bf.v, c1[nt], 0, 0, 0);
    }

    #pragma unroll
    for (int nt = 0; nt < 4; ++nt) {
        #pragma unroll
        for (int r = 0; r < 4; ++r) {
            const int o = 16 * nt + qw * 4 + r;
            lds_h1[wid][o][pt] = __float2half(fmaxf(c1[nt][r], 0.0f));
        }
    }

    f32x4 c2[4];
    #pragma unroll
    for (int nt = 0; nt < 4; ++nt) {
        const float4 bb = *(const float4*)&b2[16 * nt + qw * 4];
        c2[nt][0] = bb.x * ENC_SCALE; c2[nt][1] = bb.y * ENC_SCALE;
        c2[nt][2] = bb.z * ENC_SCALE; c2[nt][3] = bb.w * ENC_SCALE;
    }
    #pragma unroll
    for (int kb = 0; kb < 2; ++kb) {
        union { uint32_t u[4]; f16x8 v; } hb;
        #pragma unroll
        for (int j2 = 0; j2 < 4; ++j2) {
            const int k0 = kb * 32 + qw * 8 + 2 * j2;
            const uint32_t lo = __half_as_ushort(lds_h1[wid][k0][pt]);
            const uint32_t hi = __half_as_ushort(lds_h1[wid][k0 + 1][pt]);
            hb.u[j2] = lo | (hi << 16);
        }
        #pragma unroll
        for (int nt = 0; nt < 4; ++nt) {
            const f16x8 a = *reinterpret_cast<const f16x8*>(&w2f[((nt * 2 + kb) * 64 + lane) * 8]);
            c2[nt] = __builtin_amdgcn_mfma_f32_16x16x32_f16(a, hb.v, c2[nt], 0, 0, 0);
        }
    }

    float part = 0.0f;
    #pragma unroll
    for (int nt = 0; nt < 4; ++nt) {
        const float4 w3v = *(const float4*)&W3[16 * nt + qw * 4];
        part = fmaf(fmaxf(c2[nt][0], 0.0f), w3v.x, part);
        part = fmaf(fmaxf(c2[nt][1], 0.0f), w3v.y, part);
        part = fmaf(fmaxf(c2[nt][2], 0.0f), w3v.z, part);
        part = fmaf(fmaxf(c2[nt][3], 0.0f), w3v.w, part);
    }
    part += __shfl_xor(part, 16, 64);
    part += __shfl_xor(part, 32, 64);
    if (lane < 16) out[i] = part * ENC_INV + b3[0];
}

// ---------- Fallback VALU MLP (enc stored x256 -> rescale on read) ----------
__global__ __launch_bounds__(NTHREADS, 4) void mlp_kernel(
    const __half2* __restrict__ enc,
    const float* __restrict__ W1, const float* __restrict__ b1,
    const float* __restrict__ W2, const float* __restrict__ b2,
    const float* __restrict__ W3, const float* __restrict__ b3,
    float* __restrict__ out, int n)
{
    const int i = blockIdx.x * NTHREADS + threadIdx.x;
    if (i >= n) return;

#define DECLH(m) float4 h##m = *(const float4*)&b1[4 * (m)];
    H16(DECLH)
#undef DECLH

    #pragma unroll
    for (int l = 0; l < NLVL; ++l) {
        const float2 f = __half22float2(enc[(size_t)l * n + i]);
        const float f0 = f.x * ENC_INV, f1 = f.y * ENC_INV;
        const float* wra = &W1[(2 * l) * HIDDEN];
        const float* wrb = &W1[(2 * l + 1) * HIDDEN];
#define UPDH(m) { \
        const float4 wa = *(const float4*)&wra[4 * (m)]; \
        const float4 wb = *(const float4*)&wrb[4 * (m)]; \
        h##m.x = fmaf(f0, wa.x, fmaf(f1, wb.x, h##m.x)); \
        h##m.y = fmaf(f0, wa.y, fmaf(f1, wb.y, h##m.y)); \
        h##m.z = fmaf(f0, wa.z, fmaf(f1, wb.z, h##m.z)); \
        h##m.w = fmaf(f0, wa.w, fmaf(f1, wb.w, h##m.w)); }
        H16(UPDH)
#undef UPDH
    }

#define RELUH(m) { h##m.x = fmaxf(h##m.x, 0.0f); h##m.y = fmaxf(h##m.y, 0.0f); \
                   h##m.z = fmaxf(h##m.z, 0.0f); h##m.w = fmaxf(h##m.w, 0.0f); }
    H16(RELUH)
#undef RELUH

    float acc = b3[0];
    #pragma unroll 2
    for (int jb = 0; jb < HIDDEN; jb += 4) {
        float4 t = *(const float4*)&b2[jb];
#define L2K(m) { \
        const float4 r0 = *(const float4*)&W2[(4 * (m) + 0) * HIDDEN + jb]; \
        const float4 r1 = *(const float4*)&W2[(4 * (m) + 1) * HIDDEN + jb]; \
        const float4 r2 = *(const float4*)&W2[(4 * (m) + 2) * HIDDEN + jb]; \
        const float4 r3 = *(const float4*)&W2[(4 * (m) + 3) * HIDDEN + jb]; \
        t.x = fmaf(h##m.x, r0.x, t.x); t.y = fmaf(h##m.x, r0.y, t.y); \
        t.z = fmaf(h##m.x, r0.z, t.z); t.w = fmaf(h##m.x, r0.w, t.w); \
        t.x = fmaf(h##m.y, r1.x, t.x); t.y = fmaf(h##m.y, r1.y, t.y); \
        t.z = fmaf(h##m.y, r1.z, t.z); t.w = fmaf(h##m.y, r1.w, t.w); \
        t.x = fmaf(h##m.z, r2.x, t.x); t.y = fmaf(h##m.z, r2.y, t.y); \
        t.z = fmaf(h##m.z, r2.z, t.z); t.w = fmaf(h##m.z, r2.w, t.w); \
        t.x = fmaf(h##m.w, r3.x, t.x); t.y = fmaf(h##m.w, r3.y, t.y); \
        t.z = fmaf(h##m.w, r3.z, t.z); t.w = fmaf(h##m.w, r3.w, t.w); }
        H16(L2K)
#undef L2K
        const float4 w3v = *(const float4*)&W3[jb];
        acc = fmaf(fmaxf(t.x, 0.0f), w3v.x, acc);
        acc = fmaf(fmaxf(t.y, 0.0f), w3v.y, acc);
        acc = fmaf(fmaxf(t.z, 0.0f), w3v.z, acc);
        acc = fmaf(fmaxf(t.w, 0.0f), w3v.w, acc);
    }

    out[i] = acc;
}

// ---------- Fallback: fused kernel (if ws too small for split) ----------
template <bool USE_H2>
__global__ __launch_bounds__(NTHREADS, 4) void sdf_tcnn_fused(
    const float* __restrict__ x,
    const void* __restrict__ tbl,
    const float* __restrict__ W1, const float* __restrict__ b1,
    const float* __restrict__ W2, const float* __restrict__ b2,
    const float* __restrict__ W3, const float* __restrict__ b3,
    float* __restrict__ out, int n)
{
    const int i = blockIdx.x * NTHREADS + threadIdx.x;
    if (i >= n) return;

    const float u = (x[3 * i + 0] + 1.0f) * 0.5f;
    const float v = (x[3 * i + 1] + 1.0f) * 0.5f;
    const float w = (x[3 * i + 2] + 1.0f) * 0.5f;

#define DECLH(m) float4 h##m = *(const float4*)&b1[4 * (m)];
    H16(DECLH)
#undef DECLH

    #pragma unroll
    for (int l = 0; l < NLVL; ++l) {
        const float sc = LV.scale[l];
        const int res = LV.res[l];
        const float pu = u * sc + 0.5f;
        const float pv = v * sc + 0.5f;
        const float pw = w * sc + 0.5f;
        const float fu = floorf(pu), fv = floorf(pv), fw = floorf(pw);
        const float wu = pu - fu, wv = pv - fv, ww = pw - fw;
        const int iu = (int)fu, iv = (int)fv, iw = (int)fw;

        int idx[8];
        #pragma unroll
        for (int b = 0; b < 8; ++b) {
            const int o0 = (b >> 2) & 1, o1 = (b >> 1) & 1, o2 = b & 1;
            if (LV.dense[l]) {
                idx[b] = (iu + o0) + (iv + o1) * res + (iw + o2) * (res * res);
            } else {
                const uint32_t c0 = (uint32_t)(iu + o0);
                const uint32_t c1 = (uint32_t)(iv + o1);
                const uint32_t c2 = (uint32_t)(iw + o2);
                const uint32_t h = c0 ^ (c1 * 2654435761u) ^ (c2 * 805459861u);
                idx[b] = (int)(h & (TBL_SIZE - 1u));
            }
        }

        float f0 = 0.0f, f1 = 0.0f;
        if constexpr (USE_H2) {
            const __half2* tl = (const __half2*)tbl + (size_t)l * TBL_SIZE;
            __half2 cfh[8];
            #pragma unroll
            for (int b = 0; b < 8; ++b) cfh[b] = tl[idx[b]];
            #pragma unroll
            for (int b = 0; b < 8; ++b) {
                const int o0 = (b >> 2) & 1, o1 = (b >> 1) & 1, o2 = b & 1;
                const float wt = (o0 ? wu : 1.0f - wu) *
                                 (o1 ? wv : 1.0f - wv) *
                                 (o2 ? ww : 1.0f - ww);
                const float2 cf = __half22float2(cfh[b]);
                f0 = fmaf(cf.x, wt, f0);
                f1 = fmaf(cf.y, wt, f1);
            }
        } else {
            const float2* tl = (const float2*)tbl + (size_t)l * TBL_SIZE;
            float2 cf[8];
            #pragma unroll
            for (int b = 0; b < 8; ++b) cf[b] = tl[idx[b]];
            #pragma unroll
            for (int b = 0; b < 8; ++b) {
                const int o0 = (b >> 2) & 1, o1 = (b >> 1) & 1, o2 = b & 1;
                const float wt = (o0 ? wu : 1.0f - wu) *
                                 (o1 ? wv : 1.0f - wv) *
                                 (o2 ? ww : 1.0f - ww);
                f0 = fmaf(cf[b].x, wt, f0);
                f1 = fmaf(cf[b].y, wt, f1);
            }
        }

        const float* wra = &W1[(2 * l) * HIDDEN];
        const float* wrb = &W1[(2 * l + 1) * HIDDEN];
#define UPDH(m) { \
        const float4 wa = *(const float4*)&wra[4 * (m)]; \
        const float4 wb = *(const float4*)&wrb[4 * (m)]; \
        h##m.x = fmaf(f0, wa.x, fmaf(f1, wb.x, h##m.x)); \
        h##m.y = fmaf(f0, wa.y, fmaf(f1, wb.y, h##m.y)); \
        h##m.z = fmaf(f0, wa.z, fmaf(f1, wb.z, h##m.z)); \
        h##m.w = fmaf(f0, wa.w, fmaf(f1, wb.w, h##m.w)); }
        H16(UPDH)
#undef UPDH
    }

#define RELUH(m) { h##m.x = fmaxf(h##m.x, 0.0f); h##m.y = fmaxf(h##m.y, 0.0f); \
                   h##m.z = fmaxf(h##m.z, 0.0f); h##m.w = fmaxf(h##m.w, 0.0f); }
    H16(RELUH)
#undef RELUH

    float acc = b3[0];
    #pragma unroll 2
    for (int jb = 0; jb < HIDDEN; jb += 4) {
        float4 t = *(const float4*)&b2[jb];
#define L2K(m) { \
        const float4 r0 = *(const float4*)&W2[(4 * (m) + 0) * HIDDEN + jb]; \
        const float4 r1 = *(const float4*)&W2[(4 * (m) + 1) * HIDDEN + jb]; \
        const float4 r2 = *(const float4*)&W2[(4 * (m) + 2) * HIDDEN + jb]; \
        const float4 r3 = *(const float4*)&W2[(4 * (m) + 3) * HIDDEN + jb]; \
        t.x = fmaf(h##m.x, r0.x, t.x); t.y = fmaf(h##m.x, r0.y, t.y); \
        t.z = fmaf(h##m.x, r0.z, t.z); t.w = fmaf(h##m.x, r0.w, t.w); \
        t.x = fmaf(h##m.y, r1.x, t.x); t.y = fmaf(h##m.y, r1.y, t.y); \
        t.z = fmaf(h##m.y, r1.z, t.z); t.w = fmaf(h##m.y, r1.w, t.w); \
        t.x = fmaf(h##m.z, r2.x, t.x); t.y = fmaf(h##m.z, r2.y, t.y); \
        t.z = fmaf(h##m.z, r2.z, t.z); t.w = fmaf(h##m.z, r2.w, t.w); \
        t.x = fmaf(h##m.w, r3.x, t.x); t.y = fmaf(h##m.w, r3.y, t.y); \
        t.z = fmaf(h##m.w, r3.z, t.z); t.w = fmaf(h##m.w, r3.w, t.w); }
        H16(L2K)
#undef L2K
        const float4 w3v = *(const float4*)&W3[jb];
        acc = fmaf(fmaxf(t.x, 0.0f), w3v.x, acc);
        acc = fmaf(fmaxf(t.y, 0.0f), w3v.y, acc);
        acc = fmaf(fmaxf(t.z, 0.0f), w3v.z, acc);
        acc = fmaf(fmaxf(t.w, 0.0f), w3v.w, acc);
    }

    out[i] = acc;
}

extern "C" void kernel_launch(void* const* d_in, const int* in_sizes, int n_in,
                              void* d_out, int out_size, void* d_ws, size_t ws_size,
                              hipStream_t stream) {
    const float* x     = (const float*)d_in[0];
    const float* table = (const float*)d_in[1];
    const float* W1    = (const float*)d_in[2];
    const float* b1    = (const float*)d_in[3];
    const float* W2    = (const float*)d_in[4];
    const float* b2    = (const float*)d_in[5];
    const float* W3    = (const float*)d_in[6];
    const float* b3    = (const float*)d_in[7];
    float* out = (float*)d_out;

    const int n = in_sizes[0] / 3;
    const int n_entries = NLVL * (int)TBL_SIZE;
    const size_t tbl_bytes   = (size_t)n_entries * sizeof(__half2);        // 33.6 MB
    const size_t quad_bytes  = (size_t)PO.total * 16;                      // ~13.2 MB
    const size_t wfrag_bytes = 16384;                                      // w1f 4KB + w2f 8KB
    const size_t enc_bytes   = (size_t)NLVL * (size_t)n * sizeof(__half2); // 64 MB
    const int nb_mlp = (n + NTHREADS - 1) / NTHREADS;
    const int nb_enc = (n + NTHREADS * PPT - 1) / (NTHREADS * PPT);

    if (ws_size >= tbl_bytes + quad_bytes + wfrag_bytes + enc_bytes) {
        __half2* tbl_h2 = (__half2*)d_ws;
        uint4* qd = (uint4*)((char*)d_ws + tbl_bytes);
        __half* w1f = (__half*)((char*)d_ws + tbl_bytes + quad_bytes);
        __half* w2f = w1f + 4 * 64 * 8;
        __half2* enc = (__half2*)((char*)d_ws + tbl_bytes + quad_bytes + wfrag_bytes);

        hipLaunchKernelGGL(cvt_table, dim3(2048), dim3(256), 0, stream,
                           (const float2*)table, tbl_h2, n_entries);
        hipLaunchKernelGGL(cvt_quads, dim3((PO.total + 255) / 256), dim3(256), 0, stream,
                           tbl_h2, qd);
        hipLaunchKernelGGL(cvt_wfrags, dim3(16), dim3(256), 0, stream,
                           W1, W2, w1f, w2f);
        hipLaunchKernelGGL(encode_phased, dim3(nb_enc * NLVL), dim3(NTHREADS), 0, stream,
                           x, tbl_h2, qd, enc, n, nb_enc);
        if ((n & 63) == 0) {
            hipLaunchKernelGGL(mlp_mfma, dim3(n / 64), dim3(256), 0, stream,
                               enc, w1f, w2f, b1, b2, W3, b3, out, n);
        } else {
            hipLaunchKernelGGL(mlp_kernel, dim3(nb_mlp), dim3(NTHREADS), 0, stream,
                               enc, W1, b1, W2, b2, W3, b3, out, n);
        }
    } else if (ws_size >= tbl_bytes) {
        __half2* tbl_h2 = (__half2*)d_ws;
        hipLaunchKernelGGL(cvt_table, dim3(2048), dim3(256), 0, stream,
                           (const float2*)table, tbl_h2, n_entries);
        hipLaunchKernelGGL((sdf_tcnn_fused<true>), dim3(nb_mlp), dim3(NTHREADS), 0, stream,
                           x, (const void*)tbl_h2, W1, b1, W2, b2, W3, b3, out, n);
    } else {
        hipLaunchKernelGGL((sdf_tcnn_fused<false>), dim3(nb_mlp), dim3(NTHREADS), 0, stream,
                           x, (const void*)table, W1, b1, W2, b2, W3, b3, out, n);
    }
}

// Round 13
// 321.098 us; speedup vs baseline: 2.5085x; 1.0412x over previous
//
#include <hip/hip_runtime.h>
#include <hip/hip_fp16.h>
#include <cstdint>

#define NTHREADS 256
#define TBL_SIZE (1u << 19)
#define HIDDEN 64
#define NLVL 16
#define NDENSE 5          // levels 0..4 dense; 5..15 hashed (res^3 vs T)
#define NHASH (NLVL - NDENSE)
#define PPT 2
#define ENC_SCALE 256.0f  // exact pow2: keeps fp16 enc/h1 in normal range for MFMA
#define ENC_INV (1.0f / 256.0f)

struct Levels { float scale[16]; int res[16]; int dense[16]; };
constexpr Levels make_levels() {
    Levels L{};
    double s = 16.0;
    for (int l = 0; l < 16; ++l) {
        double sc = s - 1.0;
        L.scale[l] = (float)sc;
        int fi = (int)sc;
        int res = fi + (((double)fi < sc) ? 1 : 0) + 1;   // ceil(sc)+1
        L.res[l] = res;
        L.dense[l] = ((long long)res * res * res <= (long long)TBL_SIZE) ? 1 : 0;
        s *= 1.3819;
    }
    return L;
}
constexpr Levels LV = make_levels();
static_assert(LV.dense[NDENSE - 1] == 1 && LV.dense[NDENSE] == 0, "dense split");

// quad-table offsets for dense levels (16B entries); region covers tcnn's
// unclamped dense indexing up to res(1+res+res^2) (round-9 bugfix).
struct PairOffs { int off[17]; int total; };
constexpr PairOffs make_pairoffs() {
    PairOffs P{}; int o = 0;
    for (int l = 0; l < 16; ++l) {
        P.off[l] = o;
        if (LV.dense[l]) {
            const int r = LV.res[l];
            o += r * (1 + r + r * r) + 2;
        }
    }
    P.off[16] = o; P.total = o;
    return P;
}
constexpr PairOffs PO = make_pairoffs();

#define H16(M) M(0) M(1) M(2) M(3) M(4) M(5) M(6) M(7) \
               M(8) M(9) M(10) M(11) M(12) M(13) M(14) M(15)

typedef _Float16 f16x8 __attribute__((ext_vector_type(8)));
typedef float f32x4 __attribute__((ext_vector_type(4)));

static __device__ __forceinline__ __half2 u32_h2(uint32_t u) {
    union { uint32_t u; __half2 h; } c; c.u = u; return c.h;
}
static __device__ __forceinline__ uint32_t h2_u32(__half2 h) {
    union { __half2 h; uint32_t u; } c; c.h = h; return c.u;
}

// ---------- f32 table -> fp16 repack (HASH LEVELS ONLY; dense uses quads) ----------
__global__ __launch_bounds__(256) void cvt_table(const float2* __restrict__ in,
                                                 __half2* __restrict__ out, int n) {
    for (int i = blockIdx.x * 256 + threadIdx.x; i < n; i += gridDim.x * 256) {
        const float2 v = in[i];
        out[i] = __floats2half2_rn(v.x, v.y);
    }
}

// ---------- dense-level quad table, built straight from the f32 table ----------
// qd[off+idx] = fp16 of (t[idx], t[idx+1], t[idx+res], t[idx+res+1])
__global__ __launch_bounds__(256) void cvt_quads(const float2* __restrict__ tf,
                                                 uint4* __restrict__ qd) {
    for (int i = blockIdx.x * 256 + threadIdx.x; i < PO.total; i += gridDim.x * 256) {
        int lvl = 0;
        #pragma unroll
        for (int l = 0; l < NLVL; ++l)
            if (LV.dense[l] && i >= PO.off[l] && i < PO.off[l + 1]) lvl = l;
        const int local = i - PO.off[lvl];
        const int res = LV.res[lvl];
        const float2* base = tf + (size_t)lvl * TBL_SIZE + local;
        uint4 q;
        q.x = h2_u32(__floats2half2_rn(base[0].x, base[0].y));
        q.y = h2_u32(__floats2half2_rn(base[1].x, base[1].y));
        q.z = h2_u32(__floats2half2_rn(base[res].x, base[res].y));
        q.w = h2_u32(__floats2half2_rn(base[res + 1].x, base[res + 1].y));
        qd[i] = q;
    }
}

// ---------- W1^T / W2^T packed into exact MFMA A-fragment order (f16) ----------
__global__ __launch_bounds__(256) void cvt_wfrags(const float* __restrict__ W1,
                                                  const float* __restrict__ W2,
                                                  __half* __restrict__ w1f,
                                                  __half* __restrict__ w2f) {
    const int t = blockIdx.x * 256 + threadIdx.x;
    for (int i = t; i < 4 * 64 * 8; i += gridDim.x * 256) {
        const int j = i & 7, lane = (i >> 3) & 63, nt = i >> 9;
        const int k = (lane >> 4) * 8 + j;
        const int o = (lane & 15) + 16 * nt;
        w1f[i] = __float2half(W1[k * HIDDEN + o]);
    }
    for (int i = t; i < 4 * 2 * 64 * 8; i += gridDim.x * 256) {
        const int j = i & 7, lane = (i >> 3) & 63, kb = (i >> 9) & 1, nt = i >> 10;
        const int k = 32 * kb + (lane >> 4) * 8 + j;
        const int o = (lane & 15) + 16 * nt;
        w2f[i] = __float2half(W2[k * HIDDEN + o]);
    }
}

// dense-level gather via quads: 2x 16B loads, bilinear xy + lerp z
static __device__ __forceinline__ float2 gather_dense(
    const uint4* __restrict__ qd, int res, int doff,
    int iu, int iv, int iw, float wu, float wv, float ww)
{
    float f0 = 0.0f, f1 = 0.0f;
    const float lx = 1.0f - wu;
    const int base = iu + iv * res + iw * res * res;
    #pragma unroll
    for (int o2 = 0; o2 < 2; ++o2) {
        const int idx = base + (o2 ? res * res : 0);
        const uint4 q = qd[doff + idx];
        const float2 a = __half22float2(u32_h2(q.x));   // (0,0)
        const float2 b = __half22float2(u32_h2(q.y));   // (1,0)
        const float2 c = __half22float2(u32_h2(q.z));   // (0,1)
        const float2 d = __half22float2(u32_h2(q.w));   // (1,1)
        const float x0l = fmaf(lx, a.x, wu * b.x);
        const float x1l = fmaf(lx, c.x, wu * d.x);
        const float y0l = fmaf(lx, a.y, wu * b.y);
        const float y1l = fmaf(lx, c.y, wu * d.y);
        const float bil0 = fmaf(1.0f - wv, x0l, wv * x1l);
        const float bil1 = fmaf(1.0f - wv, y0l, wv * y1l);
        const float wz = o2 ? ww : 1.0f - ww;
        f0 = fmaf(bil0, wz, f0);
        f1 = fmaf(bil1, wz, f1);
    }
    return make_float2(f0, f1);
}

// hash-level gather: iu even -> 4x 8B pair loads (h^1 trick, PRIMES[0]==1);
// iu odd -> 8x 4B loads (corners straddle two aligned pairs; 8 is the floor).
static __device__ __forceinline__ float2 gather_hash(
    const __half2* __restrict__ tl,
    int iu, int iv, int iw, float wu, float wv, float ww)
{
    float f0 = 0.0f, f1 = 0.0f;
    const float lx = 1.0f - wu;
    const uint32_t r1a = (uint32_t)iv * 2654435761u;
    const uint32_t r1b = r1a + 2654435761u;
    const uint32_t r2a = (uint32_t)iw * 805459861u;
    const uint32_t r2b = r2a + 805459861u;
    if ((iu & 1) == 0) {
        #pragma unroll
        for (int b4 = 0; b4 < 4; ++b4) {
            const int o1 = (b4 >> 1) & 1, o2 = b4 & 1;
            const uint32_t rest = (o1 ? r1b : r1a) ^ (o2 ? r2b : r2a);
            const uint32_t h0 = ((uint32_t)iu ^ rest) & (TBL_SIZE - 1u);
            const unsigned long long pr =
                *reinterpret_cast<const unsigned long long*>(tl + (h0 & ~1u));
            const uint32_t lo = (uint32_t)pr, hi = (uint32_t)(pr >> 32);
            const uint32_t sel = h0 & 1u;
            const float2 a = __half22float2(u32_h2(sel ? hi : lo)); // c0
            const float2 b = __half22float2(u32_h2(sel ? lo : hi)); // c1
            const float wyz = (o1 ? wv : 1.0f - wv) * (o2 ? ww : 1.0f - ww);
            f0 = fmaf(fmaf(lx, a.x, wu * b.x), wyz, f0);
            f1 = fmaf(fmaf(lx, a.y, wu * b.y), wyz, f1);
        }
    } else {
        #pragma unroll
        for (int b4 = 0; b4 < 4; ++b4) {
            const int o1 = (b4 >> 1) & 1, o2 = b4 & 1;
            const uint32_t rest = (o1 ? r1b : r1a) ^ (o2 ? r2b : r2a);
            const uint32_t h0 = ((uint32_t)iu ^ rest) & (TBL_SIZE - 1u);
            const uint32_t h1 = ((uint32_t)(iu + 1) ^ rest) & (TBL_SIZE - 1u);
            const float2 a = __half22float2(tl[h0]);
            const float2 b = __half22float2(tl[h1]);
            const float wyz = (o1 ? wv : 1.0f - wv) * (o2 ? ww : 1.0f - ww);
            f0 = fmaf(fmaf(lx, a.x, wu * b.x), wyz, f0);
            f1 = fmaf(fmaf(lx, a.y, wu * b.y), wyz, f1);
        }
    }
    return make_float2(f0, f1);
}

// ---------- Kernel A1: ALL dense levels in ONE phase (x read once) ----------
__global__ __launch_bounds__(NTHREADS, 8) void encode_dense(
    const float* __restrict__ x,
    const uint4* __restrict__ qd,
    __half2* __restrict__ enc, int n)
{
    const int i0 = blockIdx.x * (NTHREADS * PPT) + threadIdx.x;
    const int i1 = i0 + NTHREADS;
    if (i0 >= n) return;

    const float u0 = (x[3 * i0 + 0] + 1.0f) * 0.5f;
    const float v0 = (x[3 * i0 + 1] + 1.0f) * 0.5f;
    const float w0 = (x[3 * i0 + 2] + 1.0f) * 0.5f;
    const bool has1 = (i1 < n);
    const int j1 = has1 ? i1 : i0;
    const float u1 = (x[3 * j1 + 0] + 1.0f) * 0.5f;
    const float v1 = (x[3 * j1 + 1] + 1.0f) * 0.5f;
    const float w1 = (x[3 * j1 + 2] + 1.0f) * 0.5f;

    #pragma unroll
    for (int l = 0; l < NDENSE; ++l) {
        const float sc = LV.scale[l];
        const int res = LV.res[l];
        const int doff = PO.off[l];

        const float pu0 = u0 * sc + 0.5f, pv0 = v0 * sc + 0.5f, pw0 = w0 * sc + 0.5f;
        const float fu0 = floorf(pu0), fv0 = floorf(pv0), fw0 = floorf(pw0);
        const float2 fA = gather_dense(qd, res, doff, (int)fu0, (int)fv0, (int)fw0,
                                       pu0 - fu0, pv0 - fv0, pw0 - fw0);
        const float pu1 = u1 * sc + 0.5f, pv1 = v1 * sc + 0.5f, pw1 = w1 * sc + 0.5f;
        const float fu1 = floorf(pu1), fv1 = floorf(pv1), fw1 = floorf(pw1);
        const float2 fB = gather_dense(qd, res, doff, (int)fu1, (int)fv1, (int)fw1,
                                       pu1 - fu1, pv1 - fv1, pw1 - fw1);

        enc[(size_t)l * n + i0] = __floats2half2_rn(fA.x * ENC_SCALE, fA.y * ENC_SCALE);
        if (has1) enc[(size_t)l * n + i1] = __floats2half2_rn(fB.x * ENC_SCALE, fB.y * ENC_SCALE);
    }
}

// ---------- Kernel A2: LEVEL-PHASED hash encode (11 phases) ----------
__global__ __launch_bounds__(NTHREADS, 8) void encode_hash(
    const float* __restrict__ x,
    const __half2* __restrict__ tbl,
    __half2* __restrict__ enc, int n, int nb)
{
    const int bid = blockIdx.x;
    const int lvl = NDENSE + bid / nb;        // uniform per block
    const int pb  = bid - (lvl - NDENSE) * nb;
    const int i0 = pb * (NTHREADS * PPT) + threadIdx.x;
    const int i1 = i0 + NTHREADS;
    if (i0 >= n) return;

    const float sc = LV.scale[lvl];
    const __half2* tl = tbl + (size_t)lvl * TBL_SIZE;

    const float u0 = (x[3 * i0 + 0] + 1.0f) * 0.5f;
    const float v0 = (x[3 * i0 + 1] + 1.0f) * 0.5f;
    const float w0 = (x[3 * i0 + 2] + 1.0f) * 0.5f;
    const float pu0 = u0 * sc + 0.5f, pv0 = v0 * sc + 0.5f, pw0 = w0 * sc + 0.5f;
    const float fu0 = floorf(pu0), fv0 = floorf(pv0), fw0 = floorf(pw0);

    const bool has1 = (i1 < n);
    const int j1 = has1 ? i1 : i0;
    const float u1 = (x[3 * j1 + 0] + 1.0f) * 0.5f;
    const float v1 = (x[3 * j1 + 1] + 1.0f) * 0.5f;
    const float w1 = (x[3 * j1 + 2] + 1.0f) * 0.5f;
    const float pu1 = u1 * sc + 0.5f, pv1 = v1 * sc + 0.5f, pw1 = w1 * sc + 0.5f;
    const float fu1 = floorf(pu1), fv1 = floorf(pv1), fw1 = floorf(pw1);

    const float2 fA = gather_hash(tl, (int)fu0, (int)fv0, (int)fw0,
                                  pu0 - fu0, pv0 - fv0, pw0 - fw0);
    const float2 fB = gather_hash(tl, (int)fu1, (int)fv1, (int)fw1,
                                  pu1 - fu1, pv1 - fv1, pw1 - fw1);

    enc[(size_t)lvl * n + i0] = __floats2half2_rn(fA.x * ENC_SCALE, fA.y * ENC_SCALE);
    if (has1) enc[(size_t)lvl * n + i1] = __floats2half2_rn(fB.x * ENC_SCALE, fB.y * ENC_SCALE);
}

// ---------- Kernel B: MFMA MLP (transposed: h^T = W^T @ enc^T) ----------
__global__ __launch_bounds__(256) void mlp_mfma(
    const __half2* __restrict__ enc,
    const __half* __restrict__ w1f, const __half* __restrict__ w2f,
    const float* __restrict__ b1, const float* __restrict__ b2,
    const float* __restrict__ W3, const float* __restrict__ b3,
    float* __restrict__ out, int n)
{
    __shared__ __half lds_h1[4][64][18];
    const int wid  = threadIdx.x >> 6;
    const int lane = threadIdx.x & 63;
    const int tile = blockIdx.x * 4 + wid;
    const int pt = lane & 15;
    const int qw = lane >> 4;
    const int i = tile * 16 + pt;

    union { uint32_t u[4]; f16x8 v; } bf;
    #pragma unroll
    for (int jj = 0; jj < 4; ++jj)
        bf.u[jj] = *reinterpret_cast<const uint32_t*>(&enc[(size_t)(qw * 4 + jj) * n + i]);

    f32x4 c1[4];
    #pragma unroll
    for (int nt = 0; nt < 4; ++nt) {
        const float4 bb = *(const float4*)&b1[16 * nt + qw * 4];
        c1[nt][0] = bb.x * ENC_SCALE; c1[nt][1] = bb.y * ENC_SCALE;
        c1[nt][2] = bb.z * ENC_SCALE; c1[nt][3] = bb.w * ENC_SCALE;
        const f16x8 a = *reinterpret_cast<const f16x8*>(&w1f[(nt * 64 + lane) * 8]);
        c1[nt] = __builtin_amdgcn_mfma_f32_16x16x32_f16(a, bf.v, c1[nt], 0, 0, 0);
    }

    #pragma unroll
    for (int nt = 0; nt < 4; ++nt) {
        #pragma unroll
        for (int r = 0; r < 4; ++r) {
            const int o = 16 * nt + qw * 4 + r;
            lds_h1[wid][o][pt] = __float2half(fmaxf(c1[nt][r], 0.0f));
        }
    }

    f32x4 c2[4];
    #pragma unroll
    for (int nt = 0; nt < 4; ++nt) {
        const float4 bb = *(const float4*)&b2[16 * nt + qw * 4];
        c2[nt][0] = bb.x * ENC_SCALE; c2[nt][1] = bb.y * ENC_SCALE;
        c2[nt][2] = bb.z * ENC_SCALE; c2[nt][3] = bb.w * ENC_SCALE;
    }
    #pragma unroll
    for (int kb = 0; kb < 2; ++kb) {
        union { uint32_t u[4]; f16x8 v; } hb;
        #pragma unroll
        for (int j2 = 0; j2 < 4; ++j2) {
            const int k0 = kb * 32 + qw * 8 + 2 * j2;
            const uint32_t lo = __half_as_ushort(lds_h1[wid][k0][pt]);
            const uint32_t hi = __half_as_ushort(lds_h1[wid][k0 + 1][pt]);
            hb.u[j2] = lo | (hi << 16);
        }
        #pragma unroll
        for (int nt = 0; nt < 4; ++nt) {
            const f16x8 a = *reinterpret_cast<const f16x8*>(&w2f[((nt * 2 + kb) * 64 + lane) * 8]);
            c2[nt] = __builtin_amdgcn_mfma_f32_16x16x32_f16(a, hb.v, c2[nt], 0, 0, 0);
        }
    }

    float part = 0.0f;
    #pragma unroll
    for (int nt = 0; nt < 4; ++nt) {
        const float4 w3v = *(const float4*)&W3[16 * nt + qw * 4];
        part = fmaf(fmaxf(c2[nt][0], 0.0f), w3v.x, part);
        part = fmaf(fmaxf(c2[nt][1], 0.0f), w3v.y, part);
        part = fmaf(fmaxf(c2[nt][2], 0.0f), w3v.z, part);
        part = fmaf(fmaxf(c2[nt][3], 0.0f), w3v.w, part);
    }
    part += __shfl_xor(part, 16, 64);
    part += __shfl_xor(part, 32, 64);
    if (lane < 16) out[i] = part * ENC_INV + b3[0];
}

// ---------- Fallback: fused kernel (if ws too small for split) ----------
template <bool USE_H2>
__global__ __launch_bounds__(NTHREADS, 4) void sdf_tcnn_fused(
    const float* __restrict__ x,
    const void* __restrict__ tbl,
    const float* __restrict__ W1, const float* __restrict__ b1,
    const float* __restrict__ W2, const float* __restrict__ b2,
    const float* __restrict__ W3, const float* __restrict__ b3,
    float* __restrict__ out, int n)
{
    const int i = blockIdx.x * NTHREADS + threadIdx.x;
    if (i >= n) return;

    const float u = (x[3 * i + 0] + 1.0f) * 0.5f;
    const float v = (x[3 * i + 1] + 1.0f) * 0.5f;
    const float w = (x[3 * i + 2] + 1.0f) * 0.5f;

#define DECLH(m) float4 h##m = *(const float4*)&b1[4 * (m)];
    H16(DECLH)
#undef DECLH

    #pragma unroll
    for (int l = 0; l < NLVL; ++l) {
        const float sc = LV.scale[l];
        const int res = LV.res[l];
        const float pu = u * sc + 0.5f;
        const float pv = v * sc + 0.5f;
        const float pw = w * sc + 0.5f;
        const float fu = floorf(pu), fv = floorf(pv), fw = floorf(pw);
        const float wu = pu - fu, wv = pv - fv, ww = pw - fw;
        const int iu = (int)fu, iv = (int)fv, iw = (int)fw;

        int idx[8];
        #pragma unroll
        for (int b = 0; b < 8; ++b) {
            const int o0 = (b >> 2) & 1, o1 = (b >> 1) & 1, o2 = b & 1;
            if (LV.dense[l]) {
                idx[b] = (iu + o0) + (iv + o1) * res + (iw + o2) * (res * res);
            } else {
                const uint32_t c0 = (uint32_t)(iu + o0);
                const uint32_t c1 = (uint32_t)(iv + o1);
                const uint32_t c2 = (uint32_t)(iw + o2);
                const uint32_t h = c0 ^ (c1 * 2654435761u) ^ (c2 * 805459861u);
                idx[b] = (int)(h & (TBL_SIZE - 1u));
            }
        }

        float f0 = 0.0f, f1 = 0.0f;
        if constexpr (USE_H2) {
            const __half2* tl = (const __half2*)tbl + (size_t)l * TBL_SIZE;
            __half2 cfh[8];
            #pragma unroll
            for (int b = 0; b < 8; ++b) cfh[b] = tl[idx[b]];
            #pragma unroll
            for (int b = 0; b < 8; ++b) {
                const int o0 = (b >> 2) & 1, o1 = (b >> 1) & 1, o2 = b & 1;
                const float wt = (o0 ? wu : 1.0f - wu) *
                                 (o1 ? wv : 1.0f - wv) *
                                 (o2 ? ww : 1.0f - ww);
                const float2 cf = __half22float2(cfh[b]);
                f0 = fmaf(cf.x, wt, f0);
                f1 = fmaf(cf.y, wt, f1);
            }
        } else {
            const float2* tl = (const float2*)tbl + (size_t)l * TBL_SIZE;
            float2 cf[8];
            #pragma unroll
            for (int b = 0; b < 8; ++b) cf[b] = tl[idx[b]];
            #pragma unroll
            for (int b = 0; b < 8; ++b) {
                const int o0 = (b >> 2) & 1, o1 = (b >> 1) & 1, o2 = b & 1;
                const float wt = (o0 ? wu : 1.0f - wu) *
                                 (o1 ? wv : 1.0f - wv) *
                                 (o2 ? ww : 1.0f - ww);
                f0 = fmaf(cf[b].x, wt, f0);
                f1 = fmaf(cf[b].y, wt, f1);
            }
        }

        const float* wra = &W1[(2 * l) * HIDDEN];
        const float* wrb = &W1[(2 * l + 1) * HIDDEN];
#define UPDH(m) { \
        const float4 wa = *(const float4*)&wra[4 * (m)]; \
        const float4 wb = *(const float4*)&wrb[4 * (m)]; \
        h##m.x = fmaf(f0, wa.x, fmaf(f1, wb.x, h##m.x)); \
        h##m.y = fmaf(f0, wa.y, fmaf(f1, wb.y, h##m.y)); \
        h##m.z = fmaf(f0, wa.z, fmaf(f1, wb.z, h##m.z)); \
        h##m.w = fmaf(f0, wa.w, fmaf(f1, wb.w, h##m.w)); }
        H16(UPDH)
#undef UPDH
    }

#define RELUH(m) { h##m.x = fmaxf(h##m.x, 0.0f); h##m.y = fmaxf(h##m.y, 0.0f); \
                   h##m.z = fmaxf(h##m.z, 0.0f); h##m.w = fmaxf(h##m.w, 0.0f); }
    H16(RELUH)
#undef RELUH

    float acc = b3[0];
    #pragma unroll 2
    for (int jb = 0; jb < HIDDEN; jb += 4) {
        float4 t = *(const float4*)&b2[jb];
#define L2K(m) { \
        const float4 r0 = *(const float4*)&W2[(4 * (m) + 0) * HIDDEN + jb]; \
        const float4 r1 = *(const float4*)&W2[(4 * (m) + 1) * HIDDEN + jb]; \
        const float4 r2 = *(const float4*)&W2[(4 * (m) + 2) * HIDDEN + jb]; \
        const float4 r3 = *(const float4*)&W2[(4 * (m) + 3) * HIDDEN + jb]; \
        t.x = fmaf(h##m.x, r0.x, t.x); t.y = fmaf(h##m.x, r0.y, t.y); \
        t.z = fmaf(h##m.x, r0.z, t.z); t.w = fmaf(h##m.x, r0.w, t.w); \
        t.x = fmaf(h##m.y, r1.x, t.x); t.y = fmaf(h##m.y, r1.y, t.y); \
        t.z = fmaf(h##m.y, r1.z, t.z); t.w = fmaf(h##m.y, r1.w, t.w); \
        t.x = fmaf(h##m.z, r2.x, t.x); t.y = fmaf(h##m.z, r2.y, t.y); \
        t.z = fmaf(h##m.z, r2.z, t.z); t.w = fmaf(h##m.z, r2.w, t.w); \
        t.x = fmaf(h##m.w, r3.x, t.x); t.y = fmaf(h##m.w, r3.y, t.y); \
        t.z = fmaf(h##m.w, r3.z, t.z); t.w = fmaf(h##m.w, r3.w, t.w); }
        H16(L2K)
#undef L2K
        const float4 w3v = *(const float4*)&W3[jb];
        acc = fmaf(fmaxf(t.x, 0.0f), w3v.x, acc);
        acc = fmaf(fmaxf(t.y, 0.0f), w3v.y, acc);
        acc = fmaf(fmaxf(t.z, 0.0f), w3v.z, acc);
        acc = fmaf(fmaxf(t.w, 0.0f), w3v.w, acc);
    }

    out[i] = acc;
}

extern "C" void kernel_launch(void* const* d_in, const int* in_sizes, int n_in,
                              void* d_out, int out_size, void* d_ws, size_t ws_size,
                              hipStream_t stream) {
    const float* x     = (const float*)d_in[0];
    const float* table = (const float*)d_in[1];
    const float* W1    = (const float*)d_in[2];
    const float* b1    = (const float*)d_in[3];
    const float* W2    = (const float*)d_in[4];
    const float* b2    = (const float*)d_in[5];
    const float* W3    = (const float*)d_in[6];
    const float* b3    = (const float*)d_in[7];
    float* out = (float*)d_out;

    const int n = in_sizes[0] / 3;
    const int n_entries = NLVL * (int)TBL_SIZE;
    const size_t tbl_bytes   = (size_t)n_entries * sizeof(__half2);        // 33.6 MB
    const size_t quad_bytes  = (size_t)PO.total * 16;                      // ~13.2 MB
    const size_t wfrag_bytes = 16384;                                      // w1f 4KB + w2f 8KB
    const size_t enc_bytes   = (size_t)NLVL * (size_t)n * sizeof(__half2); // 64 MB
    const int nb_mlp = (n + NTHREADS - 1) / NTHREADS;
    const int nb_enc = (n + NTHREADS * PPT - 1) / (NTHREADS * PPT);

    if (ws_size >= tbl_bytes + quad_bytes + wfrag_bytes + enc_bytes) {
        __half2* tbl_h2 = (__half2*)d_ws;
        uint4* qd = (uint4*)((char*)d_ws + tbl_bytes);
        __half* w1f = (__half*)((char*)d_ws + tbl_bytes + quad_bytes);
        __half* w2f = w1f + 4 * 64 * 8;
        __half2* enc = (__half2*)((char*)d_ws + tbl_bytes + quad_bytes + wfrag_bytes);

        // fp16 repack: hash levels only (dense served entirely by quads)
        hipLaunchKernelGGL(cvt_table, dim3(2048), dim3(256), 0, stream,
                           (const float2*)table + (size_t)NDENSE * TBL_SIZE,
                           tbl_h2 + (size_t)NDENSE * TBL_SIZE,
                           NHASH * (int)TBL_SIZE);
        hipLaunchKernelGGL(cvt_quads, dim3((PO.total + 255) / 256), dim3(256), 0, stream,
                           (const float2*)table, qd);
        hipLaunchKernelGGL(cvt_wfrags, dim3(16), dim3(256), 0, stream,
                           W1, W2, w1f, w2f);
        hipLaunchKernelGGL(encode_dense, dim3(nb_enc), dim3(NTHREADS), 0, stream,
                           x, qd, enc, n);
        hipLaunchKernelGGL(encode_hash, dim3(nb_enc * NHASH), dim3(NTHREADS), 0, stream,
                           x, tbl_h2, enc, n, nb_enc);
        hipLaunchKernelGGL(mlp_mfma, dim3((n + 63) / 64), dim3(256), 0, stream,
                           enc, w1f, w2f, b1, b2, W3, b3, out, n);
    } else {
        hipLaunchKernelGGL((sdf_tcnn_fused<false>), dim3(nb_mlp), dim3(NTHREADS), 0, stream,
                           x, (const void*)table, W1, b1, W2, b2, W3, b3, out, n);
    }
}

// Round 14
// 307.527 us; speedup vs baseline: 2.6192x; 1.0441x over previous
//
#include <hip/hip_runtime.h>
#include <hip/hip_fp16.h>
#include <cstdint>

#define NTHREADS 256
#define TBL_SIZE (1u << 19)
#define HIDDEN 64
#define NLVL 16
#define NDENSE 5          // levels 0..4 dense; 5..15 hashed
#define NHASH (NLVL - NDENSE)
#define PPT 2
#define ENC_SCALE 256.0f  // exact pow2: keeps fp16 enc/h1 in normal range for MFMA
#define ENC_INV (1.0f / 256.0f)
#define MLP_TPW 4         // tiles per wave in mlp (weight regs amortized)

struct Levels { float scale[16]; int res[16]; int dense[16]; };
constexpr Levels make_levels() {
    Levels L{};
    double s = 16.0;
    for (int l = 0; l < 16; ++l) {
        double sc = s - 1.0;
        L.scale[l] = (float)sc;
        int fi = (int)sc;
        int res = fi + (((double)fi < sc) ? 1 : 0) + 1;   // ceil(sc)+1
        L.res[l] = res;
        L.dense[l] = ((long long)res * res * res <= (long long)TBL_SIZE) ? 1 : 0;
        s *= 1.3819;
    }
    return L;
}
constexpr Levels LV = make_levels();
static_assert(LV.dense[NDENSE - 1] == 1 && LV.dense[NDENSE] == 0, "dense split");

// quad-table offsets for dense levels (16B entries); region covers tcnn's
// unclamped dense indexing up to res(1+res+res^2) (round-9 lesson).
struct PairOffs { int off[17]; int total; };
constexpr PairOffs make_pairoffs() {
    PairOffs P{}; int o = 0;
    for (int l = 0; l < 16; ++l) {
        P.off[l] = o;
        if (LV.dense[l]) {
            const int r = LV.res[l];
            o += r * (1 + r + r * r) + 2;
        }
    }
    P.off[16] = o; P.total = o;
    return P;
}
constexpr PairOffs PO = make_pairoffs();

// l5 linearized quad table: l5 is hashed (81^3 slightly > T) but only 538k
// cells -> dense re-tabulation of hashed values, 2 requests/pt instead of 6.
constexpr int RES5 = LV.res[NDENSE];
constexpr int QD5_TOTAL = RES5 * (1 + RES5 + RES5 * RES5) + 2;

#define H16(M) M(0) M(1) M(2) M(3) M(4) M(5) M(6) M(7) \
               M(8) M(9) M(10) M(11) M(12) M(13) M(14) M(15)

typedef _Float16 f16x8 __attribute__((ext_vector_type(8)));
typedef float f32x4 __attribute__((ext_vector_type(4)));

static __device__ __forceinline__ __half2 u32_h2(uint32_t u) {
    union { uint32_t u; __half2 h; } c; c.u = u; return c.h;
}
static __device__ __forceinline__ uint32_t h2_u32(__half2 h) {
    union { __half2 h; uint32_t u; } c; c.h = h; return c.u;
}
static __device__ __forceinline__ uint32_t hash3(uint32_t c0, uint32_t c1, uint32_t c2) {
    return (c0 ^ (c1 * 2654435761u) ^ (c2 * 805459861u)) & (TBL_SIZE - 1u);
}

// ---------- merged conversion kernel (one launch) ----------
// seg1: fp16 repack of hash levels; seg2: dense quads; seg3: l5 quad retab;
// seg4: W1/W2 MFMA A-fragment packs.
__global__ __launch_bounds__(256) void cvt_all(
    const float2* __restrict__ tf, __half2* __restrict__ tbl_h2,
    uint4* __restrict__ qd, uint4* __restrict__ qd5,
    const float* __restrict__ W1, const float* __restrict__ W2,
    __half* __restrict__ w1f, __half* __restrict__ w2f, int use_qd5)
{
    const int gid = blockIdx.x * 256 + threadIdx.x;
    const int stride = gridDim.x * 256;

    // seg1: hash-level fp16 repack
    const int W_tbl = NHASH * (int)TBL_SIZE;
    const float2* tf_h = tf + (size_t)NDENSE * TBL_SIZE;
    __half2* th_h = tbl_h2 + (size_t)NDENSE * TBL_SIZE;
    for (int i = gid; i < W_tbl; i += stride) {
        const float2 v = tf_h[i];
        th_h[i] = __floats2half2_rn(v.x, v.y);
    }

    // seg2: dense-level quads straight from f32 table
    for (int i = gid; i < PO.total; i += stride) {
        int lvl = 0;
        #pragma unroll
        for (int l = 0; l < NDENSE; ++l)
            if (i >= PO.off[l] && i < PO.off[l + 1]) lvl = l;
        const int local = i - PO.off[lvl];
        const int res = LV.res[lvl];
        const float2* base = tf + (size_t)lvl * TBL_SIZE + local;
        uint4 q;
        q.x = h2_u32(__floats2half2_rn(base[0].x, base[0].y));
        q.y = h2_u32(__floats2half2_rn(base[1].x, base[1].y));
        q.z = h2_u32(__floats2half2_rn(base[res].x, base[res].y));
        q.w = h2_u32(__floats2half2_rn(base[res + 1].x, base[res + 1].y));
        qd[i] = q;
    }

    // seg3: l5 linearized quads (hash each corner, tabulate densely)
    if (use_qd5) {
        const float2* t5 = tf + (size_t)NDENSE * TBL_SIZE;
        for (int i = gid; i < QD5_TOTAL; i += stride) {
            const uint32_t c2 = (uint32_t)i / (uint32_t)(RES5 * RES5);
            const uint32_t rem = (uint32_t)i % (uint32_t)(RES5 * RES5);
            const uint32_t c1 = rem / (uint32_t)RES5;
            const uint32_t c0 = rem % (uint32_t)RES5;
            const float2 a = t5[hash3(c0, c1, c2)];
            const float2 b = t5[hash3(c0 + 1, c1, c2)];
            const float2 c = t5[hash3(c0, c1 + 1, c2)];
            const float2 d = t5[hash3(c0 + 1, c1 + 1, c2)];
            uint4 q;
            q.x = h2_u32(__floats2half2_rn(a.x, a.y));
            q.y = h2_u32(__floats2half2_rn(b.x, b.y));
            q.z = h2_u32(__floats2half2_rn(c.x, c.y));
            q.w = h2_u32(__floats2half2_rn(d.x, d.y));
            qd5[i] = q;
        }
    }

    // seg4: W1^T/W2^T A-frag packs
    for (int i = gid; i < 4 * 64 * 8; i += stride) {
        const int j = i & 7, lane = (i >> 3) & 63, nt = i >> 9;
        const int k = (lane >> 4) * 8 + j;
        const int o = (lane & 15) + 16 * nt;
        w1f[i] = __float2half(W1[k * HIDDEN + o]);
    }
    for (int i = gid; i < 4 * 2 * 64 * 8; i += stride) {
        const int j = i & 7, lane = (i >> 3) & 63, kb = (i >> 9) & 1, nt = i >> 10;
        const int k = 32 * kb + (lane >> 4) * 8 + j;
        const int o = (lane & 15) + 16 * nt;
        w2f[i] = __float2half(W2[k * HIDDEN + o]);
    }
}

// dense-style gather via quads: 2x 16B loads, bilinear xy + lerp z
static __device__ __forceinline__ float2 gather_dense(
    const uint4* __restrict__ qd, int res, int doff,
    int iu, int iv, int iw, float wu, float wv, float ww)
{
    float f0 = 0.0f, f1 = 0.0f;
    const float lx = 1.0f - wu;
    const int base = iu + iv * res + iw * res * res;
    #pragma unroll
    for (int o2 = 0; o2 < 2; ++o2) {
        const int idx = base + (o2 ? res * res : 0);
        const uint4 q = qd[doff + idx];
        const float2 a = __half22float2(u32_h2(q.x));   // (0,0)
        const float2 b = __half22float2(u32_h2(q.y));   // (1,0)
        const float2 c = __half22float2(u32_h2(q.z));   // (0,1)
        const float2 d = __half22float2(u32_h2(q.w));   // (1,1)
        const float x0l = fmaf(lx, a.x, wu * b.x);
        const float x1l = fmaf(lx, c.x, wu * d.x);
        const float y0l = fmaf(lx, a.y, wu * b.y);
        const float y1l = fmaf(lx, c.y, wu * d.y);
        const float bil0 = fmaf(1.0f - wv, x0l, wv * x1l);
        const float bil1 = fmaf(1.0f - wv, y0l, wv * y1l);
        const float wz = o2 ? ww : 1.0f - ww;
        f0 = fmaf(bil0, wz, f0);
        f1 = fmaf(bil1, wz, f1);
    }
    return make_float2(f0, f1);
}

// hash gather: iu even -> 4x 8B pair loads (h^1 trick); iu odd -> 8x 4B loads
static __device__ __forceinline__ float2 gather_hash(
    const __half2* __restrict__ tl,
    int iu, int iv, int iw, float wu, float wv, float ww)
{
    float f0 = 0.0f, f1 = 0.0f;
    const float lx = 1.0f - wu;
    const uint32_t r1a = (uint32_t)iv * 2654435761u;
    const uint32_t r1b = r1a + 2654435761u;
    const uint32_t r2a = (uint32_t)iw * 805459861u;
    const uint32_t r2b = r2a + 805459861u;
    if ((iu & 1) == 0) {
        #pragma unroll
        for (int b4 = 0; b4 < 4; ++b4) {
            const int o1 = (b4 >> 1) & 1, o2 = b4 & 1;
            const uint32_t rest = (o1 ? r1b : r1a) ^ (o2 ? r2b : r2a);
            const uint32_t h0 = ((uint32_t)iu ^ rest) & (TBL_SIZE - 1u);
            const unsigned long long pr =
                *reinterpret_cast<const unsigned long long*>(tl + (h0 & ~1u));
            const uint32_t lo = (uint32_t)pr, hi = (uint32_t)(pr >> 32);
            const uint32_t sel = h0 & 1u;
            const float2 a = __half22float2(u32_h2(sel ? hi : lo)); // c0
            const float2 b = __half22float2(u32_h2(sel ? lo : hi)); // c1
            const float wyz = (o1 ? wv : 1.0f - wv) * (o2 ? ww : 1.0f - ww);
            f0 = fmaf(fmaf(lx, a.x, wu * b.x), wyz, f0);
            f1 = fmaf(fmaf(lx, a.y, wu * b.y), wyz, f1);
        }
    } else {
        #pragma unroll
        for (int b4 = 0; b4 < 4; ++b4) {
            const int o1 = (b4 >> 1) & 1, o2 = b4 & 1;
            const uint32_t rest = (o1 ? r1b : r1a) ^ (o2 ? r2b : r2a);
            const uint32_t h0 = ((uint32_t)iu ^ rest) & (TBL_SIZE - 1u);
            const uint32_t h1 = ((uint32_t)(iu + 1) ^ rest) & (TBL_SIZE - 1u);
            const float2 a = __half22float2(tl[h0]);
            const float2 b = __half22float2(tl[h1]);
            const float wyz = (o1 ? wv : 1.0f - wv) * (o2 ? ww : 1.0f - ww);
            f0 = fmaf(fmaf(lx, a.x, wu * b.x), wyz, f0);
            f1 = fmaf(fmaf(lx, a.y, wu * b.y), wyz, f1);
        }
    }
    return make_float2(f0, f1);
}

// ---------- Kernel A1: ALL dense levels in ONE phase ----------
__global__ __launch_bounds__(NTHREADS, 8) void encode_dense(
    const float* __restrict__ x,
    const uint4* __restrict__ qd,
    __half2* __restrict__ enc, int n)
{
    const int i0 = blockIdx.x * (NTHREADS * PPT) + threadIdx.x;
    const int i1 = i0 + NTHREADS;
    if (i0 >= n) return;

    const float u0 = (x[3 * i0 + 0] + 1.0f) * 0.5f;
    const float v0 = (x[3 * i0 + 1] + 1.0f) * 0.5f;
    const float w0 = (x[3 * i0 + 2] + 1.0f) * 0.5f;
    const bool has1 = (i1 < n);
    const int j1 = has1 ? i1 : i0;
    const float u1 = (x[3 * j1 + 0] + 1.0f) * 0.5f;
    const float v1 = (x[3 * j1 + 1] + 1.0f) * 0.5f;
    const float w1 = (x[3 * j1 + 2] + 1.0f) * 0.5f;

    #pragma unroll
    for (int l = 0; l < NDENSE; ++l) {
        const float sc = LV.scale[l];
        const int res = LV.res[l];
        const int doff = PO.off[l];

        const float pu0 = u0 * sc + 0.5f, pv0 = v0 * sc + 0.5f, pw0 = w0 * sc + 0.5f;
        const float fu0 = floorf(pu0), fv0 = floorf(pv0), fw0 = floorf(pw0);
        const float2 fA = gather_dense(qd, res, doff, (int)fu0, (int)fv0, (int)fw0,
                                       pu0 - fu0, pv0 - fv0, pw0 - fw0);
        const float pu1 = u1 * sc + 0.5f, pv1 = v1 * sc + 0.5f, pw1 = w1 * sc + 0.5f;
        const float fu1 = floorf(pu1), fv1 = floorf(pv1), fw1 = floorf(pw1);
        const float2 fB = gather_dense(qd, res, doff, (int)fu1, (int)fv1, (int)fw1,
                                       pu1 - fu1, pv1 - fv1, pw1 - fw1);

        enc[(size_t)l * n + i0] = __floats2half2_rn(fA.x * ENC_SCALE, fA.y * ENC_SCALE);
        if (has1) enc[(size_t)l * n + i1] = __floats2half2_rn(fB.x * ENC_SCALE, fB.y * ENC_SCALE);
    }
}

// ---------- Kernel A2: LEVEL-PHASED hash encode; l5 optionally quad-served ----------
__global__ __launch_bounds__(NTHREADS, 8) void encode_hash(
    const float* __restrict__ x,
    const __half2* __restrict__ tbl,
    const uint4* __restrict__ qd5, int use_qd5,
    __half2* __restrict__ enc, int n, int nb)
{
    const int bid = blockIdx.x;
    const int lvl = NDENSE + bid / nb;        // uniform per block
    const int pb  = bid - (lvl - NDENSE) * nb;
    const int i0 = pb * (NTHREADS * PPT) + threadIdx.x;
    const int i1 = i0 + NTHREADS;
    if (i0 >= n) return;

    const float sc = LV.scale[lvl];
    const __half2* tl = tbl + (size_t)lvl * TBL_SIZE;

    const float u0 = (x[3 * i0 + 0] + 1.0f) * 0.5f;
    const float v0 = (x[3 * i0 + 1] + 1.0f) * 0.5f;
    const float w0 = (x[3 * i0 + 2] + 1.0f) * 0.5f;
    const float pu0 = u0 * sc + 0.5f, pv0 = v0 * sc + 0.5f, pw0 = w0 * sc + 0.5f;
    const float fu0 = floorf(pu0), fv0 = floorf(pv0), fw0 = floorf(pw0);

    const bool has1 = (i1 < n);
    const int j1 = has1 ? i1 : i0;
    const float u1 = (x[3 * j1 + 0] + 1.0f) * 0.5f;
    const float v1 = (x[3 * j1 + 1] + 1.0f) * 0.5f;
    const float w1 = (x[3 * j1 + 2] + 1.0f) * 0.5f;
    const float pu1 = u1 * sc + 0.5f, pv1 = v1 * sc + 0.5f, pw1 = w1 * sc + 0.5f;
    const float fu1 = floorf(pu1), fv1 = floorf(pv1), fw1 = floorf(pw1);

    float2 fA, fB;
    if (lvl == NDENSE && use_qd5) {           // block-uniform branch
        fA = gather_dense(qd5, RES5, 0, (int)fu0, (int)fv0, (int)fw0,
                          pu0 - fu0, pv0 - fv0, pw0 - fw0);
        fB = gather_dense(qd5, RES5, 0, (int)fu1, (int)fv1, (int)fw1,
                          pu1 - fu1, pv1 - fv1, pw1 - fw1);
    } else {
        fA = gather_hash(tl, (int)fu0, (int)fv0, (int)fw0,
                         pu0 - fu0, pv0 - fv0, pw0 - fw0);
        fB = gather_hash(tl, (int)fu1, (int)fv1, (int)fw1,
                         pu1 - fu1, pv1 - fv1, pw1 - fw1);
    }

    enc[(size_t)lvl * n + i0] = __floats2half2_rn(fA.x * ENC_SCALE, fA.y * ENC_SCALE);
    if (has1) enc[(size_t)lvl * n + i1] = __floats2half2_rn(fB.x * ENC_SCALE, fB.y * ENC_SCALE);
}

// ---------- Kernel B: MFMA MLP, 4 tiles/wave (weights held in registers) ----------
__global__ __launch_bounds__(256, 3) void mlp_mfma(
    const __half2* __restrict__ enc,
    const __half* __restrict__ w1f, const __half* __restrict__ w2f,
    const float* __restrict__ b1, const float* __restrict__ b2,
    const float* __restrict__ W3, const float* __restrict__ b3,
    float* __restrict__ out, int n)
{
    __shared__ __half lds_h1[4][64][18];
    const int wid  = threadIdx.x >> 6;
    const int lane = threadIdx.x & 63;
    const int pt = lane & 15;
    const int qw = lane >> 4;

    // A-frags and biases loaded ONCE per wave, reused across MLP_TPW tiles
    f16x8 a1[4];
    #pragma unroll
    for (int nt = 0; nt < 4; ++nt)
        a1[nt] = *reinterpret_cast<const f16x8*>(&w1f[(nt * 64 + lane) * 8]);
    f16x8 a2[8];
    #pragma unroll
    for (int q8 = 0; q8 < 8; ++q8)
        a2[q8] = *reinterpret_cast<const f16x8*>(&w2f[(q8 * 64 + lane) * 8]);

    float4 bb1[4], bb2[4], w3v[4];
    #pragma unroll
    for (int nt = 0; nt < 4; ++nt) {
        const float4 t1 = *(const float4*)&b1[16 * nt + qw * 4];
        bb1[nt] = make_float4(t1.x * ENC_SCALE, t1.y * ENC_SCALE, t1.z * ENC_SCALE, t1.w * ENC_SCALE);
        const float4 t2 = *(const float4*)&b2[16 * nt + qw * 4];
        bb2[nt] = make_float4(t2.x * ENC_SCALE, t2.y * ENC_SCALE, t2.z * ENC_SCALE, t2.w * ENC_SCALE);
        w3v[nt] = *(const float4*)&W3[16 * nt + qw * 4];
    }
    const float b3s = b3[0];

    const int base_tile = (blockIdx.x * 4 + wid) * MLP_TPW;

    #pragma unroll
    for (int t = 0; t < MLP_TPW; ++t) {
        const int i = (base_tile + t) * 16 + pt;
        const int ic = (i < n) ? i : (n - 1);   // clamp loads; stores guarded

        union { uint32_t u[4]; f16x8 v; } bf;
        #pragma unroll
        for (int jj = 0; jj < 4; ++jj)
            bf.u[jj] = *reinterpret_cast<const uint32_t*>(&enc[(size_t)(qw * 4 + jj) * n + ic]);

        f32x4 c1[4];
        #pragma unroll
        for (int nt = 0; nt < 4; ++nt) {
            c1[nt][0] = bb1[nt].x; c1[nt][1] = bb1[nt].y;
            c1[nt][2] = bb1[nt].z; c1[nt][3] = bb1[nt].w;
            c1[nt] = __builtin_amdgcn_mfma_f32_16x16x32_f16(a1[nt], bf.v, c1[nt], 0, 0, 0);
        }

        #pragma unroll
        for (int nt = 0; nt < 4; ++nt) {
            #pragma unroll
            for (int r = 0; r < 4; ++r) {
                const int o = 16 * nt + qw * 4 + r;
                lds_h1[wid][o][pt] = __float2half(fmaxf(c1[nt][r], 0.0f));
            }
        }

        f32x4 c2[4];
        #pragma unroll
        for (int nt = 0; nt < 4; ++nt) {
            c2[nt][0] = bb2[nt].x; c2[nt][1] = bb2[nt].y;
            c2[nt][2] = bb2[nt].z; c2[nt][3] = bb2[nt].w;
        }
        #pragma unroll
        for (int kb = 0; kb < 2; ++kb) {
            union { uint32_t u[4]; f16x8 v; } hb;
            #pragma unroll
            for (int j2 = 0; j2 < 4; ++j2) {
                const int k0 = kb * 32 + qw * 8 + 2 * j2;
                const uint32_t lo = __half_as_ushort(lds_h1[wid][k0][pt]);
                const uint32_t hi = __half_as_ushort(lds_h1[wid][k0 + 1][pt]);
                hb.u[j2] = lo | (hi << 16);
            }
            #pragma unroll
            for (int nt = 0; nt < 4; ++nt)
                c2[nt] = __builtin_amdgcn_mfma_f32_16x16x32_f16(a2[nt * 2 + kb], hb.v, c2[nt], 0, 0, 0);
        }

        float part = 0.0f;
        #pragma unroll
        for (int nt = 0; nt < 4; ++nt) {
            part = fmaf(fmaxf(c2[nt][0], 0.0f), w3v[nt].x, part);
            part = fmaf(fmaxf(c2[nt][1], 0.0f), w3v[nt].y, part);
            part = fmaf(fmaxf(c2[nt][2], 0.0f), w3v[nt].z, part);
            part = fmaf(fmaxf(c2[nt][3], 0.0f), w3v[nt].w, part);
        }
        part += __shfl_xor(part, 16, 64);
        part += __shfl_xor(part, 32, 64);
        if (lane < 16 && i < n) out[i] = part * ENC_INV + b3s;
    }
}

// ---------- Fallback: fused kernel (ws too small) ----------
__global__ __launch_bounds__(NTHREADS, 4) void sdf_tcnn_fused(
    const float* __restrict__ x,
    const float* __restrict__ tblf,
    const float* __restrict__ W1, const float* __restrict__ b1,
    const float* __restrict__ W2, const float* __restrict__ b2,
    const float* __restrict__ W3, const float* __restrict__ b3,
    float* __restrict__ out, int n)
{
    const int i = blockIdx.x * NTHREADS + threadIdx.x;
    if (i >= n) return;

    const float u = (x[3 * i + 0] + 1.0f) * 0.5f;
    const float v = (x[3 * i + 1] + 1.0f) * 0.5f;
    const float w = (x[3 * i + 2] + 1.0f) * 0.5f;

#define DECLH(m) float4 h##m = *(const float4*)&b1[4 * (m)];
    H16(DECLH)
#undef DECLH

    #pragma unroll
    for (int l = 0; l < NLVL; ++l) {
        const float sc = LV.scale[l];
        const int res = LV.res[l];
        const float pu = u * sc + 0.5f;
        const float pv = v * sc + 0.5f;
        const float pw = w * sc + 0.5f;
        const float fu = floorf(pu), fv = floorf(pv), fw = floorf(pw);
        const float wu = pu - fu, wv = pv - fv, ww = pw - fw;
        const int iu = (int)fu, iv = (int)fv, iw = (int)fw;

        int idx[8];
        #pragma unroll
        for (int b = 0; b < 8; ++b) {
            const int o0 = (b >> 2) & 1, o1 = (b >> 1) & 1, o2 = b & 1;
            if (LV.dense[l]) {
                idx[b] = (iu + o0) + (iv + o1) * res + (iw + o2) * (res * res);
            } else {
                idx[b] = (int)hash3((uint32_t)(iu + o0), (uint32_t)(iv + o1), (uint32_t)(iw + o2));
            }
        }
        const float2* tl = (const float2*)tblf + (size_t)l * TBL_SIZE;
        float2 cf[8];
        #pragma unroll
        for (int b = 0; b < 8; ++b) cf[b] = tl[idx[b]];
        float f0 = 0.0f, f1 = 0.0f;
        #pragma unroll
        for (int b = 0; b < 8; ++b) {
            const int o0 = (b >> 2) & 1, o1 = (b >> 1) & 1, o2 = b & 1;
            const float wt = (o0 ? wu : 1.0f - wu) *
                             (o1 ? wv : 1.0f - wv) *
                             (o2 ? ww : 1.0f - ww);
            f0 = fmaf(cf[b].x, wt, f0);
            f1 = fmaf(cf[b].y, wt, f1);
        }

        const float* wra = &W1[(2 * l) * HIDDEN];
        const float* wrb = &W1[(2 * l + 1) * HIDDEN];
#define UPDH(m) { \
        const float4 wa = *(const float4*)&wra[4 * (m)]; \
        const float4 wb = *(const float4*)&wrb[4 * (m)]; \
        h##m.x = fmaf(f0, wa.x, fmaf(f1, wb.x, h##m.x)); \
        h##m.y = fmaf(f0, wa.y, fmaf(f1, wb.y, h##m.y)); \
        h##m.z = fmaf(f0, wa.z, fmaf(f1, wb.z, h##m.z)); \
        h##m.w = fmaf(f0, wa.w, fmaf(f1, wb.w, h##m.w)); }
        H16(UPDH)
#undef UPDH
    }

#define RELUH(m) { h##m.x = fmaxf(h##m.x, 0.0f); h##m.y = fmaxf(h##m.y, 0.0f); \
                   h##m.z = fmaxf(h##m.z, 0.0f); h##m.w = fmaxf(h##m.w, 0.0f); }
    H16(RELUH)
#undef RELUH

    float acc = b3[0];
    #pragma unroll 2
    for (int jb = 0; jb < HIDDEN; jb += 4) {
        float4 t = *(const float4*)&b2[jb];
#define L2K(m) { \
        const float4 r0 = *(const float4*)&W2[(4 * (m) + 0) * HIDDEN + jb]; \
        const float4 r1 = *(const float4*)&W2[(4 * (m) + 1) * HIDDEN + jb]; \
        const float4 r2 = *(const float4*)&W2[(4 * (m) + 2) * HIDDEN + jb]; \
        const float4 r3 = *(const float4*)&W2[(4 * (m) + 3) * HIDDEN + jb]; \
        t.x = fmaf(h##m.x, r0.x, t.x); t.y = fmaf(h##m.x, r0.y, t.y); \
        t.z = fmaf(h##m.x, r0.z, t.z); t.w = fmaf(h##m.x, r0.w, t.w); \
        t.x = fmaf(h##m.y, r1.x, t.x); t.y = fmaf(h##m.y, r1.y, t.y); \
        t.z = fmaf(h##m.y, r1.z, t.z); t.w = fmaf(h##m.y, r1.w, t.w); \
        t.x = fmaf(h##m.z, r2.x, t.x); t.y = fmaf(h##m.z, r2.y, t.y); \
        t.z = fmaf(h##m.z, r2.z, t.z); t.w = fmaf(h##m.z, r2.w, t.w); \
        t.x = fmaf(h##m.w, r3.x, t.x); t.y = fmaf(h##m.w, r3.y, t.y); \
        t.z = fmaf(h##m.w, r3.z, t.z); t.w = fmaf(h##m.w, r3.w, t.w); }
        H16(L2K)
#undef L2K
        const float4 w3v = *(const float4*)&W3[jb];
        acc = fmaf(fmaxf(t.x, 0.0f), w3v.x, acc);
        acc = fmaf(fmaxf(t.y, 0.0f), w3v.y, acc);
        acc = fmaf(fmaxf(t.z, 0.0f), w3v.z, acc);
        acc = fmaf(fmaxf(t.w, 0.0f), w3v.w, acc);
    }

    out[i] = acc;
}

extern "C" void kernel_launch(void* const* d_in, const int* in_sizes, int n_in,
                              void* d_out, int out_size, void* d_ws, size_t ws_size,
                              hipStream_t stream) {
    const float* x     = (const float*)d_in[0];
    const float* table = (const float*)d_in[1];
    const float* W1    = (const float*)d_in[2];
    const float* b1    = (const float*)d_in[3];
    const float* W2    = (const float*)d_in[4];
    const float* b2    = (const float*)d_in[5];
    const float* W3    = (const float*)d_in[6];
    const float* b3    = (const float*)d_in[7];
    float* out = (float*)d_out;

    const int n = in_sizes[0] / 3;
    const size_t tbl_bytes   = (size_t)NLVL * TBL_SIZE * sizeof(__half2);   // 33.6 MB
    const size_t quad_bytes  = (size_t)PO.total * 16;                       // ~13.2 MB
    const size_t qd5_bytes   = (size_t)QD5_TOTAL * 16;                      // ~8.6 MB
    const size_t wfrag_bytes = 16384;
    const size_t enc_bytes   = (size_t)NLVL * (size_t)n * sizeof(__half2);  // 64 MB
    const size_t base_need   = tbl_bytes + quad_bytes + wfrag_bytes + enc_bytes;
    const int nb_enc = (n + NTHREADS * PPT - 1) / (NTHREADS * PPT);

    if (ws_size >= base_need) {
        const int use_qd5 = (ws_size >= base_need + qd5_bytes) ? 1 : 0;
        char* p = (char*)d_ws;
        __half2* tbl_h2 = (__half2*)p;                 p += tbl_bytes;
        uint4* qd = (uint4*)p;                         p += quad_bytes;
        __half* w1f = (__half*)p;                      p += 4 * 64 * 8 * sizeof(__half);
        __half* w2f = (__half*)p;                      p += 4 * 2 * 64 * 8 * sizeof(__half);
        __half2* enc = (__half2*)p;                    p += enc_bytes;
        uint4* qd5 = use_qd5 ? (uint4*)p : nullptr;

        hipLaunchKernelGGL(cvt_all, dim3(4096), dim3(256), 0, stream,
                           (const float2*)table, tbl_h2, qd, qd5, W1, W2, w1f, w2f, use_qd5);
        hipLaunchKernelGGL(encode_dense, dim3(nb_enc), dim3(NTHREADS), 0, stream,
                           x, qd, enc, n);
        hipLaunchKernelGGL(encode_hash, dim3(nb_enc * NHASH), dim3(NTHREADS), 0, stream,
                           x, tbl_h2, qd5, use_qd5, enc, n, nb_enc);
        hipLaunchKernelGGL(mlp_mfma, dim3((n + 16 * MLP_TPW * 4 - 1) / (16 * MLP_TPW * 4)),
                           dim3(256), 0, stream,
                           enc, w1f, w2f, b1, b2, W3, b3, out, n);
    } else {
        hipLaunchKernelGGL(sdf_tcnn_fused, dim3((n + NTHREADS - 1) / NTHREADS), dim3(NTHREADS), 0, stream,
                           x, table, W1, b1, W2, b2, W3, b3, out, n);
    }
}

// Round 15
// 302.734 us; speedup vs baseline: 2.6606x; 1.0158x over previous
//
#include <hip/hip_runtime.h>
#include <hip/hip_fp16.h>
#include <cstdint>

#define NTHREADS 256
#define TBL_SIZE (1u << 19)
#define HIDDEN 64
#define NLVL 16
#define NDENSE 5          // levels 0..4 dense; 5..15 hashed
#define NHASH (NLVL - NDENSE)
#define PPT 2
#define ENC_SCALE 256.0f  // exact pow2: keeps fp16 enc/h1 in normal range for MFMA
#define ENC_INV (1.0f / 256.0f)
#define MLP_TPW 4         // tiles per wave in mlp (weight regs amortized)

struct Levels { float scale[16]; int res[16]; int dense[16]; };
constexpr Levels make_levels() {
    Levels L{};
    double s = 16.0;
    for (int l = 0; l < 16; ++l) {
        double sc = s - 1.0;
        L.scale[l] = (float)sc;
        int fi = (int)sc;
        int res = fi + (((double)fi < sc) ? 1 : 0) + 1;   // ceil(sc)+1
        L.res[l] = res;
        L.dense[l] = ((long long)res * res * res <= (long long)TBL_SIZE) ? 1 : 0;
        s *= 1.3819;
    }
    return L;
}
constexpr Levels LV = make_levels();
static_assert(LV.dense[NDENSE - 1] == 1 && LV.dense[NDENSE] == 0, "dense split");

// quad-table offsets for dense levels (16B entries); region covers tcnn's
// unclamped dense indexing up to res(1+res+res^2) (round-9 lesson).
struct PairOffs { int off[17]; int total; };
constexpr PairOffs make_pairoffs() {
    PairOffs P{}; int o = 0;
    for (int l = 0; l < 16; ++l) {
        P.off[l] = o;
        if (LV.dense[l]) {
            const int r = LV.res[l];
            o += r * (1 + r + r * r) + 2;
        }
    }
    P.off[16] = o; P.total = o;
    return P;
}
constexpr PairOffs PO = make_pairoffs();

#define H16(M) M(0) M(1) M(2) M(3) M(4) M(5) M(6) M(7) \
               M(8) M(9) M(10) M(11) M(12) M(13) M(14) M(15)

typedef _Float16 f16x8 __attribute__((ext_vector_type(8)));
typedef float f32x4 __attribute__((ext_vector_type(4)));

static __device__ __forceinline__ __half2 u32_h2(uint32_t u) {
    union { uint32_t u; __half2 h; } c; c.u = u; return c.h;
}
static __device__ __forceinline__ uint32_t h2_u32(__half2 h) {
    union { __half2 h; uint32_t u; } c; c.h = h; return c.u;
}
static __device__ __forceinline__ uint32_t hash3(uint32_t c0, uint32_t c1, uint32_t c2) {
    return (c0 ^ (c1 * 2654435761u) ^ (c2 * 805459861u)) & (TBL_SIZE - 1u);
}

// ---------- merged conversion kernel (one launch) ----------
// seg1: fp16 repack of hash levels; seg2: dense quads; seg3: W-frag packs.
__global__ __launch_bounds__(256) void cvt_all(
    const float2* __restrict__ tf, __half2* __restrict__ tbl_h2,
    uint4* __restrict__ qd,
    const float* __restrict__ W1, const float* __restrict__ W2,
    __half* __restrict__ w1f, __half* __restrict__ w2f)
{
    const int gid = blockIdx.x * 256 + threadIdx.x;
    const int stride = gridDim.x * 256;

    // seg1: hash-level fp16 repack
    const int W_tbl = NHASH * (int)TBL_SIZE;
    const float2* tf_h = tf + (size_t)NDENSE * TBL_SIZE;
    __half2* th_h = tbl_h2 + (size_t)NDENSE * TBL_SIZE;
    for (int i = gid; i < W_tbl; i += stride) {
        const float2 v = tf_h[i];
        th_h[i] = __floats2half2_rn(v.x, v.y);
    }

    // seg2: dense-level quads straight from f32 table
    for (int i = gid; i < PO.total; i += stride) {
        int lvl = 0;
        #pragma unroll
        for (int l = 0; l < NDENSE; ++l)
            if (i >= PO.off[l] && i < PO.off[l + 1]) lvl = l;
        const int local = i - PO.off[lvl];
        const int res = LV.res[lvl];
        const float2* base = tf + (size_t)lvl * TBL_SIZE + local;
        uint4 q;
        q.x = h2_u32(__floats2half2_rn(base[0].x, base[0].y));
        q.y = h2_u32(__floats2half2_rn(base[1].x, base[1].y));
        q.z = h2_u32(__floats2half2_rn(base[res].x, base[res].y));
        q.w = h2_u32(__floats2half2_rn(base[res + 1].x, base[res + 1].y));
        qd[i] = q;
    }

    // seg3: W1^T/W2^T A-frag packs
    for (int i = gid; i < 4 * 64 * 8; i += stride) {
        const int j = i & 7, lane = (i >> 3) & 63, nt = i >> 9;
        const int k = (lane >> 4) * 8 + j;
        const int o = (lane & 15) + 16 * nt;
        w1f[i] = __float2half(W1[k * HIDDEN + o]);
    }
    for (int i = gid; i < 4 * 2 * 64 * 8; i += stride) {
        const int j = i & 7, lane = (i >> 3) & 63, kb = (i >> 9) & 1, nt = i >> 10;
        const int k = 32 * kb + (lane >> 4) * 8 + j;
        const int o = (lane & 15) + 16 * nt;
        w2f[i] = __float2half(W2[k * HIDDEN + o]);
    }
}

// dense-style gather via quads: 2x 16B loads, bilinear xy + lerp z
static __device__ __forceinline__ float2 gather_dense(
    const uint4* __restrict__ qd, int res, int doff,
    int iu, int iv, int iw, float wu, float wv, float ww)
{
    float f0 = 0.0f, f1 = 0.0f;
    const float lx = 1.0f - wu;
    const int base = iu + iv * res + iw * res * res;
    #pragma unroll
    for (int o2 = 0; o2 < 2; ++o2) {
        const int idx = base + (o2 ? res * res : 0);
        const uint4 q = qd[doff + idx];
        const float2 a = __half22float2(u32_h2(q.x));   // (0,0)
        const float2 b = __half22float2(u32_h2(q.y));   // (1,0)
        const float2 c = __half22float2(u32_h2(q.z));   // (0,1)
        const float2 d = __half22float2(u32_h2(q.w));   // (1,1)
        const float x0l = fmaf(lx, a.x, wu * b.x);
        const float x1l = fmaf(lx, c.x, wu * d.x);
        const float y0l = fmaf(lx, a.y, wu * b.y);
        const float y1l = fmaf(lx, c.y, wu * d.y);
        const float bil0 = fmaf(1.0f - wv, x0l, wv * x1l);
        const float bil1 = fmaf(1.0f - wv, y0l, wv * y1l);
        const float wz = o2 ? ww : 1.0f - ww;
        f0 = fmaf(bil0, wz, f0);
        f1 = fmaf(bil1, wz, f1);
    }
    return make_float2(f0, f1);
}

// hash gather: iu even -> 4x 8B pair loads (h^1 trick, PRIMES[0]==1);
// iu odd -> 8x 4B loads (corners straddle two aligned pairs; 8 is the floor)
static __device__ __forceinline__ float2 gather_hash(
    const __half2* __restrict__ tl,
    int iu, int iv, int iw, float wu, float wv, float ww)
{
    float f0 = 0.0f, f1 = 0.0f;
    const float lx = 1.0f - wu;
    const uint32_t r1a = (uint32_t)iv * 2654435761u;
    const uint32_t r1b = r1a + 2654435761u;
    const uint32_t r2a = (uint32_t)iw * 805459861u;
    const uint32_t r2b = r2a + 805459861u;
    if ((iu & 1) == 0) {
        #pragma unroll
        for (int b4 = 0; b4 < 4; ++b4) {
            const int o1 = (b4 >> 1) & 1, o2 = b4 & 1;
            const uint32_t rest = (o1 ? r1b : r1a) ^ (o2 ? r2b : r2a);
            const uint32_t h0 = ((uint32_t)iu ^ rest) & (TBL_SIZE - 1u);
            const unsigned long long pr =
                *reinterpret_cast<const unsigned long long*>(tl + (h0 & ~1u));
            const uint32_t lo = (uint32_t)pr, hi = (uint32_t)(pr >> 32);
            const uint32_t sel = h0 & 1u;
            const float2 a = __half22float2(u32_h2(sel ? hi : lo)); // c0
            const float2 b = __half22float2(u32_h2(sel ? lo : hi)); // c1
            const float wyz = (o1 ? wv : 1.0f - wv) * (o2 ? ww : 1.0f - ww);
            f0 = fmaf(fmaf(lx, a.x, wu * b.x), wyz, f0);
            f1 = fmaf(fmaf(lx, a.y, wu * b.y), wyz, f1);
        }
    } else {
        #pragma unroll
        for (int b4 = 0; b4 < 4; ++b4) {
            const int o1 = (b4 >> 1) & 1, o2 = b4 & 1;
            const uint32_t rest = (o1 ? r1b : r1a) ^ (o2 ? r2b : r2a);
            const uint32_t h0 = ((uint32_t)iu ^ rest) & (TBL_SIZE - 1u);
            const uint32_t h1 = ((uint32_t)(iu + 1) ^ rest) & (TBL_SIZE - 1u);
            const float2 a = __half22float2(tl[h0]);
            const float2 b = __half22float2(tl[h1]);
            const float wyz = (o1 ? wv : 1.0f - wv) * (o2 ? ww : 1.0f - ww);
            f0 = fmaf(fmaf(lx, a.x, wu * b.x), wyz, f0);
            f1 = fmaf(fmaf(lx, a.y, wu * b.y), wyz, f1);
        }
    }
    return make_float2(f0, f1);
}

// ---------- Kernel A1: ALL dense levels in ONE phase ----------
__global__ __launch_bounds__(NTHREADS, 8) void encode_dense(
    const float* __restrict__ x,
    const uint4* __restrict__ qd,
    __half2* __restrict__ enc, int n)
{
    const int i0 = blockIdx.x * (NTHREADS * PPT) + threadIdx.x;
    const int i1 = i0 + NTHREADS;
    if (i0 >= n) return;

    const float u0 = (x[3 * i0 + 0] + 1.0f) * 0.5f;
    const float v0 = (x[3 * i0 + 1] + 1.0f) * 0.5f;
    const float w0 = (x[3 * i0 + 2] + 1.0f) * 0.5f;
    const bool has1 = (i1 < n);
    const int j1 = has1 ? i1 : i0;
    const float u1 = (x[3 * j1 + 0] + 1.0f) * 0.5f;
    const float v1 = (x[3 * j1 + 1] + 1.0f) * 0.5f;
    const float w1 = (x[3 * j1 + 2] + 1.0f) * 0.5f;

    #pragma unroll
    for (int l = 0; l < NDENSE; ++l) {
        const float sc = LV.scale[l];
        const int res = LV.res[l];
        const int doff = PO.off[l];

        const float pu0 = u0 * sc + 0.5f, pv0 = v0 * sc + 0.5f, pw0 = w0 * sc + 0.5f;
        const float fu0 = floorf(pu0), fv0 = floorf(pv0), fw0 = floorf(pw0);
        const float2 fA = gather_dense(qd, res, doff, (int)fu0, (int)fv0, (int)fw0,
                                       pu0 - fu0, pv0 - fv0, pw0 - fw0);
        const float pu1 = u1 * sc + 0.5f, pv1 = v1 * sc + 0.5f, pw1 = w1 * sc + 0.5f;
        const float fu1 = floorf(pu1), fv1 = floorf(pv1), fw1 = floorf(pw1);
        const float2 fB = gather_dense(qd, res, doff, (int)fu1, (int)fv1, (int)fw1,
                                       pu1 - fu1, pv1 - fv1, pw1 - fw1);

        enc[(size_t)l * n + i0] = __floats2half2_rn(fA.x * ENC_SCALE, fA.y * ENC_SCALE);
        if (has1) enc[(size_t)l * n + i1] = __floats2half2_rn(fB.x * ENC_SCALE, fB.y * ENC_SCALE);
    }
}

// ---------- Kernel A2: LEVEL-PHASED hash encode (11 phases) ----------
__global__ __launch_bounds__(NTHREADS, 8) void encode_hash(
    const float* __restrict__ x,
    const __half2* __restrict__ tbl,
    __half2* __restrict__ enc, int n, int nb)
{
    const int bid = blockIdx.x;
    const int lvl = NDENSE + bid / nb;        // uniform per block
    const int pb  = bid - (lvl - NDENSE) * nb;
    const int i0 = pb * (NTHREADS * PPT) + threadIdx.x;
    const int i1 = i0 + NTHREADS;
    if (i0 >= n) return;

    const float sc = LV.scale[lvl];
    const __half2* tl = tbl + (size_t)lvl * TBL_SIZE;

    const float u0 = (x[3 * i0 + 0] + 1.0f) * 0.5f;
    const float v0 = (x[3 * i0 + 1] + 1.0f) * 0.5f;
    const float w0 = (x[3 * i0 + 2] + 1.0f) * 0.5f;
    const float pu0 = u0 * sc + 0.5f, pv0 = v0 * sc + 0.5f, pw0 = w0 * sc + 0.5f;
    const float fu0 = floorf(pu0), fv0 = floorf(pv0), fw0 = floorf(pw0);

    const bool has1 = (i1 < n);
    const int j1 = has1 ? i1 : i0;
    const float u1 = (x[3 * j1 + 0] + 1.0f) * 0.5f;
    const float v1 = (x[3 * j1 + 1] + 1.0f) * 0.5f;
    const float w1 = (x[3 * j1 + 2] + 1.0f) * 0.5f;
    const float pu1 = u1 * sc + 0.5f, pv1 = v1 * sc + 0.5f, pw1 = w1 * sc + 0.5f;
    const float fu1 = floorf(pu1), fv1 = floorf(pv1), fw1 = floorf(pw1);

    const float2 fA = gather_hash(tl, (int)fu0, (int)fv0, (int)fw0,
                                  pu0 - fu0, pv0 - fv0, pw0 - fw0);
    const float2 fB = gather_hash(tl, (int)fu1, (int)fv1, (int)fw1,
                                  pu1 - fu1, pv1 - fv1, pw1 - fw1);

    enc[(size_t)lvl * n + i0] = __floats2half2_rn(fA.x * ENC_SCALE, fA.y * ENC_SCALE);
    if (has1) enc[(size_t)lvl * n + i1] = __floats2half2_rn(fB.x * ENC_SCALE, fB.y * ENC_SCALE);
}

// ---------- Kernel B: MFMA MLP, 4 tiles/wave (weights held in registers) ----------
__global__ __launch_bounds__(256, 3) void mlp_mfma(
    const __half2* __restrict__ enc,
    const __half* __restrict__ w1f, const __half* __restrict__ w2f,
    const float* __restrict__ b1, const float* __restrict__ b2,
    const float* __restrict__ W3, const float* __restrict__ b3,
    float* __restrict__ out, int n)
{
    __shared__ __half lds_h1[4][64][18];
    const int wid  = threadIdx.x >> 6;
    const int lane = threadIdx.x & 63;
    const int pt = lane & 15;
    const int qw = lane >> 4;

    // A-frags and biases loaded ONCE per wave, reused across MLP_TPW tiles
    f16x8 a1[4];
    #pragma unroll
    for (int nt = 0; nt < 4; ++nt)
        a1[nt] = *reinterpret_cast<const f16x8*>(&w1f[(nt * 64 + lane) * 8]);
    f16x8 a2[8];
    #pragma unroll
    for (int q8 = 0; q8 < 8; ++q8)
        a2[q8] = *reinterpret_cast<const f16x8*>(&w2f[(q8 * 64 + lane) * 8]);

    float4 bb1[4], bb2[4], w3v[4];
    #pragma unroll
    for (int nt = 0; nt < 4; ++nt) {
        const float4 t1 = *(const float4*)&b1[16 * nt + qw * 4];
        bb1[nt] = make_float4(t1.x * ENC_SCALE, t1.y * ENC_SCALE, t1.z * ENC_SCALE, t1.w * ENC_SCALE);
        const float4 t2 = *(const float4*)&b2[16 * nt + qw * 4];
        bb2[nt] = make_float4(t2.x * ENC_SCALE, t2.y * ENC_SCALE, t2.z * ENC_SCALE, t2.w * ENC_SCALE);
        w3v[nt] = *(const float4*)&W3[16 * nt + qw * 4];
    }
    const float b3s = b3[0];

    const int base_tile = (blockIdx.x * 4 + wid) * MLP_TPW;

    #pragma unroll
    for (int t = 0; t < MLP_TPW; ++t) {
        const int i = (base_tile + t) * 16 + pt;
        const int ic = (i < n) ? i : (n - 1);   // clamp loads; stores guarded

        union { uint32_t u[4]; f16x8 v; } bf;
        #pragma unroll
        for (int jj = 0; jj < 4; ++jj)
            bf.u[jj] = *reinterpret_cast<const uint32_t*>(&enc[(size_t)(qw * 4 + jj) * n + ic]);

        f32x4 c1[4];
        #pragma unroll
        for (int nt = 0; nt < 4; ++nt) {
            c1[nt][0] = bb1[nt].x; c1[nt][1] = bb1[nt].y;
            c1[nt][2] = bb1[nt].z; c1[nt][3] = bb1[nt].w;
            c1[nt] = __builtin_amdgcn_mfma_f32_16x16x32_f16(a1[nt], bf.v, c1[nt], 0, 0, 0);
        }

        #pragma unroll
        for (int nt = 0; nt < 4; ++nt) {
            #pragma unroll
            for (int r = 0; r < 4; ++r) {
                const int o = 16 * nt + qw * 4 + r;
                lds_h1[wid][o][pt] = __float2half(fmaxf(c1[nt][r], 0.0f));
            }
        }

        f32x4 c2[4];
        #pragma unroll
        for (int nt = 0; nt < 4; ++nt) {
            c2[nt][0] = bb2[nt].x; c2[nt][1] = bb2[nt].y;
            c2[nt][2] = bb2[nt].z; c2[nt][3] = bb2[nt].w;
        }
        #pragma unroll
        for (int kb = 0; kb < 2; ++kb) {
            union { uint32_t u[4]; f16x8 v; } hb;
            #pragma unroll
            for (int j2 = 0; j2 < 4; ++j2) {
                const int k0 = kb * 32 + qw * 8 + 2 * j2;
                const uint32_t lo = __half_as_ushort(lds_h1[wid][k0][pt]);
                const uint32_t hi = __half_as_ushort(lds_h1[wid][k0 + 1][pt]);
                hb.u[j2] = lo | (hi << 16);
            }
            #pragma unroll
            for (int nt = 0; nt < 4; ++nt)
                c2[nt] = __builtin_amdgcn_mfma_f32_16x16x32_f16(a2[nt * 2 + kb], hb.v, c2[nt], 0, 0, 0);
        }

        float part = 0.0f;
        #pragma unroll
        for (int nt = 0; nt < 4; ++nt) {
            part = fmaf(fmaxf(c2[nt][0], 0.0f), w3v[nt].x, part);
            part = fmaf(fmaxf(c2[nt][1], 0.0f), w3v[nt].y, part);
            part = fmaf(fmaxf(c2[nt][2], 0.0f), w3v[nt].z, part);
            part = fmaf(fmaxf(c2[nt][3], 0.0f), w3v[nt].w, part);
        }
        part += __shfl_xor(part, 16, 64);
        part += __shfl_xor(part, 32, 64);
        if (lane < 16 && i < n) out[i] = part * ENC_INV + b3s;
    }
}

// ---------- Fallback: fused kernel (ws too small) ----------
__global__ __launch_bounds__(NTHREADS, 4) void sdf_tcnn_fused(
    const float* __restrict__ x,
    const float* __restrict__ tblf,
    const float* __restrict__ W1, const float* __restrict__ b1,
    const float* __restrict__ W2, const float* __restrict__ b2,
    const float* __restrict__ W3, const float* __restrict__ b3,
    float* __restrict__ out, int n)
{
    const int i = blockIdx.x * NTHREADS + threadIdx.x;
    if (i >= n) return;

    const float u = (x[3 * i + 0] + 1.0f) * 0.5f;
    const float v = (x[3 * i + 1] + 1.0f) * 0.5f;
    const float w = (x[3 * i + 2] + 1.0f) * 0.5f;

#define DECLH(m) float4 h##m = *(const float4*)&b1[4 * (m)];
    H16(DECLH)
#undef DECLH

    #pragma unroll
    for (int l = 0; l < NLVL; ++l) {
        const float sc = LV.scale[l];
        const int res = LV.res[l];
        const float pu = u * sc + 0.5f;
        const float pv = v * sc + 0.5f;
        const float pw = w * sc + 0.5f;
        const float fu = floorf(pu), fv = floorf(pv), fw = floorf(pw);
        const float wu = pu - fu, wv = pv - fv, ww = pw - fw;
        const int iu = (int)fu, iv = (int)fv, iw = (int)fw;

        int idx[8];
        #pragma unroll
        for (int b = 0; b < 8; ++b) {
            const int o0 = (b >> 2) & 1, o1 = (b >> 1) & 1, o2 = b & 1;
            if (LV.dense[l]) {
                idx[b] = (iu + o0) + (iv + o1) * res + (iw + o2) * (res * res);
            } else {
                idx[b] = (int)hash3((uint32_t)(iu + o0), (uint32_t)(iv + o1), (uint32_t)(iw + o2));
            }
        }
        const float2* tl = tblf ? (const float2*)tblf + (size_t)l * TBL_SIZE : nullptr;
        float2 cf[8];
        #pragma unroll
        for (int b = 0; b < 8; ++b) cf[b] = tl[idx[b]];
        float f0 = 0.0f, f1 = 0.0f;
        #pragma unroll
        for (int b = 0; b < 8; ++b) {
            const int o0 = (b >> 2) & 1, o1 = (b >> 1) & 1, o2 = b & 1;
            const float wt = (o0 ? wu : 1.0f - wu) *
                             (o1 ? wv : 1.0f - wv) *
                             (o2 ? ww : 1.0f - ww);
            f0 = fmaf(cf[b].x, wt, f0);
            f1 = fmaf(cf[b].y, wt, f1);
        }

        const float* wra = &W1[(2 * l) * HIDDEN];
        const float* wrb = &W1[(2 * l + 1) * HIDDEN];
#define UPDH(m) { \
        const float4 wa = *(const float4*)&wra[4 * (m)]; \
        const float4 wb = *(const float4*)&wrb[4 * (m)]; \
        h##m.x = fmaf(f0, wa.x, fmaf(f1, wb.x, h##m.x)); \
        h##m.y = fmaf(f0, wa.y, fmaf(f1, wb.y, h##m.y)); \
        h##m.z = fmaf(f0, wa.z, fmaf(f1, wb.z, h##m.z)); \
        h##m.w = fmaf(f0, wa.w, fmaf(f1, wb.w, h##m.w)); }
        H16(UPDH)
#undef UPDH
    }

#define RELUH(m) { h##m.x = fmaxf(h##m.x, 0.0f); h##m.y = fmaxf(h##m.y, 0.0f); \
                   h##m.z = fmaxf(h##m.z, 0.0f); h##m.w = fmaxf(h##m.w, 0.0f); }
    H16(RELUH)
#undef RELUH

    float acc = b3[0];
    #pragma unroll 2
    for (int jb = 0; jb < HIDDEN; jb += 4) {
        float4 t = *(const float4*)&b2[jb];
#define L2K(m) { \
        const float4 r0 = *(const float4*)&W2[(4 * (m) + 0) * HIDDEN + jb]; \
        const float4 r1 = *(const float4*)&W2[(4 * (m) + 1) * HIDDEN + jb]; \
        const float4 r2 = *(const float4*)&W2[(4 * (m) + 2) * HIDDEN + jb]; \
        const float4 r3 = *(const float4*)&W2[(4 * (m) + 3) * HIDDEN + jb]; \
        t.x = fmaf(h##m.x, r0.x, t.x); t.y = fmaf(h##m.x, r0.y, t.y); \
        t.z = fmaf(h##m.x, r0.z, t.z); t.w = fmaf(h##m.x, r0.w, t.w); \
        t.x = fmaf(h##m.y, r1.x, t.x); t.y = fmaf(h##m.y, r1.y, t.y); \
        t.z = fmaf(h##m.y, r1.z, t.z); t.w = fmaf(h##m.y, r1.w, t.w); \
        t.x = fmaf(h##m.z, r2.x, t.x); t.y = fmaf(h##m.z, r2.y, t.y); \
        t.z = fmaf(h##m.z, r2.z, t.z); t.w = fmaf(h##m.z, r2.w, t.w); \
        t.x = fmaf(h##m.w, r3.x, t.x); t.y = fmaf(h##m.w, r3.y, t.y); \
        t.z = fmaf(h##m.w, r3.z, t.z); t.w = fmaf(h##m.w, r3.w, t.w); }
        H16(L2K)
#undef L2K
        const float4 w3v = *(const float4*)&W3[jb];
        acc = fmaf(fmaxf(t.x, 0.0f), w3v.x, acc);
        acc = fmaf(fmaxf(t.y, 0.0f), w3v.y, acc);
        acc = fmaf(fmaxf(t.z, 0.0f), w3v.z, acc);
        acc = fmaf(fmaxf(t.w, 0.0f), w3v.w, acc);
    }

    out[i] = acc;
}

extern "C" void kernel_launch(void* const* d_in, const int* in_sizes, int n_in,
                              void* d_out, int out_size, void* d_ws, size_t ws_size,
                              hipStream_t stream) {
    const float* x     = (const float*)d_in[0];
    const float* table = (const float*)d_in[1];
    const float* W1    = (const float*)d_in[2];
    const float* b1    = (const float*)d_in[3];
    const float* W2    = (const float*)d_in[4];
    const float* b2    = (const float*)d_in[5];
    const float* W3    = (const float*)d_in[6];
    const float* b3    = (const float*)d_in[7];
    float* out = (float*)d_out;

    const int n = in_sizes[0] / 3;
    const size_t tbl_bytes   = (size_t)NLVL * TBL_SIZE * sizeof(__half2);   // 33.6 MB
    const size_t quad_bytes  = (size_t)PO.total * 16;                       // ~13.2 MB
    const size_t wfrag_bytes = 16384;
    const size_t enc_bytes   = (size_t)NLVL * (size_t)n * sizeof(__half2);  // 64 MB
    const size_t base_need   = tbl_bytes + quad_bytes + wfrag_bytes + enc_bytes;
    const int nb_enc = (n + NTHREADS * PPT - 1) / (NTHREADS * PPT);

    if (ws_size >= base_need) {
        char* p = (char*)d_ws;
        __half2* tbl_h2 = (__half2*)p;                 p += tbl_bytes;
        uint4* qd = (uint4*)p;                         p += quad_bytes;
        __half* w1f = (__half*)p;                      p += 4 * 64 * 8 * sizeof(__half);
        __half* w2f = (__half*)p;                      p += 4 * 2 * 64 * 8 * sizeof(__half);
        __half2* enc = (__half2*)p;

        hipLaunchKernelGGL(cvt_all, dim3(4096), dim3(256), 0, stream,
                           (const float2*)table, tbl_h2, qd, W1, W2, w1f, w2f);
        hipLaunchKernelGGL(encode_dense, dim3(nb_enc), dim3(NTHREADS), 0, stream,
                           x, qd, enc, n);
        hipLaunchKernelGGL(encode_hash, dim3(nb_enc * NHASH), dim3(NTHREADS), 0, stream,
                           x, tbl_h2, enc, n, nb_enc);
        hipLaunchKernelGGL(mlp_mfma, dim3((n + 16 * MLP_TPW * 4 - 1) / (16 * MLP_TPW * 4)),
                           dim3(256), 0, stream,
                           enc, w1f, w2f, b1, b2, W3, b3, out, n);
    } else {
        hipLaunchKernelGGL(sdf_tcnn_fused, dim3((n + NTHREADS - 1) / NTHREADS), dim3(NTHREADS), 0, stream,
                           x, table, W1, b1, W2, b2, W3, b3, out, n);
    }
}